// Round 10
// baseline (256.457 us; speedup 1.0000x reference)
//
#include <hip/hip_runtime.h>
#include <stdint.h>

#define D_MODEL 1024
#define SEQ     2048
#define NHEAD   16
#define BATCH   2
#define NROWS   (BATCH*SEQ)   // 4096

typedef _Float16 f16;
typedef _Float16 f16x8 __attribute__((ext_vector_type(8)));
typedef _Float16 f16x4 __attribute__((ext_vector_type(4)));
typedef __fp16   h16x2 __attribute__((ext_vector_type(2)));
typedef float    f32x4 __attribute__((ext_vector_type(4)));

#define MFMA16 __builtin_amdgcn_mfma_f32_16x16x32_f16

__device__ __forceinline__ void gload16(const void* g, void* l) {
  __builtin_amdgcn_global_load_lds(
      (const __attribute__((address_space(1))) void*)g,
      (__attribute__((address_space(3))) void*)l, 16, 0, 0);
}

__device__ __forceinline__ int pkh2(float a, float b) {
  union { h16x2 h; int i; } u;
  u.h = __builtin_amdgcn_cvt_pkrtz(a, b);
  return u.i;
}

// ---------------- convert / split kernels ----------------
__global__ void split4_kernel(const float* __restrict__ in, f16* __restrict__ hi,
                              f16* __restrict__ lo, int n4, float scale) {
  int i = blockIdx.x * blockDim.x + threadIdx.x;
  if (i >= n4) return;
  float4 v = reinterpret_cast<const float4*>(in)[i];
  v.x *= scale; v.y *= scale; v.z *= scale; v.w *= scale;
  f16x4 h, l4;
  h[0] = (f16)v.x; h[1] = (f16)v.y; h[2] = (f16)v.z; h[3] = (f16)v.w;
  l4[0] = (f16)(v.x - (float)h[0]);
  l4[1] = (f16)(v.y - (float)h[1]);
  l4[2] = (f16)(v.z - (float)h[2]);
  l4[3] = (f16)(v.w - (float)h[3]);
  *reinterpret_cast<f16x4*>(hi + 4*(size_t)i) = h;
  *reinterpret_cast<f16x4*>(lo + 4*(size_t)i) = l4;
}

// fused weight prep: wq split (scaled), wk split, wv cvt, wo cvt — one pass
__global__ void prep_w_kernel(const float* __restrict__ pq, const float* __restrict__ pk,
                              const float* __restrict__ pv, const float* __restrict__ po,
                              f16* __restrict__ wq_hi, f16* __restrict__ wq_lo,
                              f16* __restrict__ wk_hi, f16* __restrict__ wk_lo,
                              f16* __restrict__ wv_h,  f16* __restrict__ wo_h,
                              int n4, float qscale) {
  int i = blockIdx.x * blockDim.x + threadIdx.x;
  if (i >= n4) return;
  {
    float4 v = reinterpret_cast<const float4*>(pq)[i];
    v.x *= qscale; v.y *= qscale; v.z *= qscale; v.w *= qscale;
    f16x4 h, l4;
    h[0] = (f16)v.x; h[1] = (f16)v.y; h[2] = (f16)v.z; h[3] = (f16)v.w;
    l4[0] = (f16)(v.x - (float)h[0]); l4[1] = (f16)(v.y - (float)h[1]);
    l4[2] = (f16)(v.z - (float)h[2]); l4[3] = (f16)(v.w - (float)h[3]);
    *reinterpret_cast<f16x4*>(wq_hi + 4*(size_t)i) = h;
    *reinterpret_cast<f16x4*>(wq_lo + 4*(size_t)i) = l4;
  }
  {
    float4 v = reinterpret_cast<const float4*>(pk)[i];
    f16x4 h, l4;
    h[0] = (f16)v.x; h[1] = (f16)v.y; h[2] = (f16)v.z; h[3] = (f16)v.w;
    l4[0] = (f16)(v.x - (float)h[0]); l4[1] = (f16)(v.y - (float)h[1]);
    l4[2] = (f16)(v.z - (float)h[2]); l4[3] = (f16)(v.w - (float)h[3]);
    *reinterpret_cast<f16x4*>(wk_hi + 4*(size_t)i) = h;
    *reinterpret_cast<f16x4*>(wk_lo + 4*(size_t)i) = l4;
  }
  {
    float4 v = reinterpret_cast<const float4*>(pv)[i];
    f16x4 h;
    h[0] = (f16)v.x; h[1] = (f16)v.y; h[2] = (f16)v.z; h[3] = (f16)v.w;
    *reinterpret_cast<f16x4*>(wv_h + 4*(size_t)i) = h;
  }
  {
    float4 v = reinterpret_cast<const float4*>(po)[i];
    f16x4 h;
    h[0] = (f16)v.x; h[1] = (f16)v.y; h[2] = (f16)v.z; h[3] = (f16)v.w;
    *reinterpret_cast<f16x4*>(wo_h + 4*(size_t)i) = h;
  }
}

// ---------------- GEMM: C[M,N] = A[M,K] · B[N,K]^T  (NT, plain fp16) -------------
// 128x128 tile, 4 waves 2x2 (each 64x64, 16 MFMA per 8 ds_reads per K-step).
template<bool F32_OUT, bool COLCHUNK>
__global__ __launch_bounds__(256, 4)
void gemm_nt(const f16* __restrict__ A, const f16* __restrict__ B,
             f16* __restrict__ Ch, float* __restrict__ Cf,
             int M, int N, int K)
{
  constexpr int STRIDE = 16384;       // 8KB A + 8KB B per buffer
  __shared__ __align__(16) char smem[2 * STRIDE];

  const int tid = threadIdx.x;
  const int w = tid >> 6, l = tid & 63;
  const int wr = (w >> 1) * 64;
  const int wc = (w & 1) * 64;

  const int gx = gridDim.x, gy = gridDim.y;
  const int nwg = gx * gy;
  const int flat = blockIdx.y * gx + blockIdx.x;
  const int swz = (flat & 7) * (nwg >> 3) + (flat >> 3);
  const int bxn = COLCHUNK ? (swz / gy) : (swz % gx);
  const int byn = COLCHUNK ? (swz % gy) : (swz / gx);
  const int bm = byn * 128, bn = bxn * 128;

  f32x4 acc[4][4] = {};

  const int rl = l >> 2;
  const int sc = 8 * ((l & 3) ^ ((l >> 3) & 3));   // pre-swizzled source chunk

  auto stage = [&](int kt) {
    char* dst = smem + (kt & 1) * STRIDE;
    const int k0 = kt * 32;
#pragma unroll
    for (int i = 0; i < 4; i++) {
      const int s = i * 4 + w;                     // 0..15
      const f16* base = (s < 8) ? A : B;
      const int row0 = (s < 8) ? (bm + s * 16) : (bn + (s - 8) * 16);
      gload16(base + (size_t)(row0 + rl) * K + k0 + sc,
              dst + ((s < 8) ? 0 : 8192) + (s & 7) * 1024);
    }
  };

  const int nkt = K >> 5;
  stage(0);

  for (int kt = 0; kt < nkt; kt++) {
    if (kt + 1 < nkt) {
      stage(kt + 1);
      asm volatile("s_waitcnt vmcnt(4)" ::: "memory");
    } else {
      asm volatile("s_waitcnt vmcnt(0)" ::: "memory");
    }
    __builtin_amdgcn_s_barrier();

    const char* buf = smem + (kt & 1) * STRIDE;
    const int ar = l & 15;
    const int ak = 16 * ((l >> 4) ^ ((ar >> 1) & 3));
    f16x8 a[4], b[4];
#pragma unroll
    for (int mi = 0; mi < 4; mi++)
      a[mi] = *(const f16x8*)(buf + (size_t)(wr + mi*16 + ar) * 64 + ak);
#pragma unroll
    for (int ni = 0; ni < 4; ni++)
      b[ni] = *(const f16x8*)(buf + 8192 + (size_t)(wc + ni*16 + ar) * 64 + ak);
    __builtin_amdgcn_s_setprio(1);
#pragma unroll
    for (int ni = 0; ni < 4; ni++)
#pragma unroll
      for (int mi = 0; mi < 4; mi++)
        acc[mi][ni] = MFMA16(a[mi], b[ni], acc[mi][ni], 0, 0, 0);
    __builtin_amdgcn_s_setprio(0);
    __builtin_amdgcn_s_barrier();
  }

  const int crow0 = bm + wr + (l >> 4) * 4;
  const int ccol0 = bn + wc + (l & 15);
#pragma unroll
  for (int mi = 0; mi < 4; mi++) {
#pragma unroll
    for (int ni = 0; ni < 4; ni++) {
#pragma unroll
      for (int j = 0; j < 4; j++) {
        size_t idx = (size_t)(crow0 + mi*16 + j) * N + (ccol0 + ni*16);
        float v = acc[mi][ni][j];
        if (F32_OUT) Cf[idx] = v;
        else         Ch[idx] = (f16)v;
      }
    }
  }
}

// ---------------- fused Q+K projection GEMM v2 (4-phase, 3-buffer ring) ----------
// Tile 256x64 (Q and K outputs), 512 thr / 8 waves (4 row x 2 col), BK=32.
// LDS ring: 3 x 48KB (Ahi 16K | Alo 16K | Bqh 4K | Bql 4K | Bkh 4K | Bkl 4K).
// Per K-step: 4 phases x {ds_read subtile, issue 2 gloads for t+2, barrier,
// lgkmcnt(0), setprio(1), 12 MFMA, setprio(0), barrier}; counted vmcnt(6)
// once per K-step (T3+T4). 256 blocks = 1/CU, uniform duration.
__global__ __launch_bounds__(512, 2)
void gemm_qk(const f16* __restrict__ Ahi, const f16* __restrict__ Alo,
             const f16* __restrict__ Bqh, const f16* __restrict__ Bql,
             const f16* __restrict__ Bkh, const f16* __restrict__ Bkl,
             f16* __restrict__ Qh, f16* __restrict__ Qlo2,
             f16* __restrict__ Kh, f16* __restrict__ Klo2)
{
  constexpr int K = D_MODEL, N = D_MODEL;
  constexpr int BUF = 49152;
  constexpr int KT = 32;
  __shared__ __align__(16) char smem[3 * BUF];   // 144KB

  const int tid = threadIdx.x;
  const int w = tid >> 6, l = tid & 63;
  const int wr = (w & 3) * 64;
  const int wc = (w >> 2) * 32;

  const int flat = blockIdx.y * 16 + blockIdx.x;           // grid (16,16)
  const int swz = (flat & 7) * 32 + (flat >> 3);           // XCD-chunked
  const int bm = (swz >> 4) * 256, bn = (swz & 15) * 64;

  f32x4 accQ[4][2] = {}, accK[4][2] = {};

  const int rl = l >> 2;
  const int sc = 8 * ((l & 3) ^ ((l >> 3) & 3));

  // issue one of the 6 per-wave staging gloads for tile t
  auto stage2 = [&](int t, int i) {
    char* buf = smem + (t % 3) * BUF;
    const int k0 = t * 32;
    const int s = i * 8 + w;                    // 0..47
    if (s < 32) {
      const f16* base = (s < 16) ? Ahi : Alo;
      const int row0 = bm + ((s & 15) << 4);
      gload16(base + (size_t)(row0 + rl) * K + k0 + sc,
              buf + ((s < 16) ? 0 : 16384) + ((s & 15) << 10));
    } else {
      const int arr = (s - 32) >> 2;            // 0..3
      const f16* base = arr == 0 ? Bqh : arr == 1 ? Bql : arr == 2 ? Bkh : Bkl;
      const int row0 = bn + ((s & 3) << 4);
      gload16(base + (size_t)(row0 + rl) * K + k0 + sc,
              buf + 32768 + arr * 4096 + ((s & 3) << 10));
    }
  };

  // prologue: 2 tiles in flight
#pragma unroll
  for (int i = 0; i < 6; i++) stage2(0, i);
#pragma unroll
  for (int i = 0; i < 6; i++) stage2(1, i);
  asm volatile("s_waitcnt vmcnt(6)" ::: "memory");   // tile-0 loads done
  __builtin_amdgcn_s_barrier();

  for (int t = 0; t < KT; t++) {
    const char* buf = smem + (t % 3) * BUF;
    const bool pf = (t + 2 < KT);
    const int ar = l & 15;
    const int ak = 16 * ((l >> 4) ^ ((ar >> 1) & 3));
    const int bo0 = (wc + ar) * 64 + ak;        // B row group ni=0
    const int bo1 = (wc + 16 + ar) * 64 + ak;   // ni=1
    f16x8 a_hi[4], a_lo[4], b0, b1;

    // ---- P0: A frags + Bq(ni=0); 12 Q-MFMAs ----
#pragma unroll
    for (int mi = 0; mi < 4; mi++) {
      a_hi[mi] = *(const f16x8*)(buf + (size_t)(wr + mi*16 + ar) * 64 + ak);
      a_lo[mi] = *(const f16x8*)(buf + 16384 + (size_t)(wr + mi*16 + ar) * 64 + ak);
    }
    b0 = *(const f16x8*)(buf + 32768 + bo0);
    b1 = *(const f16x8*)(buf + 36864 + bo0);
    if (pf) { stage2(t + 2, 0); stage2(t + 2, 1); }
    __builtin_amdgcn_s_barrier();
    asm volatile("s_waitcnt lgkmcnt(0)" ::: "memory");
    __builtin_amdgcn_s_setprio(1);
#pragma unroll
    for (int mi = 0; mi < 4; mi++) {
      accQ[mi][0] = MFMA16(a_hi[mi], b0, accQ[mi][0], 0, 0, 0);
      accQ[mi][0] = MFMA16(a_hi[mi], b1, accQ[mi][0], 0, 0, 0);
      accQ[mi][0] = MFMA16(a_lo[mi], b0, accQ[mi][0], 0, 0, 0);
    }
    __builtin_amdgcn_s_setprio(0);
    __builtin_amdgcn_s_barrier();

    // ---- P1: Bk(ni=0); 12 K-MFMAs ----
    b0 = *(const f16x8*)(buf + 40960 + bo0);
    b1 = *(const f16x8*)(buf + 45056 + bo0);
    if (pf) { stage2(t + 2, 2); stage2(t + 2, 3); }
    __builtin_amdgcn_s_barrier();
    asm volatile("s_waitcnt lgkmcnt(0)" ::: "memory");
    __builtin_amdgcn_s_setprio(1);
#pragma unroll
    for (int mi = 0; mi < 4; mi++) {
      accK[mi][0] = MFMA16(a_hi[mi], b0, accK[mi][0], 0, 0, 0);
      accK[mi][0] = MFMA16(a_hi[mi], b1, accK[mi][0], 0, 0, 0);
      accK[mi][0] = MFMA16(a_lo[mi], b0, accK[mi][0], 0, 0, 0);
    }
    __builtin_amdgcn_s_setprio(0);
    __builtin_amdgcn_s_barrier();

    // ---- P2: Bq(ni=1); 12 Q-MFMAs ----
    b0 = *(const f16x8*)(buf + 32768 + bo1);
    b1 = *(const f16x8*)(buf + 36864 + bo1);
    if (pf) { stage2(t + 2, 4); stage2(t + 2, 5); }
    __builtin_amdgcn_s_barrier();
    asm volatile("s_waitcnt lgkmcnt(0)" ::: "memory");
    __builtin_amdgcn_s_setprio(1);
#pragma unroll
    for (int mi = 0; mi < 4; mi++) {
      accQ[mi][1] = MFMA16(a_hi[mi], b0, accQ[mi][1], 0, 0, 0);
      accQ[mi][1] = MFMA16(a_hi[mi], b1, accQ[mi][1], 0, 0, 0);
      accQ[mi][1] = MFMA16(a_lo[mi], b0, accQ[mi][1], 0, 0, 0);
    }
    __builtin_amdgcn_s_setprio(0);
    __builtin_amdgcn_s_barrier();

    // ---- P3: Bk(ni=1); 12 K-MFMAs; counted vmcnt ----
    b0 = *(const f16x8*)(buf + 40960 + bo1);
    b1 = *(const f16x8*)(buf + 45056 + bo1);
    __builtin_amdgcn_s_barrier();
    asm volatile("s_waitcnt lgkmcnt(0)" ::: "memory");
    __builtin_amdgcn_s_setprio(1);
#pragma unroll
    for (int mi = 0; mi < 4; mi++) {
      accK[mi][1] = MFMA16(a_hi[mi], b0, accK[mi][1], 0, 0, 0);
      accK[mi][1] = MFMA16(a_hi[mi], b1, accK[mi][1], 0, 0, 0);
      accK[mi][1] = MFMA16(a_lo[mi], b0, accK[mi][1], 0, 0, 0);
    }
    __builtin_amdgcn_s_setprio(0);
    if (pf) asm volatile("s_waitcnt vmcnt(6)" ::: "memory");
    else    asm volatile("s_waitcnt vmcnt(0)" ::: "memory");
    __builtin_amdgcn_s_barrier();
  }

  const int crow0 = bm + wr + (l >> 4) * 4;
  const int ccol0 = bn + wc + (l & 15);
#pragma unroll
  for (int mi = 0; mi < 4; mi++) {
#pragma unroll
    for (int ni = 0; ni < 2; ni++) {
#pragma unroll
      for (int j = 0; j < 4; j++) {
        size_t idx = (size_t)(crow0 + mi*16 + j) * N + (ccol0 + ni*16);
        float qv = accQ[mi][ni][j];
        f16 qh = (f16)qv;
        Qh[idx] = qh;  Qlo2[idx] = (f16)(qv - (float)qh);
        float kv = accK[mi][ni][j];
        f16 kh = (f16)kv;
        Kh[idx] = kh;  Klo2[idx] = (f16)(kv - (float)kh);
      }
    }
  }
}

// ---------------- flash attention v7 (causal, uniform-duration pair blocks) ----------
// (unchanged from round 9 — isolating the GEMM changes)
__global__ __launch_bounds__(512, 4)
void attn_kernel(const f16* __restrict__ Qhi, const f16* __restrict__ Qlo,
                 const f16* __restrict__ Khi, const f16* __restrict__ Klo,
                 const f16* __restrict__ VT, f16* __restrict__ Out)
{
  __shared__ __align__(16) char smem[49152];   // 4 x 12KB ring (+ merge reuse)

  const int tid = threadIdx.x, w = tid >> 6, l = tid & 63;
  const int g = l >> 4, q4 = l & 15;
  const int wi = w & 3, grp = w >> 2;
  const int flat = blockIdx.x;
  const int xcd = flat & 7, slot = flat >> 3;
  const int bh = xcd * 4 + (slot >> 4);
  const int c = slot & 15;
  const int b = bh >> 4, h = bh & 15;
  const int bS = b * SEQ;
  const size_t hoff = (size_t)h * 64;
  const int T  = 64 - 2 * c;
  const int P1 = 2 * c + 2;
  const int P2 = 31 - 2 * c;

  int qw = (grp ? (31 - c) : c) * 64 + wi * 16;

  f16x8 qh[2], ql[2];
  auto loadQ = [&]() {
#pragma unroll
    for (int ks = 0; ks < 2; ks++) {
      const size_t base = (size_t)(bS + qw + q4) * D_MODEL + hoff + ks * 32 + g * 8;
      qh[ks] = *(const f16x8*)(Qhi + base);
      ql[ks] = *(const f16x8*)(Qlo + base);
    }
  };
  loadQ();

  f32x4 o[4] = {};
  float m_run = -INFINITY, l_run = 0.f;

  const int k_src = 8 * ((l & 7) ^ (l >> 3));
  const int v_src = 8 * ((l & 3) ^ ((l >> 2) & 3));

  auto stage = [&](int t) {
    const int kv0 = t * 32;
    char* sb = smem + (t & 3) * 12288;
    if (w < 4) {
      const f16* src = (w < 2) ? Khi : Klo;
      char* dstc = sb + ((w < 2) ? 0 : 4096);
      const int wi2 = w & 1;
#pragma unroll
      for (int gi = 0; gi < 2; gi++) {
        const int sub = 2 * wi2 + gi;
        const int row = 8 * sub + (l >> 3);
        gload16(src + (size_t)(bS + kv0 + row) * D_MODEL + hoff + k_src,
                dstc + sub * 1024);
      }
    } else if (w < 6) {
      const int wi2 = w - 4;
#pragma unroll
      for (int gi = 0; gi < 2; gi++) {
        const int sub = 2 * wi2 + gi;
        const int drow = 16 * sub + (l >> 2);
        gload16(VT + (hoff + drow) * (size_t)NROWS + bS + kv0 + v_src,
                sb + 8192 + sub * 1024);
      }
    }
  };

  const int idx_lo = (q4 + 32 * (g & 1)) * 4;
  const int idx_hi = idx_lo + 64;
  const bool upper = (l >= 32);

  auto compute = [&](int t) {
    const char* sb = smem + (t & 3) * 12288;
    const int kv0 = t * 32;

    f32x4 s[2] = {};
    __builtin_amdgcn_s_setprio(1);
#pragma unroll
    for (int ni = 0; ni < 2; ni++) {
      const int row = ni * 16 + q4;
#pragma unroll
      for (int ks = 0; ks < 2; ks++) {
        const int boff = row * 128 + 16 * ((ks * 4 + g) ^ (row & 7));
        f16x8 kh8 = *(const f16x8*)(sb + boff);
        f16x8 kl8 = *(const f16x8*)(sb + 4096 + boff);
        s[ni] = MFMA16(kh8, qh[ks], s[ni], 0, 0, 0);
        s[ni] = MFMA16(kh8, ql[ks], s[ni], 0, 0, 0);
        s[ni] = MFMA16(kl8, qh[ks], s[ni], 0, 0, 0);
      }
    }
    __builtin_amdgcn_s_setprio(0);

    const bool need_mask = (kv0 + 31) > qw;
    const int q_abs = qw + q4;
    float p[2][4];
    float pm = -INFINITY;
#pragma unroll
    for (int ni = 0; ni < 2; ni++)
#pragma unroll
      for (int j = 0; j < 4; j++) {
        float v = s[ni][j];
        if (need_mask && (kv0 + ni * 16 + 4 * g + j) > q_abs) v = -INFINITY;
        p[ni][j] = v;
        pm = fmaxf(pm, v);
      }
    pm = fmaxf(pm, __shfl_xor(pm, 16));
    pm = fmaxf(pm, __shfl_xor(pm, 32));

    if (!__all(pm - m_run <= 8.0f)) {
      const float mn = fmaxf(m_run, pm);
      const float sc2 = __builtin_amdgcn_exp2f(m_run - mn);
      m_run = mn;
      l_run *= sc2;
#pragma unroll
      for (int nd = 0; nd < 4; nd++)
#pragma unroll
        for (int j = 0; j < 4; j++) o[nd][j] *= sc2;
    }
    float ps = 0.f;
#pragma unroll
    for (int ni = 0; ni < 2; ni++)
#pragma unroll
      for (int j = 0; j < 4; j++) {
        const float e = __builtin_amdgcn_exp2f(p[ni][j] - m_run);
        p[ni][j] = e;
        ps += e;
      }
    ps += __shfl_xor(ps, 16);
    ps += __shfl_xor(ps, 32);
    l_run += ps;

    const int pk0 = pkh2(p[0][0], p[0][1]);
    const int pk1 = pkh2(p[0][2], p[0][3]);
    const int pk2 = pkh2(p[1][0], p[1][1]);
    const int pk3 = pkh2(p[1][2], p[1][3]);
    const int b0l = __builtin_amdgcn_ds_bpermute(idx_lo, pk0);
    const int b2l = __builtin_amdgcn_ds_bpermute(idx_lo, pk2);
    const int b1l = __builtin_amdgcn_ds_bpermute(idx_lo, pk1);
    const int b3l = __builtin_amdgcn_ds_bpermute(idx_lo, pk3);
    const int b0h = __builtin_amdgcn_ds_bpermute(idx_hi, pk0);
    const int b2h = __builtin_amdgcn_ds_bpermute(idx_hi, pk2);
    const int b1h = __builtin_amdgcn_ds_bpermute(idx_hi, pk1);
    const int b3h = __builtin_amdgcn_ds_bpermute(idx_hi, pk3);
    union { int u[4]; f16x8 v; } pu;
    pu.u[0] = upper ? b2l : b0l;
    pu.u[1] = upper ? b3l : b1l;
    pu.u[2] = upper ? b2h : b0h;
    pu.u[3] = upper ? b3h : b1h;
    const f16x8 pa = pu.v;

    __builtin_amdgcn_s_setprio(1);
#pragma unroll
    for (int nd = 0; nd < 4; nd++) {
      const int d = nd * 16 + q4;
      f16x8 bv = *(const f16x8*)(sb + 8192 + d * 64 + 16 * (g ^ (d & 3)));
      o[nd] = MFMA16(bv, pa, o[nd], 0, 0, 0);
    }
    __builtin_amdgcn_s_setprio(0);
  };

  stage(0);
  stage(1);

  for (int t = 0; t < P1; t++) {
    stage(t + 2);
    asm volatile("s_waitcnt vmcnt(4)" ::: "memory");
    __builtin_amdgcn_s_barrier();
    compute(t);
    __builtin_amdgcn_s_barrier();
  }

  if (grp == 0) {
    const float inv = 1.0f / l_run;
    const size_t rowb = (size_t)(bS + qw + q4) * D_MODEL + hoff;
#pragma unroll
    for (int nd = 0; nd < 4; nd++) {
      f16x4 v;
#pragma unroll
      for (int j = 0; j < 4; j++) v[j] = (f16)(o[nd][j] * inv);
      *reinterpret_cast<f16x4*>(Out + rowb + nd * 16 + 4 * g) = v;
    }
    qw = (31 - c) * 64 + wi * 16;
    loadQ();
#pragma unroll
    for (int nd = 0; nd < 4; nd++)
#pragma unroll
      for (int j = 0; j < 4; j++) o[nd][j] = 0.f;
    m_run = -INFINITY;
    l_run = 0.f;
  }

  for (int j = 0; j < P2; j++) {
    const int u = P1 + 2 * j;
    const bool st = (u + 3) < T;
    if (st) { stage(u + 2); stage(u + 3); }
    if (st) asm volatile("s_waitcnt vmcnt(4)" ::: "memory");
    else    asm volatile("s_waitcnt vmcnt(0)" ::: "memory");
    __builtin_amdgcn_s_barrier();
    compute(u + grp);
    __builtin_amdgcn_s_barrier();
  }

  if (grp == 0) {
    float* mb = (float*)smem + wi * 1152 + l * 18;
#pragma unroll
    for (int nd = 0; nd < 4; nd++)
#pragma unroll
      for (int j = 0; j < 4; j++) mb[nd * 4 + j] = o[nd][j];
    mb[16] = m_run;
    mb[17] = l_run;
  }
  __syncthreads();
  if (grp == 1) {
    const float* mb = (const float*)smem + wi * 1152 + l * 18;
    const float m2 = mb[16], l2 = mb[17];
    const float mm = fmaxf(m_run, m2);
    const float a1 = __builtin_amdgcn_exp2f(m_run - mm);
    const float a2 = __builtin_amdgcn_exp2f(m2 - mm);
    const float inv = 1.0f / (l_run * a1 + l2 * a2);
    const size_t rowb = (size_t)(bS + qw + q4) * D_MODEL + hoff;
#pragma unroll
    for (int nd = 0; nd < 4; nd++) {
      f16x4 v;
#pragma unroll
      for (int j = 0; j < 4; j++)
        v[j] = (f16)((o[nd][j] * a1 + mb[nd * 4 + j] * a2) * inv);
      *reinterpret_cast<f16x4*>(Out + rowb + nd * 16 + 4 * g) = v;
    }
  }
}

// ---------------- launcher ----------------
extern "C" void kernel_launch(void* const* d_in, const int* in_sizes, int n_in,
                              void* d_out, int out_size, void* d_ws, size_t ws_size,
                              hipStream_t stream) {
  const float* x  = (const float*)d_in[0];
  const float* pq = (const float*)d_in[1];
  const float* pk = (const float*)d_in[2];
  const float* pv = (const float*)d_in[3];
  const float* po = (const float*)d_in[4];
  float* out = (float*)d_out;

  char* ws = (char*)d_ws;
  size_t off = 0;
  auto alloc = [&](size_t elems) {
    f16* p = (f16*)(ws + off);
    off += ((elems * 2 + 255) & ~(size_t)255);
    return p;
  };
  f16* x_hi  = alloc((size_t)NROWS * D_MODEL);
  f16* x_lo  = alloc((size_t)NROWS * D_MODEL);
  f16* wq_hi = alloc((size_t)D_MODEL * D_MODEL);
  f16* wq_lo = alloc((size_t)D_MODEL * D_MODEL);
  f16* wk_hi = alloc((size_t)D_MODEL * D_MODEL);
  f16* wk_lo = alloc((size_t)D_MODEL * D_MODEL);
  f16* wv_h  = alloc((size_t)D_MODEL * D_MODEL);
  f16* wo_h  = alloc((size_t)D_MODEL * D_MODEL);
  f16* q_hi  = alloc((size_t)NROWS * D_MODEL);
  f16* q_lo  = alloc((size_t)NROWS * D_MODEL);
  f16* k_hi  = alloc((size_t)NROWS * D_MODEL);
  f16* k_lo  = alloc((size_t)NROWS * D_MODEL);
  f16* vt    = alloc((size_t)NROWS * D_MODEL);   // VT[m][b*SEQ+s]
  f16* ao    = alloc((size_t)NROWS * D_MODEL);

  const int n4x = NROWS * D_MODEL / 4;
  const int n4w = D_MODEL * D_MODEL / 4;
  const float qscale = 0.125f * 1.44269504088896f;
  split4_kernel<<<n4x/256, 256, 0, stream>>>(x, x_hi, x_lo, n4x, 1.0f);
  prep_w_kernel<<<n4w/256, 256, 0, stream>>>(pq, pk, pv, po,
                                             wq_hi, wq_lo, wk_hi, wk_lo, wv_h, wo_h,
                                             n4w, qscale);

  // fused Q+K projection, 4-phase pipelined
  gemm_qk<<<dim3(16, 16), 512, 0, stream>>>(x_hi, x_lo, wq_hi, wq_lo, wk_hi, wk_lo,
                                            q_hi, q_lo, k_hi, k_lo);
  // V projection with transposed output: VT[m][n] = sum_k wv[m][k] x[n][k]
  dim3 gv(NROWS/128, D_MODEL/128);  // (32, 8) col-chunked
  gemm_nt<false, true><<<gv, 256, 0, stream>>>(wv_h, x_hi, vt, nullptr, D_MODEL, NROWS, D_MODEL);

  attn_kernel<<<dim3(512), 512, 0, stream>>>(q_hi, q_lo, k_hi, k_lo, vt, ao);

  dim3 gg(D_MODEL/128, NROWS/128);  // (8, 32) row-chunked
  gemm_nt<true, false><<<gg, 256, 0, stream>>>(ao, wo_h, nullptr, out, NROWS, D_MODEL, D_MODEL);
}

// Round 11
// 170.045 us; speedup vs baseline: 1.5082x; 1.5082x over previous
//
#include <hip/hip_runtime.h>
#include <stdint.h>

#define D_MODEL 1024
#define SEQ     2048
#define NHEAD   16
#define BATCH   2
#define NROWS   (BATCH*SEQ)   // 4096

typedef _Float16 f16;
typedef _Float16 f16x8 __attribute__((ext_vector_type(8)));
typedef _Float16 f16x4 __attribute__((ext_vector_type(4)));
typedef __fp16   h16x2 __attribute__((ext_vector_type(2)));
typedef float    f32x4 __attribute__((ext_vector_type(4)));

#define MFMA16 __builtin_amdgcn_mfma_f32_16x16x32_f16

__device__ __forceinline__ void gload16(const void* g, void* l) {
  __builtin_amdgcn_global_load_lds(
      (const __attribute__((address_space(1))) void*)g,
      (__attribute__((address_space(3))) void*)l, 16, 0, 0);
}

__device__ __forceinline__ int pkh2(float a, float b) {
  union { h16x2 h; int i; } u;
  u.h = __builtin_amdgcn_cvt_pkrtz(a, b);
  return u.i;
}

// ---------------- convert / split kernels ----------------
__global__ void split4_kernel(const float* __restrict__ in, f16* __restrict__ hi,
                              f16* __restrict__ lo, int n4, float scale) {
  int i = blockIdx.x * blockDim.x + threadIdx.x;
  if (i >= n4) return;
  float4 v = reinterpret_cast<const float4*>(in)[i];
  v.x *= scale; v.y *= scale; v.z *= scale; v.w *= scale;
  f16x4 h, l4;
  h[0] = (f16)v.x; h[1] = (f16)v.y; h[2] = (f16)v.z; h[3] = (f16)v.w;
  l4[0] = (f16)(v.x - (float)h[0]);
  l4[1] = (f16)(v.y - (float)h[1]);
  l4[2] = (f16)(v.z - (float)h[2]);
  l4[3] = (f16)(v.w - (float)h[3]);
  *reinterpret_cast<f16x4*>(hi + 4*(size_t)i) = h;
  *reinterpret_cast<f16x4*>(lo + 4*(size_t)i) = l4;
}

// fused weight prep: wq split (scaled), wk split, wv cvt, wo cvt — one pass
__global__ void prep_w_kernel(const float* __restrict__ pq, const float* __restrict__ pk,
                              const float* __restrict__ pv, const float* __restrict__ po,
                              f16* __restrict__ wq_hi, f16* __restrict__ wq_lo,
                              f16* __restrict__ wk_hi, f16* __restrict__ wk_lo,
                              f16* __restrict__ wv_h,  f16* __restrict__ wo_h,
                              int n4, float qscale) {
  int i = blockIdx.x * blockDim.x + threadIdx.x;
  if (i >= n4) return;
  {
    float4 v = reinterpret_cast<const float4*>(pq)[i];
    v.x *= qscale; v.y *= qscale; v.z *= qscale; v.w *= qscale;
    f16x4 h, l4;
    h[0] = (f16)v.x; h[1] = (f16)v.y; h[2] = (f16)v.z; h[3] = (f16)v.w;
    l4[0] = (f16)(v.x - (float)h[0]); l4[1] = (f16)(v.y - (float)h[1]);
    l4[2] = (f16)(v.z - (float)h[2]); l4[3] = (f16)(v.w - (float)h[3]);
    *reinterpret_cast<f16x4*>(wq_hi + 4*(size_t)i) = h;
    *reinterpret_cast<f16x4*>(wq_lo + 4*(size_t)i) = l4;
  }
  {
    float4 v = reinterpret_cast<const float4*>(pk)[i];
    f16x4 h, l4;
    h[0] = (f16)v.x; h[1] = (f16)v.y; h[2] = (f16)v.z; h[3] = (f16)v.w;
    l4[0] = (f16)(v.x - (float)h[0]); l4[1] = (f16)(v.y - (float)h[1]);
    l4[2] = (f16)(v.z - (float)h[2]); l4[3] = (f16)(v.w - (float)h[3]);
    *reinterpret_cast<f16x4*>(wk_hi + 4*(size_t)i) = h;
    *reinterpret_cast<f16x4*>(wk_lo + 4*(size_t)i) = l4;
  }
  {
    float4 v = reinterpret_cast<const float4*>(pv)[i];
    f16x4 h;
    h[0] = (f16)v.x; h[1] = (f16)v.y; h[2] = (f16)v.z; h[3] = (f16)v.w;
    *reinterpret_cast<f16x4*>(wv_h + 4*(size_t)i) = h;
  }
  {
    float4 v = reinterpret_cast<const float4*>(po)[i];
    f16x4 h;
    h[0] = (f16)v.x; h[1] = (f16)v.y; h[2] = (f16)v.z; h[3] = (f16)v.w;
    *reinterpret_cast<f16x4*>(wo_h + 4*(size_t)i) = h;
  }
}

// ---------------- GEMM: C[M,N] = A[M,K] · B[N,K]^T  (NT, plain fp16) -------------
// 128x128 tile, 4 waves 2x2 (each 64x64, 16 MFMA per 8 ds_reads per K-step).
template<bool F32_OUT, bool COLCHUNK>
__global__ __launch_bounds__(256, 4)
void gemm_nt(const f16* __restrict__ A, const f16* __restrict__ B,
             f16* __restrict__ Ch, float* __restrict__ Cf,
             int M, int N, int K)
{
  constexpr int STRIDE = 16384;       // 8KB A + 8KB B per buffer
  __shared__ __align__(16) char smem[2 * STRIDE];

  const int tid = threadIdx.x;
  const int w = tid >> 6, l = tid & 63;
  const int wr = (w >> 1) * 64;
  const int wc = (w & 1) * 64;

  const int gx = gridDim.x, gy = gridDim.y;
  const int nwg = gx * gy;
  const int flat = blockIdx.y * gx + blockIdx.x;
  const int swz = (flat & 7) * (nwg >> 3) + (flat >> 3);
  const int bxn = COLCHUNK ? (swz / gy) : (swz % gx);
  const int byn = COLCHUNK ? (swz % gy) : (swz / gx);
  const int bm = byn * 128, bn = bxn * 128;

  f32x4 acc[4][4] = {};

  const int rl = l >> 2;
  const int sc = 8 * ((l & 3) ^ ((l >> 3) & 3));   // pre-swizzled source chunk

  auto stage = [&](int kt) {
    char* dst = smem + (kt & 1) * STRIDE;
    const int k0 = kt * 32;
#pragma unroll
    for (int i = 0; i < 4; i++) {
      const int s = i * 4 + w;                     // 0..15
      const f16* base = (s < 8) ? A : B;
      const int row0 = (s < 8) ? (bm + s * 16) : (bn + (s - 8) * 16);
      gload16(base + (size_t)(row0 + rl) * K + k0 + sc,
              dst + ((s < 8) ? 0 : 8192) + (s & 7) * 1024);
    }
  };

  const int nkt = K >> 5;
  stage(0);

  for (int kt = 0; kt < nkt; kt++) {
    if (kt + 1 < nkt) {
      stage(kt + 1);
      asm volatile("s_waitcnt vmcnt(4)" ::: "memory");
    } else {
      asm volatile("s_waitcnt vmcnt(0)" ::: "memory");
    }
    __builtin_amdgcn_s_barrier();

    const char* buf = smem + (kt & 1) * STRIDE;
    const int ar = l & 15;
    const int ak = 16 * ((l >> 4) ^ ((ar >> 1) & 3));
    f16x8 a[4], b[4];
#pragma unroll
    for (int mi = 0; mi < 4; mi++)
      a[mi] = *(const f16x8*)(buf + (size_t)(wr + mi*16 + ar) * 64 + ak);
#pragma unroll
    for (int ni = 0; ni < 4; ni++)
      b[ni] = *(const f16x8*)(buf + 8192 + (size_t)(wc + ni*16 + ar) * 64 + ak);
    __builtin_amdgcn_s_setprio(1);
#pragma unroll
    for (int ni = 0; ni < 4; ni++)
#pragma unroll
      for (int mi = 0; mi < 4; mi++)
        acc[mi][ni] = MFMA16(a[mi], b[ni], acc[mi][ni], 0, 0, 0);
    __builtin_amdgcn_s_setprio(0);
    __builtin_amdgcn_s_barrier();
  }

  const int crow0 = bm + wr + (l >> 4) * 4;
  const int ccol0 = bn + wc + (l & 15);
#pragma unroll
  for (int mi = 0; mi < 4; mi++) {
#pragma unroll
    for (int ni = 0; ni < 4; ni++) {
#pragma unroll
      for (int j = 0; j < 4; j++) {
        size_t idx = (size_t)(crow0 + mi*16 + j) * N + (ccol0 + ni*16);
        float v = acc[mi][ni][j];
        if (F32_OUT) Cf[idx] = v;
        else         Ch[idx] = (f16)v;
      }
    }
  }
}

// ---------------- fused Q+K projection GEMM (split fp16, 2-barrier, R9) ----------
// Tile 128x64, BK=32, double-buffered (2x32KB LDS), counted vmcnt(8).
// A fragments amortize over BOTH Q and K MFMAs (16 ds_reads / 48 MFMA per
// wave-K-step). Measured 53us, ~39% of dense peak (structure ceiling).
__global__ __launch_bounds__(256, 2)
void gemm_qk(const f16* __restrict__ Ahi, const f16* __restrict__ Alo,
             const f16* __restrict__ Bqh, const f16* __restrict__ Bql,
             const f16* __restrict__ Bkh, const f16* __restrict__ Bkl,
             f16* __restrict__ Qh, f16* __restrict__ Qlo2,
             f16* __restrict__ Kh, f16* __restrict__ Klo2)
{
  constexpr int N = D_MODEL, K = D_MODEL;
  constexpr int STRIDE = 32768;
  __shared__ __align__(16) char smem[2 * STRIDE];
  // per buffer: Ahi 0 | Alo 8192 | Bqh 16384 | Bql 20480 | Bkh 24576 | Bkl 28672

  const int tid = threadIdx.x;
  const int w = tid >> 6, l = tid & 63;
  const int wr = (w >> 1) * 64;
  const int wc = (w & 1) * 32;

  const int flat = blockIdx.y * 16 + blockIdx.x;           // grid (16, 32)
  const int swz = (flat & 7) * 64 + (flat >> 3);           // XCD-chunked
  const int bm = (swz / 16) * 128, bn = (swz % 16) * 64;

  f32x4 accQ[4][2] = {}, accK[4][2] = {};

  const int srow = tid >> 2;
  const int schunk = 8 * (((tid & 3) ^ ((srow >> 1) & 3)));

  auto stage = [&](int kt) {
    char* dst = smem + (kt & 1) * STRIDE;
    const int k0 = kt * 32;
    const f16* ga = Ahi + (size_t)(bm + srow) * K + k0 + schunk;
    gload16(ga,        dst + (w << 10));
    gload16(ga + 64*K, dst + 4096 + (w << 10));
    const f16* gal = Alo + (size_t)(bm + srow) * K + k0 + schunk;
    gload16(gal,        dst + 8192 + (w << 10));
    gload16(gal + 64*K, dst + 12288 + (w << 10));
    const size_t bo = (size_t)(bn + srow) * K + k0 + schunk;
    gload16(Bqh + bo, dst + 16384 + (w << 10));
    gload16(Bql + bo, dst + 20480 + (w << 10));
    gload16(Bkh + bo, dst + 24576 + (w << 10));
    gload16(Bkl + bo, dst + 28672 + (w << 10));
  };

  const int nkt = K >> 5;   // 32
  stage(0);

  for (int kt = 0; kt < nkt; kt++) {
    if (kt + 1 < nkt) {
      stage(kt + 1);
      asm volatile("s_waitcnt vmcnt(8)" ::: "memory");
    } else {
      asm volatile("s_waitcnt vmcnt(0)" ::: "memory");
    }
    __builtin_amdgcn_s_barrier();

    const char* buf = smem + (kt & 1) * STRIDE;
    const int ar = (l & 15);
    const int ak = 16 * ((l >> 4) ^ ((ar >> 1) & 3));
    f16x8 a_hi[4], a_lo[4];
#pragma unroll
    for (int mi = 0; mi < 4; mi++) {
      a_hi[mi] = *(const f16x8*)(buf + (size_t)(wr + mi*16 + ar) * 64 + ak);
      a_lo[mi] = *(const f16x8*)(buf + 8192 + (size_t)(wr + mi*16 + ar) * 64 + ak);
    }
    __builtin_amdgcn_s_setprio(1);
#pragma unroll
    for (int ni = 0; ni < 2; ni++) {
      const int bo = (wc + ni*16 + ar) * 64 + ak;
      f16x8 bqh = *(const f16x8*)(buf + 16384 + bo);
      f16x8 bql = *(const f16x8*)(buf + 20480 + bo);
      f16x8 bkh = *(const f16x8*)(buf + 24576 + bo);
      f16x8 bkl = *(const f16x8*)(buf + 28672 + bo);
#pragma unroll
      for (int mi = 0; mi < 4; mi++) {
        accQ[mi][ni] = MFMA16(a_hi[mi], bqh, accQ[mi][ni], 0, 0, 0);
        accQ[mi][ni] = MFMA16(a_hi[mi], bql, accQ[mi][ni], 0, 0, 0);
        accQ[mi][ni] = MFMA16(a_lo[mi], bqh, accQ[mi][ni], 0, 0, 0);
        accK[mi][ni] = MFMA16(a_hi[mi], bkh, accK[mi][ni], 0, 0, 0);
        accK[mi][ni] = MFMA16(a_hi[mi], bkl, accK[mi][ni], 0, 0, 0);
        accK[mi][ni] = MFMA16(a_lo[mi], bkh, accK[mi][ni], 0, 0, 0);
      }
    }
    __builtin_amdgcn_s_setprio(0);
    __builtin_amdgcn_s_barrier();
  }

  const int crow0 = bm + wr + (l >> 4) * 4;
  const int ccol0 = bn + wc + (l & 15);
#pragma unroll
  for (int mi = 0; mi < 4; mi++) {
#pragma unroll
    for (int ni = 0; ni < 2; ni++) {
#pragma unroll
      for (int j = 0; j < 4; j++) {
        size_t idx = (size_t)(crow0 + mi*16 + j) * N + (ccol0 + ni*16);
        float qv = accQ[mi][ni][j];
        f16 qh = (f16)qv;
        Qh[idx] = qh;  Qlo2[idx] = (f16)(qv - (float)qh);
        float kv = accK[mi][ni][j];
        f16 kh = (f16)kv;
        Kh[idx] = kh;  Klo2[idx] = (f16)(kv - (float)kh);
      }
    }
  }
}

// ---------------- flash attention v7.1 (causal, uniform-duration pair blocks) --------
// Same as R9/R10, plus: phase-1 skip of fully-masked tiles (group A, last tile).
__global__ __launch_bounds__(512, 4)
void attn_kernel(const f16* __restrict__ Qhi, const f16* __restrict__ Qlo,
                 const f16* __restrict__ Khi, const f16* __restrict__ Klo,
                 const f16* __restrict__ VT, f16* __restrict__ Out)
{
  __shared__ __align__(16) char smem[49152];   // 4 x 12KB ring (+ merge reuse)

  const int tid = threadIdx.x, w = tid >> 6, l = tid & 63;
  const int g = l >> 4, q4 = l & 15;
  const int wi = w & 3, grp = w >> 2;
  const int flat = blockIdx.x;
  const int xcd = flat & 7, slot = flat >> 3;
  const int bh = xcd * 4 + (slot >> 4);
  const int c = slot & 15;
  const int b = bh >> 4, h = bh & 15;
  const int bS = b * SEQ;
  const size_t hoff = (size_t)h * 64;
  const int T  = 64 - 2 * c;
  const int P1 = 2 * c + 2;
  const int P2 = 31 - 2 * c;

  int qw = (grp ? (31 - c) : c) * 64 + wi * 16;

  f16x8 qh[2], ql[2];
  auto loadQ = [&]() {
#pragma unroll
    for (int ks = 0; ks < 2; ks++) {
      const size_t base = (size_t)(bS + qw + q4) * D_MODEL + hoff + ks * 32 + g * 8;
      qh[ks] = *(const f16x8*)(Qhi + base);
      ql[ks] = *(const f16x8*)(Qlo + base);
    }
  };
  loadQ();

  f32x4 o[4] = {};
  float m_run = -INFINITY, l_run = 0.f;

  const int k_src = 8 * ((l & 7) ^ (l >> 3));
  const int v_src = 8 * ((l & 3) ^ ((l >> 2) & 3));

  auto stage = [&](int t) {
    const int kv0 = t * 32;
    char* sb = smem + (t & 3) * 12288;
    if (w < 4) {
      const f16* src = (w < 2) ? Khi : Klo;
      char* dstc = sb + ((w < 2) ? 0 : 4096);
      const int wi2 = w & 1;
#pragma unroll
      for (int gi = 0; gi < 2; gi++) {
        const int sub = 2 * wi2 + gi;
        const int row = 8 * sub + (l >> 3);
        gload16(src + (size_t)(bS + kv0 + row) * D_MODEL + hoff + k_src,
                dstc + sub * 1024);
      }
    } else if (w < 6) {
      const int wi2 = w - 4;
#pragma unroll
      for (int gi = 0; gi < 2; gi++) {
        const int sub = 2 * wi2 + gi;
        const int drow = 16 * sub + (l >> 2);
        gload16(VT + (hoff + drow) * (size_t)NROWS + bS + kv0 + v_src,
                sb + 8192 + sub * 1024);
      }
    }
  };

  const int idx_lo = (q4 + 32 * (g & 1)) * 4;
  const int idx_hi = idx_lo + 64;
  const bool upper = (l >= 32);

  auto compute = [&](int t) {
    const char* sb = smem + (t & 3) * 12288;
    const int kv0 = t * 32;

    f32x4 s[2] = {};
    __builtin_amdgcn_s_setprio(1);
#pragma unroll
    for (int ni = 0; ni < 2; ni++) {
      const int row = ni * 16 + q4;
#pragma unroll
      for (int ks = 0; ks < 2; ks++) {
        const int boff = row * 128 + 16 * ((ks * 4 + g) ^ (row & 7));
        f16x8 kh8 = *(const f16x8*)(sb + boff);
        f16x8 kl8 = *(const f16x8*)(sb + 4096 + boff);
        s[ni] = MFMA16(kh8, qh[ks], s[ni], 0, 0, 0);
        s[ni] = MFMA16(kh8, ql[ks], s[ni], 0, 0, 0);
        s[ni] = MFMA16(kl8, qh[ks], s[ni], 0, 0, 0);
      }
    }
    __builtin_amdgcn_s_setprio(0);

    const bool need_mask = (kv0 + 31) > qw;
    const int q_abs = qw + q4;
    float p[2][4];
    float pm = -INFINITY;
#pragma unroll
    for (int ni = 0; ni < 2; ni++)
#pragma unroll
      for (int j = 0; j < 4; j++) {
        float v = s[ni][j];
        if (need_mask && (kv0 + ni * 16 + 4 * g + j) > q_abs) v = -INFINITY;
        p[ni][j] = v;
        pm = fmaxf(pm, v);
      }
    pm = fmaxf(pm, __shfl_xor(pm, 16));
    pm = fmaxf(pm, __shfl_xor(pm, 32));

    if (!__all(pm - m_run <= 8.0f)) {
      const float mn = fmaxf(m_run, pm);
      const float sc2 = __builtin_amdgcn_exp2f(m_run - mn);
      m_run = mn;
      l_run *= sc2;
#pragma unroll
      for (int nd = 0; nd < 4; nd++)
#pragma unroll
        for (int j = 0; j < 4; j++) o[nd][j] *= sc2;
    }
    float ps = 0.f;
#pragma unroll
    for (int ni = 0; ni < 2; ni++)
#pragma unroll
      for (int j = 0; j < 4; j++) {
        const float e = __builtin_amdgcn_exp2f(p[ni][j] - m_run);
        p[ni][j] = e;
        ps += e;
      }
    ps += __shfl_xor(ps, 16);
    ps += __shfl_xor(ps, 32);
    l_run += ps;

    const int pk0 = pkh2(p[0][0], p[0][1]);
    const int pk1 = pkh2(p[0][2], p[0][3]);
    const int pk2 = pkh2(p[1][0], p[1][1]);
    const int pk3 = pkh2(p[1][2], p[1][3]);
    const int b0l = __builtin_amdgcn_ds_bpermute(idx_lo, pk0);
    const int b2l = __builtin_amdgcn_ds_bpermute(idx_lo, pk2);
    const int b1l = __builtin_amdgcn_ds_bpermute(idx_lo, pk1);
    const int b3l = __builtin_amdgcn_ds_bpermute(idx_lo, pk3);
    const int b0h = __builtin_amdgcn_ds_bpermute(idx_hi, pk0);
    const int b2h = __builtin_amdgcn_ds_bpermute(idx_hi, pk2);
    const int b1h = __builtin_amdgcn_ds_bpermute(idx_hi, pk1);
    const int b3h = __builtin_amdgcn_ds_bpermute(idx_hi, pk3);
    union { int u[4]; f16x8 v; } pu;
    pu.u[0] = upper ? b2l : b0l;
    pu.u[1] = upper ? b3l : b1l;
    pu.u[2] = upper ? b2h : b0h;
    pu.u[3] = upper ? b3h : b1h;
    const f16x8 pa = pu.v;

    __builtin_amdgcn_s_setprio(1);
#pragma unroll
    for (int nd = 0; nd < 4; nd++) {
      const int d = nd * 16 + q4;
      f16x8 bv = *(const f16x8*)(sb + 8192 + d * 64 + 16 * (g ^ (d & 3)));
      o[nd] = MFMA16(bv, pa, o[nd], 0, 0, 0);
    }
    __builtin_amdgcn_s_setprio(0);
  };

  stage(0);
  stage(1);

  for (int t = 0; t < P1; t++) {
    stage(t + 2);
    asm volatile("s_waitcnt vmcnt(4)" ::: "memory");
    __builtin_amdgcn_s_barrier();
    if (32 * t <= qw + 15) compute(t);   // skip fully-masked tiles
    __builtin_amdgcn_s_barrier();
  }

  if (grp == 0) {
    const float inv = 1.0f / l_run;
    const size_t rowb = (size_t)(bS + qw + q4) * D_MODEL + hoff;
#pragma unroll
    for (int nd = 0; nd < 4; nd++) {
      f16x4 v;
#pragma unroll
      for (int j = 0; j < 4; j++) v[j] = (f16)(o[nd][j] * inv);
      *reinterpret_cast<f16x4*>(Out + rowb + nd * 16 + 4 * g) = v;
    }
    qw = (31 - c) * 64 + wi * 16;
    loadQ();
#pragma unroll
    for (int nd = 0; nd < 4; nd++)
#pragma unroll
      for (int j = 0; j < 4; j++) o[nd][j] = 0.f;
    m_run = -INFINITY;
    l_run = 0.f;
  }

  for (int j = 0; j < P2; j++) {
    const int u = P1 + 2 * j;
    const bool st = (u + 3) < T;
    if (st) { stage(u + 2); stage(u + 3); }
    if (st) asm volatile("s_waitcnt vmcnt(4)" ::: "memory");
    else    asm volatile("s_waitcnt vmcnt(0)" ::: "memory");
    __builtin_amdgcn_s_barrier();
    compute(u + grp);
    __builtin_amdgcn_s_barrier();
  }

  if (grp == 0) {
    float* mb = (float*)smem + wi * 1152 + l * 18;
#pragma unroll
    for (int nd = 0; nd < 4; nd++)
#pragma unroll
      for (int j = 0; j < 4; j++) mb[nd * 4 + j] = o[nd][j];
    mb[16] = m_run;
    mb[17] = l_run;
  }
  __syncthreads();
  if (grp == 1) {
    const float* mb = (const float*)smem + wi * 1152 + l * 18;
    const float m2 = mb[16], l2 = mb[17];
    const float mm = fmaxf(m_run, m2);
    const float a1 = __builtin_amdgcn_exp2f(m_run - mm);
    const float a2 = __builtin_amdgcn_exp2f(m2 - mm);
    const float inv = 1.0f / (l_run * a1 + l2 * a2);
    const size_t rowb = (size_t)(bS + qw + q4) * D_MODEL + hoff;
#pragma unroll
    for (int nd = 0; nd < 4; nd++) {
      f16x4 v;
#pragma unroll
      for (int j = 0; j < 4; j++)
        v[j] = (f16)((o[nd][j] * a1 + mb[nd * 4 + j] * a2) * inv);
      *reinterpret_cast<f16x4*>(Out + rowb + nd * 16 + 4 * g) = v;
    }
  }
}

// ---------------- launcher ----------------
extern "C" void kernel_launch(void* const* d_in, const int* in_sizes, int n_in,
                              void* d_out, int out_size, void* d_ws, size_t ws_size,
                              hipStream_t stream) {
  const float* x  = (const float*)d_in[0];
  const float* pq = (const float*)d_in[1];
  const float* pk = (const float*)d_in[2];
  const float* pv = (const float*)d_in[3];
  const float* po = (const float*)d_in[4];
  float* out = (float*)d_out;

  char* ws = (char*)d_ws;
  size_t off = 0;
  auto alloc = [&](size_t elems) {
    f16* p = (f16*)(ws + off);
    off += ((elems * 2 + 255) & ~(size_t)255);
    return p;
  };
  f16* x_hi  = alloc((size_t)NROWS * D_MODEL);
  f16* x_lo  = alloc((size_t)NROWS * D_MODEL);
  f16* wq_hi = alloc((size_t)D_MODEL * D_MODEL);
  f16* wq_lo = alloc((size_t)D_MODEL * D_MODEL);
  f16* wk_hi = alloc((size_t)D_MODEL * D_MODEL);
  f16* wk_lo = alloc((size_t)D_MODEL * D_MODEL);
  f16* wv_h  = alloc((size_t)D_MODEL * D_MODEL);
  f16* wo_h  = alloc((size_t)D_MODEL * D_MODEL);
  f16* q_hi  = alloc((size_t)NROWS * D_MODEL);
  f16* q_lo  = alloc((size_t)NROWS * D_MODEL);
  f16* k_hi  = alloc((size_t)NROWS * D_MODEL);
  f16* k_lo  = alloc((size_t)NROWS * D_MODEL);
  f16* vt    = alloc((size_t)NROWS * D_MODEL);   // VT[m][b*SEQ+s]
  f16* ao    = alloc((size_t)NROWS * D_MODEL);

  const int n4x = NROWS * D_MODEL / 4;
  const int n4w = D_MODEL * D_MODEL / 4;
  const float qscale = 0.125f * 1.44269504088896f;
  split4_kernel<<<n4x/256, 256, 0, stream>>>(x, x_hi, x_lo, n4x, 1.0f);
  prep_w_kernel<<<n4w/256, 256, 0, stream>>>(pq, pk, pv, po,
                                             wq_hi, wq_lo, wk_hi, wk_lo, wv_h, wo_h,
                                             n4w, qscale);

  // fused Q+K projection (2-barrier, R9 structure — 53us measured)
  gemm_qk<<<dim3(16, 32), 256, 0, stream>>>(x_hi, x_lo, wq_hi, wq_lo, wk_hi, wk_lo,
                                            q_hi, q_lo, k_hi, k_lo);
  // V projection with transposed output: VT[m][n] = sum_k wv[m][k] x[n][k]
  dim3 gv(NROWS/128, D_MODEL/128);  // (32, 8) col-chunked
  gemm_nt<false, true><<<gv, 256, 0, stream>>>(wv_h, x_hi, vt, nullptr, D_MODEL, NROWS, D_MODEL);

  attn_kernel<<<dim3(512), 512, 0, stream>>>(q_hi, q_lo, k_hi, k_lo, vt, ao);

  dim3 gg(D_MODEL/128, NROWS/128);  // (8, 32) row-chunked
  gemm_nt<true, false><<<gg, 256, 0, stream>>>(ao, wo_h, nullptr, out, NROWS, D_MODEL, D_MODEL);
}

// Round 12
// 166.065 us; speedup vs baseline: 1.5443x; 1.0240x over previous
//
#include <hip/hip_runtime.h>
#include <stdint.h>

#define D_MODEL 1024
#define SEQ     2048
#define NHEAD   16
#define BATCH   2
#define NROWS   (BATCH*SEQ)   // 4096

typedef _Float16 f16;
typedef _Float16 f16x8 __attribute__((ext_vector_type(8)));
typedef _Float16 f16x4 __attribute__((ext_vector_type(4)));
typedef __fp16   h16x2 __attribute__((ext_vector_type(2)));
typedef float    f32x4 __attribute__((ext_vector_type(4)));

#define MFMA16 __builtin_amdgcn_mfma_f32_16x16x32_f16

__device__ __forceinline__ void gload16(const void* g, void* l) {
  __builtin_amdgcn_global_load_lds(
      (const __attribute__((address_space(1))) void*)g,
      (__attribute__((address_space(3))) void*)l, 16, 0, 0);
}

__device__ __forceinline__ int pkh2(float a, float b) {
  union { h16x2 h; int i; } u;
  u.h = __builtin_amdgcn_cvt_pkrtz(a, b);
  return u.i;
}

// ---------------- convert / split kernels ----------------
__global__ void split4_kernel(const float* __restrict__ in, f16* __restrict__ hi,
                              f16* __restrict__ lo, int n4, float scale) {
  int i = blockIdx.x * blockDim.x + threadIdx.x;
  if (i >= n4) return;
  float4 v = reinterpret_cast<const float4*>(in)[i];
  v.x *= scale; v.y *= scale; v.z *= scale; v.w *= scale;
  f16x4 h, l4;
  h[0] = (f16)v.x; h[1] = (f16)v.y; h[2] = (f16)v.z; h[3] = (f16)v.w;
  l4[0] = (f16)(v.x - (float)h[0]);
  l4[1] = (f16)(v.y - (float)h[1]);
  l4[2] = (f16)(v.z - (float)h[2]);
  l4[3] = (f16)(v.w - (float)h[3]);
  *reinterpret_cast<f16x4*>(hi + 4*(size_t)i) = h;
  *reinterpret_cast<f16x4*>(lo + 4*(size_t)i) = l4;
}

// fused weight prep: wq split (scaled), wk split, wv cvt, wo cvt — one pass
__global__ void prep_w_kernel(const float* __restrict__ pq, const float* __restrict__ pk,
                              const float* __restrict__ pv, const float* __restrict__ po,
                              f16* __restrict__ wq_hi, f16* __restrict__ wq_lo,
                              f16* __restrict__ wk_hi, f16* __restrict__ wk_lo,
                              f16* __restrict__ wv_h,  f16* __restrict__ wo_h,
                              int n4, float qscale) {
  int i = blockIdx.x * blockDim.x + threadIdx.x;
  if (i >= n4) return;
  {
    float4 v = reinterpret_cast<const float4*>(pq)[i];
    v.x *= qscale; v.y *= qscale; v.z *= qscale; v.w *= qscale;
    f16x4 h, l4;
    h[0] = (f16)v.x; h[1] = (f16)v.y; h[2] = (f16)v.z; h[3] = (f16)v.w;
    l4[0] = (f16)(v.x - (float)h[0]); l4[1] = (f16)(v.y - (float)h[1]);
    l4[2] = (f16)(v.z - (float)h[2]); l4[3] = (f16)(v.w - (float)h[3]);
    *reinterpret_cast<f16x4*>(wq_hi + 4*(size_t)i) = h;
    *reinterpret_cast<f16x4*>(wq_lo + 4*(size_t)i) = l4;
  }
  {
    float4 v = reinterpret_cast<const float4*>(pk)[i];
    f16x4 h, l4;
    h[0] = (f16)v.x; h[1] = (f16)v.y; h[2] = (f16)v.z; h[3] = (f16)v.w;
    l4[0] = (f16)(v.x - (float)h[0]); l4[1] = (f16)(v.y - (float)h[1]);
    l4[2] = (f16)(v.z - (float)h[2]); l4[3] = (f16)(v.w - (float)h[3]);
    *reinterpret_cast<f16x4*>(wk_hi + 4*(size_t)i) = h;
    *reinterpret_cast<f16x4*>(wk_lo + 4*(size_t)i) = l4;
  }
  {
    float4 v = reinterpret_cast<const float4*>(pv)[i];
    f16x4 h;
    h[0] = (f16)v.x; h[1] = (f16)v.y; h[2] = (f16)v.z; h[3] = (f16)v.w;
    *reinterpret_cast<f16x4*>(wv_h + 4*(size_t)i) = h;
  }
  {
    float4 v = reinterpret_cast<const float4*>(po)[i];
    f16x4 h;
    h[0] = (f16)v.x; h[1] = (f16)v.y; h[2] = (f16)v.z; h[3] = (f16)v.w;
    *reinterpret_cast<f16x4*>(wo_h + 4*(size_t)i) = h;
  }
}

// ---------------- GEMM: C[M,N] = A[M,K] · B[N,K]^T  (NT, plain fp16) -------------
// R9 version: 128x64 tile, 512 blocks -> 2/CU (measured best for V/O shapes).
template<bool F32_OUT, bool COLCHUNK>
__global__ __launch_bounds__(256, 2)
void gemm_nt(const f16* __restrict__ Ahi,
             const f16* __restrict__ Bhi,
             f16* __restrict__ Chi, float* __restrict__ Cf,
             int M, int N, int K)
{
  constexpr int B_OFF  = 8192;
  constexpr int STRIDE = 12288;
  __shared__ __align__(16) char smem[2 * STRIDE];

  const int tid = threadIdx.x;
  const int w = tid >> 6, l = tid & 63;
  const int wr = (w >> 1) * 64;
  const int wc = (w & 1) * 32;

  const int gx = gridDim.x, gy = gridDim.y;
  const int nwg = gx * gy;
  const int flat = blockIdx.y * gx + blockIdx.x;
  const int swz = (flat & 7) * (nwg >> 3) + (flat >> 3);
  const int bxn = COLCHUNK ? (swz / gy) : (swz % gx);
  const int byn = COLCHUNK ? (swz % gy) : (swz / gx);
  const int bm = byn * 128, bn = bxn * 64;

  f32x4 acc[4][2] = {};

  const int srow = tid >> 2;
  const int schunk = 8 * (((tid & 3) ^ ((srow >> 1) & 3)));

  auto stage = [&](int kt) {
    char* dst = smem + (kt & 1) * STRIDE;
    const int k0 = kt * 32;
    const f16* ga = Ahi + (size_t)(bm + srow) * K + k0 + schunk;
    gload16(ga,        dst + (w << 10));
    gload16(ga + 64*K, dst + 4096 + (w << 10));
    const f16* gb = Bhi + (size_t)(bn + srow) * K + k0 + schunk;
    gload16(gb,        dst + B_OFF + (w << 10));
  };

  const int nkt = K >> 5;
  stage(0);

  for (int kt = 0; kt < nkt; kt++) {
    if (kt + 1 < nkt) {
      stage(kt + 1);
      asm volatile("s_waitcnt vmcnt(3)" ::: "memory");
    } else {
      asm volatile("s_waitcnt vmcnt(0)" ::: "memory");
    }
    __builtin_amdgcn_s_barrier();

    const char* buf = smem + (kt & 1) * STRIDE;
    const int ar = (l & 15);
    const int ak = 16 * ((l >> 4) ^ ((ar >> 1) & 3));
    f16x8 a_hi[4];
#pragma unroll
    for (int mi = 0; mi < 4; mi++)
      a_hi[mi] = *(const f16x8*)(buf + (size_t)(wr + mi*16 + ar) * 64 + ak);
    __builtin_amdgcn_s_setprio(1);
#pragma unroll
    for (int ni = 0; ni < 2; ni++) {
      f16x8 b_hi = *(const f16x8*)(buf + B_OFF + (size_t)(wc + ni*16 + ar) * 64 + ak);
#pragma unroll
      for (int mi = 0; mi < 4; mi++)
        acc[mi][ni] = MFMA16(a_hi[mi], b_hi, acc[mi][ni], 0, 0, 0);
    }
    __builtin_amdgcn_s_setprio(0);
    __builtin_amdgcn_s_barrier();
  }

  const int crow0 = bm + wr + (l >> 4) * 4;
  const int ccol0 = bn + wc + (l & 15);
#pragma unroll
  for (int mi = 0; mi < 4; mi++) {
#pragma unroll
    for (int ni = 0; ni < 2; ni++) {
#pragma unroll
      for (int j = 0; j < 4; j++) {
        size_t idx = (size_t)(crow0 + mi*16 + j) * N + (ccol0 + ni*16);
        float v = acc[mi][ni][j];
        if (F32_OUT) Cf[idx] = v;
        else         Chi[idx] = (f16)v;
      }
    }
  }
}

// ---------------- fused Q+K projection GEMM (split fp16, 2-barrier, R9) ----------
__global__ __launch_bounds__(256, 2)
void gemm_qk(const f16* __restrict__ Ahi, const f16* __restrict__ Alo,
             const f16* __restrict__ Bqh, const f16* __restrict__ Bql,
             const f16* __restrict__ Bkh, const f16* __restrict__ Bkl,
             f16* __restrict__ Qh, f16* __restrict__ Qlo2,
             f16* __restrict__ Kh, f16* __restrict__ Klo2)
{
  constexpr int N = D_MODEL, K = D_MODEL;
  constexpr int STRIDE = 32768;
  __shared__ __align__(16) char smem[2 * STRIDE];

  const int tid = threadIdx.x;
  const int w = tid >> 6, l = tid & 63;
  const int wr = (w >> 1) * 64;
  const int wc = (w & 1) * 32;

  const int flat = blockIdx.y * 16 + blockIdx.x;           // grid (16, 32)
  const int swz = (flat & 7) * 64 + (flat >> 3);           // XCD-chunked
  const int bm = (swz / 16) * 128, bn = (swz % 16) * 64;

  f32x4 accQ[4][2] = {}, accK[4][2] = {};

  const int srow = tid >> 2;
  const int schunk = 8 * (((tid & 3) ^ ((srow >> 1) & 3)));

  auto stage = [&](int kt) {
    char* dst = smem + (kt & 1) * STRIDE;
    const int k0 = kt * 32;
    const f16* ga = Ahi + (size_t)(bm + srow) * K + k0 + schunk;
    gload16(ga,        dst + (w << 10));
    gload16(ga + 64*K, dst + 4096 + (w << 10));
    const f16* gal = Alo + (size_t)(bm + srow) * K + k0 + schunk;
    gload16(gal,        dst + 8192 + (w << 10));
    gload16(gal + 64*K, dst + 12288 + (w << 10));
    const size_t bo = (size_t)(bn + srow) * K + k0 + schunk;
    gload16(Bqh + bo, dst + 16384 + (w << 10));
    gload16(Bql + bo, dst + 20480 + (w << 10));
    gload16(Bkh + bo, dst + 24576 + (w << 10));
    gload16(Bkl + bo, dst + 28672 + (w << 10));
  };

  const int nkt = K >> 5;   // 32
  stage(0);

  for (int kt = 0; kt < nkt; kt++) {
    if (kt + 1 < nkt) {
      stage(kt + 1);
      asm volatile("s_waitcnt vmcnt(8)" ::: "memory");
    } else {
      asm volatile("s_waitcnt vmcnt(0)" ::: "memory");
    }
    __builtin_amdgcn_s_barrier();

    const char* buf = smem + (kt & 1) * STRIDE;
    const int ar = (l & 15);
    const int ak = 16 * ((l >> 4) ^ ((ar >> 1) & 3));
    f16x8 a_hi[4], a_lo[4];
#pragma unroll
    for (int mi = 0; mi < 4; mi++) {
      a_hi[mi] = *(const f16x8*)(buf + (size_t)(wr + mi*16 + ar) * 64 + ak);
      a_lo[mi] = *(const f16x8*)(buf + 8192 + (size_t)(wr + mi*16 + ar) * 64 + ak);
    }
    __builtin_amdgcn_s_setprio(1);
#pragma unroll
    for (int ni = 0; ni < 2; ni++) {
      const int bo = (wc + ni*16 + ar) * 64 + ak;
      f16x8 bqh = *(const f16x8*)(buf + 16384 + bo);
      f16x8 bql = *(const f16x8*)(buf + 20480 + bo);
      f16x8 bkh = *(const f16x8*)(buf + 24576 + bo);
      f16x8 bkl = *(const f16x8*)(buf + 28672 + bo);
#pragma unroll
      for (int mi = 0; mi < 4; mi++) {
        accQ[mi][ni] = MFMA16(a_hi[mi], bqh, accQ[mi][ni], 0, 0, 0);
        accQ[mi][ni] = MFMA16(a_hi[mi], bql, accQ[mi][ni], 0, 0, 0);
        accQ[mi][ni] = MFMA16(a_lo[mi], bqh, accQ[mi][ni], 0, 0, 0);
        accK[mi][ni] = MFMA16(a_hi[mi], bkh, accK[mi][ni], 0, 0, 0);
        accK[mi][ni] = MFMA16(a_hi[mi], bkl, accK[mi][ni], 0, 0, 0);
        accK[mi][ni] = MFMA16(a_lo[mi], bkh, accK[mi][ni], 0, 0, 0);
      }
    }
    __builtin_amdgcn_s_setprio(0);
    __builtin_amdgcn_s_barrier();
  }

  const int crow0 = bm + wr + (l >> 4) * 4;
  const int ccol0 = bn + wc + (l & 15);
#pragma unroll
  for (int mi = 0; mi < 4; mi++) {
#pragma unroll
    for (int ni = 0; ni < 2; ni++) {
#pragma unroll
      for (int j = 0; j < 4; j++) {
        size_t idx = (size_t)(crow0 + mi*16 + j) * N + (ccol0 + ni*16);
        float qv = accQ[mi][ni][j];
        f16 qh = (f16)qv;
        Qh[idx] = qh;  Qlo2[idx] = (f16)(qv - (float)qh);
        float kv = accK[mi][ni][j];
        f16 kh = (f16)kv;
        Kh[idx] = kh;  Klo2[idx] = (f16)(kv - (float)kh);
      }
    }
  }
}

// ---------------- flash attention v8 (pair blocks, hybrid KVBLK) -----------------
// Block = q-tile pair (c, 31-c); waves 0-3 = group A (tile c), 4-7 = group B.
// Phase 1 (KVBLK=64, c+1 iters): both groups compute the same 64-kv tile
//   (24KB: Khi 8K | Klo 8K | VT 8K; double buffer at 0/24576).
// Transition: A writes output, reloads Q for B rows, resets state.
// Phase 2 (KVBLK=32, v7 verbatim): A = even tiles, B = odd (ring 4 x 12KB);
//   (m,l,o) merged via LDS at the end.
__global__ __launch_bounds__(512, 4)
void attn_kernel(const f16* __restrict__ Qhi, const f16* __restrict__ Qlo,
                 const f16* __restrict__ Khi, const f16* __restrict__ Klo,
                 const f16* __restrict__ VT, f16* __restrict__ Out)
{
  __shared__ __align__(16) char smem[49152];

  const int tid = threadIdx.x, w = tid >> 6, l = tid & 63;
  const int g = l >> 4, q4 = l & 15;
  const int wi = w & 3, grp = w >> 2;
  const int flat = blockIdx.x;
  const int xcd = flat & 7, slot = flat >> 3;
  const int bh = xcd * 4 + (slot >> 4);        // 4 heads resident per XCD
  const int c = slot & 15;
  const int b = bh >> 4, h = bh & 15;
  const int bS = b * SEQ;
  const size_t hoff = (size_t)h * 64;
  const int T  = 64 - 2 * c;                   // total 32-tiles for B rows
  const int P1 = 2 * c + 2;                    // phase-2 start (32-units)
  const int P2 = 31 - 2 * c;                   // phase-2 iterations

  int qw = (grp ? (31 - c) : c) * 64 + wi * 16;

  f16x8 qh[2], ql[2];
  auto loadQ = [&]() {
#pragma unroll
    for (int ks = 0; ks < 2; ks++) {
      const size_t base = (size_t)(bS + qw + q4) * D_MODEL + hoff + ks * 32 + g * 8;
      qh[ks] = *(const f16x8*)(Qhi + base);
      ql[ks] = *(const f16x8*)(Qlo + base);
    }
  };
  loadQ();

  f32x4 o[4] = {};
  float m_run = -INFINITY, l_run = 0.f;

  const int k_src = 8 * ((l & 7) ^ (l >> 3));          // 128B rows: chunk ^ (row&7)
  const int v_src = 8 * ((l & 3) ^ ((l >> 2) & 3));    // 64B rows: chunk ^ (drow&3)
  const int rowloc = w * 8 + (l >> 3);                 // phase-1 staging row

  // P^T redistribution constants
  const int idx_lo = (q4 + 32 * (g & 1)) * 4;
  const int idx_hi = idx_lo + 64;
  const bool upper = (l >= 32);

  // ---------- phase-1 staging/compute (KVBLK=64, v6-verified bodies) ----------
  auto stage64 = [&](int t) {                  // t in 64-kv units
    const int kv0 = t * 64;
    char* dst = smem + (t & 1) * 24576;
    const size_t krow = (size_t)(bS + kv0 + rowloc) * D_MODEL + hoff + k_src;
    gload16(Khi + krow, dst + (w << 10));
    gload16(Klo + krow, dst + 8192 + (w << 10));
    const size_t vrow = (hoff + rowloc) * (size_t)NROWS + bS + kv0 + k_src;
    gload16(VT + vrow, dst + 16384 + (w << 10));
  };

  auto compute64 = [&](int t) {
    const char* buf = smem + (t & 1) * 24576;
    const int kv0 = t * 64;

    f32x4 s[4] = {};
    __builtin_amdgcn_s_setprio(1);
#pragma unroll
    for (int ni = 0; ni < 4; ni++) {
      const int row = ni * 16 + q4;
#pragma unroll
      for (int ks = 0; ks < 2; ks++) {
        const int boff = row * 128 + 16 * ((ks * 4 + g) ^ (row & 7));
        f16x8 kh8 = *(const f16x8*)(buf + boff);
        f16x8 kl8 = *(const f16x8*)(buf + 8192 + boff);
        s[ni] = MFMA16(kh8, qh[ks], s[ni], 0, 0, 0);
        s[ni] = MFMA16(kh8, ql[ks], s[ni], 0, 0, 0);
        s[ni] = MFMA16(kl8, qh[ks], s[ni], 0, 0, 0);
      }
    }
    __builtin_amdgcn_s_setprio(0);

    const bool need_mask = (kv0 + 63) > qw;
    const int q_abs = qw + q4;
    float p[4][4];
    float pm = -INFINITY;
#pragma unroll
    for (int ni = 0; ni < 4; ni++)
#pragma unroll
      for (int j = 0; j < 4; j++) {
        float v = s[ni][j];
        if (need_mask && (kv0 + ni * 16 + 4 * g + j) > q_abs) v = -INFINITY;
        p[ni][j] = v;
        pm = fmaxf(pm, v);
      }
    pm = fmaxf(pm, __shfl_xor(pm, 16));
    pm = fmaxf(pm, __shfl_xor(pm, 32));

    if (!__all(pm - m_run <= 8.0f)) {
      const float mn = fmaxf(m_run, pm);
      const float sc2 = __builtin_amdgcn_exp2f(m_run - mn);
      m_run = mn;
      l_run *= sc2;
#pragma unroll
      for (int nd = 0; nd < 4; nd++)
#pragma unroll
        for (int j = 0; j < 4; j++) o[nd][j] *= sc2;
    }
    float ps = 0.f;
#pragma unroll
    for (int ni = 0; ni < 4; ni++)
#pragma unroll
      for (int j = 0; j < 4; j++) {
        const float e = __builtin_amdgcn_exp2f(p[ni][j] - m_run);
        p[ni][j] = e;
        ps += e;
      }
    ps += __shfl_xor(ps, 16);
    ps += __shfl_xor(ps, 32);
    l_run += ps;

    f16x8 pa[2];
#pragma unroll
    for (int h2 = 0; h2 < 2; h2++) {
      const int pk0 = pkh2(p[2*h2][0],   p[2*h2][1]);
      const int pk1 = pkh2(p[2*h2][2],   p[2*h2][3]);
      const int pk2 = pkh2(p[2*h2+1][0], p[2*h2+1][1]);
      const int pk3 = pkh2(p[2*h2+1][2], p[2*h2+1][3]);
      const int b0l = __builtin_amdgcn_ds_bpermute(idx_lo, pk0);
      const int b2l = __builtin_amdgcn_ds_bpermute(idx_lo, pk2);
      const int b1l = __builtin_amdgcn_ds_bpermute(idx_lo, pk1);
      const int b3l = __builtin_amdgcn_ds_bpermute(idx_lo, pk3);
      const int b0h = __builtin_amdgcn_ds_bpermute(idx_hi, pk0);
      const int b2h = __builtin_amdgcn_ds_bpermute(idx_hi, pk2);
      const int b1h = __builtin_amdgcn_ds_bpermute(idx_hi, pk1);
      const int b3h = __builtin_amdgcn_ds_bpermute(idx_hi, pk3);
      union { int u[4]; f16x8 v; } pu;
      pu.u[0] = upper ? b2l : b0l;
      pu.u[1] = upper ? b3l : b1l;
      pu.u[2] = upper ? b2h : b0h;
      pu.u[3] = upper ? b3h : b1h;
      pa[h2] = pu.v;
    }

    __builtin_amdgcn_s_setprio(1);
#pragma unroll
    for (int nd = 0; nd < 4; nd++) {
      const int d = nd * 16 + q4;
#pragma unroll
      for (int h2 = 0; h2 < 2; h2++) {
        f16x8 bv = *(const f16x8*)(buf + 16384 + d * 128 + 16 * ((h2 * 4 + g) ^ (d & 7)));
        o[nd] = MFMA16(bv, pa[h2], o[nd], 0, 0, 0);
      }
    }
    __builtin_amdgcn_s_setprio(0);
  };

  // ---------- phase-2 staging/compute (KVBLK=32, v7 verbatim) ----------
  auto stage32 = [&](int t) {                  // t in 32-kv units
    const int kv0 = t * 32;
    char* sb = smem + (t & 3) * 12288;
    if (w < 4) {
      const f16* src = (w < 2) ? Khi : Klo;
      char* dstc = sb + ((w < 2) ? 0 : 4096);
      const int wi2 = w & 1;
#pragma unroll
      for (int gi = 0; gi < 2; gi++) {
        const int sub = 2 * wi2 + gi;
        const int row = 8 * sub + (l >> 3);
        gload16(src + (size_t)(bS + kv0 + row) * D_MODEL + hoff + k_src,
                dstc + sub * 1024);
      }
    } else if (w < 6) {
      const int wi2 = w - 4;
#pragma unroll
      for (int gi = 0; gi < 2; gi++) {
        const int sub = 2 * wi2 + gi;
        const int drow = 16 * sub + (l >> 2);
        gload16(VT + (hoff + drow) * (size_t)NROWS + bS + kv0 + v_src,
                sb + 8192 + sub * 1024);
      }
    }
  };

  auto compute32 = [&](int t) {
    const char* sb = smem + (t & 3) * 12288;
    const int kv0 = t * 32;

    f32x4 s[2] = {};
    __builtin_amdgcn_s_setprio(1);
#pragma unroll
    for (int ni = 0; ni < 2; ni++) {
      const int row = ni * 16 + q4;
#pragma unroll
      for (int ks = 0; ks < 2; ks++) {
        const int boff = row * 128 + 16 * ((ks * 4 + g) ^ (row & 7));
        f16x8 kh8 = *(const f16x8*)(sb + boff);
        f16x8 kl8 = *(const f16x8*)(sb + 4096 + boff);
        s[ni] = MFMA16(kh8, qh[ks], s[ni], 0, 0, 0);
        s[ni] = MFMA16(kh8, ql[ks], s[ni], 0, 0, 0);
        s[ni] = MFMA16(kl8, qh[ks], s[ni], 0, 0, 0);
      }
    }
    __builtin_amdgcn_s_setprio(0);

    const bool need_mask = (kv0 + 31) > qw;
    const int q_abs = qw + q4;
    float p[2][4];
    float pm = -INFINITY;
#pragma unroll
    for (int ni = 0; ni < 2; ni++)
#pragma unroll
      for (int j = 0; j < 4; j++) {
        float v = s[ni][j];
        if (need_mask && (kv0 + ni * 16 + 4 * g + j) > q_abs) v = -INFINITY;
        p[ni][j] = v;
        pm = fmaxf(pm, v);
      }
    pm = fmaxf(pm, __shfl_xor(pm, 16));
    pm = fmaxf(pm, __shfl_xor(pm, 32));

    if (!__all(pm - m_run <= 8.0f)) {
      const float mn = fmaxf(m_run, pm);
      const float sc2 = __builtin_amdgcn_exp2f(m_run - mn);
      m_run = mn;
      l_run *= sc2;
#pragma unroll
      for (int nd = 0; nd < 4; nd++)
#pragma unroll
        for (int j = 0; j < 4; j++) o[nd][j] *= sc2;
    }
    float ps = 0.f;
#pragma unroll
    for (int ni = 0; ni < 2; ni++)
#pragma unroll
      for (int j = 0; j < 4; j++) {
        const float e = __builtin_amdgcn_exp2f(p[ni][j] - m_run);
        p[ni][j] = e;
        ps += e;
      }
    ps += __shfl_xor(ps, 16);
    ps += __shfl_xor(ps, 32);
    l_run += ps;

    const int pk0 = pkh2(p[0][0], p[0][1]);
    const int pk1 = pkh2(p[0][2], p[0][3]);
    const int pk2 = pkh2(p[1][0], p[1][1]);
    const int pk3 = pkh2(p[1][2], p[1][3]);
    const int b0l = __builtin_amdgcn_ds_bpermute(idx_lo, pk0);
    const int b2l = __builtin_amdgcn_ds_bpermute(idx_lo, pk2);
    const int b1l = __builtin_amdgcn_ds_bpermute(idx_lo, pk1);
    const int b3l = __builtin_amdgcn_ds_bpermute(idx_lo, pk3);
    const int b0h = __builtin_amdgcn_ds_bpermute(idx_hi, pk0);
    const int b2h = __builtin_amdgcn_ds_bpermute(idx_hi, pk2);
    const int b1h = __builtin_amdgcn_ds_bpermute(idx_hi, pk1);
    const int b3h = __builtin_amdgcn_ds_bpermute(idx_hi, pk3);
    union { int u[4]; f16x8 v; } pu;
    pu.u[0] = upper ? b2l : b0l;
    pu.u[1] = upper ? b3l : b1l;
    pu.u[2] = upper ? b2h : b0h;
    pu.u[3] = upper ? b3h : b1h;
    const f16x8 pa = pu.v;

    __builtin_amdgcn_s_setprio(1);
#pragma unroll
    for (int nd = 0; nd < 4; nd++) {
      const int d = nd * 16 + q4;
      f16x8 bv = *(const f16x8*)(sb + 8192 + d * 64 + 16 * (g ^ (d & 3)));
      o[nd] = MFMA16(bv, pa, o[nd], 0, 0, 0);
    }
    __builtin_amdgcn_s_setprio(0);
  };

  // ---------- phase 1: KVBLK=64, tiles 0..c, both groups ----------
  stage64(0);
  for (int t = 0; t <= c; t++) {
    if (t + 1 <= c) {
      stage64(t + 1);
      asm volatile("s_waitcnt vmcnt(3)" ::: "memory");
    } else {
      asm volatile("s_waitcnt vmcnt(0)" ::: "memory");
    }
    __builtin_amdgcn_s_barrier();
    compute64(t);
    __builtin_amdgcn_s_barrier();
  }

  // ---------- transition: A writes output, switches to B rows ----------
  if (grp == 0) {
    const float inv = 1.0f / l_run;
    const size_t rowb = (size_t)(bS + qw + q4) * D_MODEL + hoff;
#pragma unroll
    for (int nd = 0; nd < 4; nd++) {
      f16x4 v;
#pragma unroll
      for (int j = 0; j < 4; j++) v[j] = (f16)(o[nd][j] * inv);
      *reinterpret_cast<f16x4*>(Out + rowb + nd * 16 + 4 * g) = v;
    }
    qw = (31 - c) * 64 + wi * 16;
    loadQ();
#pragma unroll
    for (int nd = 0; nd < 4; nd++)
#pragma unroll
      for (int j = 0; j < 4; j++) o[nd][j] = 0.f;
    m_run = -INFINITY;
    l_run = 0.f;
  }

  // ---------- phase 2: KVBLK=32, A = even, B = odd ----------
  stage32(P1);
  stage32(P1 + 1);
  for (int j = 0; j < P2; j++) {
    const int u = P1 + 2 * j;
    const bool st = (u + 3) < T;
    if (st) { stage32(u + 2); stage32(u + 3); }
    if (st) asm volatile("s_waitcnt vmcnt(4)" ::: "memory");
    else    asm volatile("s_waitcnt vmcnt(0)" ::: "memory");
    __builtin_amdgcn_s_barrier();
    compute32(u + grp);
    __builtin_amdgcn_s_barrier();
  }

  // ---------- merge A's phase-2 partial into B's state, write B ----------
  if (grp == 0) {
    float* mb = (float*)smem + wi * 1152 + l * 18;
#pragma unroll
    for (int nd = 0; nd < 4; nd++)
#pragma unroll
      for (int j = 0; j < 4; j++) mb[nd * 4 + j] = o[nd][j];
    mb[16] = m_run;
    mb[17] = l_run;
  }
  __syncthreads();
  if (grp == 1) {
    const float* mb = (const float*)smem + wi * 1152 + l * 18;
    const float m2 = mb[16], l2 = mb[17];
    const float mm = fmaxf(m_run, m2);
    const float a1 = __builtin_amdgcn_exp2f(m_run - mm);
    const float a2 = __builtin_amdgcn_exp2f(m2 - mm);
    const float inv = 1.0f / (l_run * a1 + l2 * a2);
    const size_t rowb = (size_t)(bS + qw + q4) * D_MODEL + hoff;
#pragma unroll
    for (int nd = 0; nd < 4; nd++) {
      f16x4 v;
#pragma unroll
      for (int j = 0; j < 4; j++)
        v[j] = (f16)((o[nd][j] * a1 + mb[nd * 4 + j] * a2) * inv);
      *reinterpret_cast<f16x4*>(Out + rowb + nd * 16 + 4 * g) = v;
    }
  }
}

// ---------------- launcher ----------------
extern "C" void kernel_launch(void* const* d_in, const int* in_sizes, int n_in,
                              void* d_out, int out_size, void* d_ws, size_t ws_size,
                              hipStream_t stream) {
  const float* x  = (const float*)d_in[0];
  const float* pq = (const float*)d_in[1];
  const float* pk = (const float*)d_in[2];
  const float* pv = (const float*)d_in[3];
  const float* po = (const float*)d_in[4];
  float* out = (float*)d_out;

  char* ws = (char*)d_ws;
  size_t off = 0;
  auto alloc = [&](size_t elems) {
    f16* p = (f16*)(ws + off);
    off += ((elems * 2 + 255) & ~(size_t)255);
    return p;
  };
  f16* x_hi  = alloc((size_t)NROWS * D_MODEL);
  f16* x_lo  = alloc((size_t)NROWS * D_MODEL);
  f16* wq_hi = alloc((size_t)D_MODEL * D_MODEL);
  f16* wq_lo = alloc((size_t)D_MODEL * D_MODEL);
  f16* wk_hi = alloc((size_t)D_MODEL * D_MODEL);
  f16* wk_lo = alloc((size_t)D_MODEL * D_MODEL);
  f16* wv_h  = alloc((size_t)D_MODEL * D_MODEL);
  f16* wo_h  = alloc((size_t)D_MODEL * D_MODEL);
  f16* q_hi  = alloc((size_t)NROWS * D_MODEL);
  f16* q_lo  = alloc((size_t)NROWS * D_MODEL);
  f16* k_hi  = alloc((size_t)NROWS * D_MODEL);
  f16* k_lo  = alloc((size_t)NROWS * D_MODEL);
  f16* vt    = alloc((size_t)NROWS * D_MODEL);   // VT[m][b*SEQ+s]
  f16* ao    = alloc((size_t)NROWS * D_MODEL);

  const int n4x = NROWS * D_MODEL / 4;
  const int n4w = D_MODEL * D_MODEL / 4;
  const float qscale = 0.125f * 1.44269504088896f;
  split4_kernel<<<n4x/256, 256, 0, stream>>>(x, x_hi, x_lo, n4x, 1.0f);
  prep_w_kernel<<<n4w/256, 256, 0, stream>>>(pq, pk, pv, po,
                                             wq_hi, wq_lo, wk_hi, wk_lo, wv_h, wo_h,
                                             n4w, qscale);

  // fused Q+K projection (2-barrier, measured ~53-55us)
  gemm_qk<<<dim3(16, 32), 256, 0, stream>>>(x_hi, x_lo, wq_hi, wq_lo, wk_hi, wk_lo,
                                            q_hi, q_lo, k_hi, k_lo);
  // V projection with transposed output: VT[m][n] = sum_k wv[m][k] x[n][k]
  dim3 gv(NROWS/64, D_MODEL/128);  // (64, 8) col-chunked, 512 blocks
  gemm_nt<false, true><<<gv, 256, 0, stream>>>(wv_h, x_hi, vt, nullptr, D_MODEL, NROWS, D_MODEL);

  attn_kernel<<<dim3(512), 512, 0, stream>>>(q_hi, q_lo, k_hi, k_lo, vt, ao);

  dim3 gg(D_MODEL/64, NROWS/128);  // (16, 32) row-chunked, 512 blocks
  gemm_nt<true, false><<<gg, 256, 0, stream>>>(ao, wo_h, nullptr, out, NROWS, D_MODEL, D_MODEL);
}

// Round 13
// 157.045 us; speedup vs baseline: 1.6330x; 1.0574x over previous
//
#include <hip/hip_runtime.h>
#include <stdint.h>

#define D_MODEL 1024
#define SEQ     2048
#define NHEAD   16
#define BATCH   2
#define NROWS   (BATCH*SEQ)   // 4096

typedef _Float16 f16;
typedef _Float16 f16x8 __attribute__((ext_vector_type(8)));
typedef _Float16 f16x4 __attribute__((ext_vector_type(4)));
typedef __fp16   h16x2 __attribute__((ext_vector_type(2)));
typedef float    f32x4 __attribute__((ext_vector_type(4)));

#define MFMA16 __builtin_amdgcn_mfma_f32_16x16x32_f16

__device__ __forceinline__ void gload16(const void* g, void* l) {
  __builtin_amdgcn_global_load_lds(
      (const __attribute__((address_space(1))) void*)g,
      (__attribute__((address_space(3))) void*)l, 16, 0, 0);
}

__device__ __forceinline__ int pkh2(float a, float b) {
  union { h16x2 h; int i; } u;
  u.h = __builtin_amdgcn_cvt_pkrtz(a, b);
  return u.i;
}

// ---------------- convert / split kernels ----------------
__global__ void split4_kernel(const float* __restrict__ in, f16* __restrict__ hi,
                              f16* __restrict__ lo, int n4, float scale) {
  int i = blockIdx.x * blockDim.x + threadIdx.x;
  if (i >= n4) return;
  float4 v = reinterpret_cast<const float4*>(in)[i];
  v.x *= scale; v.y *= scale; v.z *= scale; v.w *= scale;
  f16x4 h, l4;
  h[0] = (f16)v.x; h[1] = (f16)v.y; h[2] = (f16)v.z; h[3] = (f16)v.w;
  l4[0] = (f16)(v.x - (float)h[0]);
  l4[1] = (f16)(v.y - (float)h[1]);
  l4[2] = (f16)(v.z - (float)h[2]);
  l4[3] = (f16)(v.w - (float)h[3]);
  *reinterpret_cast<f16x4*>(hi + 4*(size_t)i) = h;
  *reinterpret_cast<f16x4*>(lo + 4*(size_t)i) = l4;
}

// fused weight prep: wq split (scaled), wk split, wv cvt, wo cvt — one pass
__global__ void prep_w_kernel(const float* __restrict__ pq, const float* __restrict__ pk,
                              const float* __restrict__ pv, const float* __restrict__ po,
                              f16* __restrict__ wq_hi, f16* __restrict__ wq_lo,
                              f16* __restrict__ wk_hi, f16* __restrict__ wk_lo,
                              f16* __restrict__ wv_h,  f16* __restrict__ wo_h,
                              int n4, float qscale) {
  int i = blockIdx.x * blockDim.x + threadIdx.x;
  if (i >= n4) return;
  {
    float4 v = reinterpret_cast<const float4*>(pq)[i];
    v.x *= qscale; v.y *= qscale; v.z *= qscale; v.w *= qscale;
    f16x4 h, l4;
    h[0] = (f16)v.x; h[1] = (f16)v.y; h[2] = (f16)v.z; h[3] = (f16)v.w;
    l4[0] = (f16)(v.x - (float)h[0]); l4[1] = (f16)(v.y - (float)h[1]);
    l4[2] = (f16)(v.z - (float)h[2]); l4[3] = (f16)(v.w - (float)h[3]);
    *reinterpret_cast<f16x4*>(wq_hi + 4*(size_t)i) = h;
    *reinterpret_cast<f16x4*>(wq_lo + 4*(size_t)i) = l4;
  }
  {
    float4 v = reinterpret_cast<const float4*>(pk)[i];
    f16x4 h, l4;
    h[0] = (f16)v.x; h[1] = (f16)v.y; h[2] = (f16)v.z; h[3] = (f16)v.w;
    l4[0] = (f16)(v.x - (float)h[0]); l4[1] = (f16)(v.y - (float)h[1]);
    l4[2] = (f16)(v.z - (float)h[2]); l4[3] = (f16)(v.w - (float)h[3]);
    *reinterpret_cast<f16x4*>(wk_hi + 4*(size_t)i) = h;
    *reinterpret_cast<f16x4*>(wk_lo + 4*(size_t)i) = l4;
  }
  {
    float4 v = reinterpret_cast<const float4*>(pv)[i];
    f16x4 h;
    h[0] = (f16)v.x; h[1] = (f16)v.y; h[2] = (f16)v.z; h[3] = (f16)v.w;
    *reinterpret_cast<f16x4*>(wv_h + 4*(size_t)i) = h;
  }
  {
    float4 v = reinterpret_cast<const float4*>(po)[i];
    f16x4 h;
    h[0] = (f16)v.x; h[1] = (f16)v.y; h[2] = (f16)v.z; h[3] = (f16)v.w;
    *reinterpret_cast<f16x4*>(wo_h + 4*(size_t)i) = h;
  }
}

// ---------------- GEMM: C[M,N] = A[M,K] · B[N,K]^T  (NT, plain fp16) -------------
// 128x64 tile, 512 blocks -> 2/CU (measured best). Used for the O projection.
template<bool F32_OUT, bool COLCHUNK>
__global__ __launch_bounds__(256, 2)
void gemm_nt(const f16* __restrict__ Ahi,
             const f16* __restrict__ Bhi,
             f16* __restrict__ Chi, float* __restrict__ Cf,
             int M, int N, int K)
{
  constexpr int B_OFF  = 8192;
  constexpr int STRIDE = 12288;
  __shared__ __align__(16) char smem[2 * STRIDE];

  const int tid = threadIdx.x;
  const int w = tid >> 6, l = tid & 63;
  const int wr = (w >> 1) * 64;
  const int wc = (w & 1) * 32;

  const int gx = gridDim.x, gy = gridDim.y;
  const int nwg = gx * gy;
  const int flat = blockIdx.y * gx + blockIdx.x;
  const int swz = (flat & 7) * (nwg >> 3) + (flat >> 3);
  const int bxn = COLCHUNK ? (swz / gy) : (swz % gx);
  const int byn = COLCHUNK ? (swz % gy) : (swz / gx);
  const int bm = byn * 128, bn = bxn * 64;

  f32x4 acc[4][2] = {};

  const int srow = tid >> 2;
  const int schunk = 8 * (((tid & 3) ^ ((srow >> 1) & 3)));

  auto stage = [&](int kt) {
    char* dst = smem + (kt & 1) * STRIDE;
    const int k0 = kt * 32;
    const f16* ga = Ahi + (size_t)(bm + srow) * K + k0 + schunk;
    gload16(ga,        dst + (w << 10));
    gload16(ga + 64*K, dst + 4096 + (w << 10));
    const f16* gb = Bhi + (size_t)(bn + srow) * K + k0 + schunk;
    gload16(gb,        dst + B_OFF + (w << 10));
  };

  const int nkt = K >> 5;
  stage(0);

  for (int kt = 0; kt < nkt; kt++) {
    if (kt + 1 < nkt) {
      stage(kt + 1);
      asm volatile("s_waitcnt vmcnt(3)" ::: "memory");
    } else {
      asm volatile("s_waitcnt vmcnt(0)" ::: "memory");
    }
    __builtin_amdgcn_s_barrier();

    const char* buf = smem + (kt & 1) * STRIDE;
    const int ar = (l & 15);
    const int ak = 16 * ((l >> 4) ^ ((ar >> 1) & 3));
    f16x8 a_hi[4];
#pragma unroll
    for (int mi = 0; mi < 4; mi++)
      a_hi[mi] = *(const f16x8*)(buf + (size_t)(wr + mi*16 + ar) * 64 + ak);
    __builtin_amdgcn_s_setprio(1);
#pragma unroll
    for (int ni = 0; ni < 2; ni++) {
      f16x8 b_hi = *(const f16x8*)(buf + B_OFF + (size_t)(wc + ni*16 + ar) * 64 + ak);
#pragma unroll
      for (int mi = 0; mi < 4; mi++)
        acc[mi][ni] = MFMA16(a_hi[mi], b_hi, acc[mi][ni], 0, 0, 0);
    }
    __builtin_amdgcn_s_setprio(0);
    __builtin_amdgcn_s_barrier();
  }

  const int crow0 = bm + wr + (l >> 4) * 4;
  const int ccol0 = bn + wc + (l & 15);
#pragma unroll
  for (int mi = 0; mi < 4; mi++) {
#pragma unroll
    for (int ni = 0; ni < 2; ni++) {
#pragma unroll
      for (int j = 0; j < 4; j++) {
        size_t idx = (size_t)(crow0 + mi*16 + j) * N + (ccol0 + ni*16);
        float v = acc[mi][ni][j];
        if (F32_OUT) Cf[idx] = v;
        else         Chi[idx] = (f16)v;
      }
    }
  }
}

// ---------------- fused Q+K+V projection GEMM ----------------
// A = x (hi/lo) [4096x1024]; Bq/Bk = wq/wk (hi/lo), Bv = wv (plain).
// Tile 128x64, BK=32, double-buffered (2x36KB LDS), counted vmcnt(9).
// Per wave-K-step: 18 ds_read_b128 / 56 MFMA (Q,K split = 3 each; V plain = 1).
// Q/K epilogue: direct [row][col] stores (with hi/lo re-split).
// V epilogue: transpose through LDS (aliasing the dead K-loop buffers) ->
// coalesced 16B stores into VT[m][n] (m = wv row, n = x row).
__global__ __launch_bounds__(256, 2)
void gemm_qkv(const f16* __restrict__ Ahi, const f16* __restrict__ Alo,
              const f16* __restrict__ Bqh, const f16* __restrict__ Bql,
              const f16* __restrict__ Bkh, const f16* __restrict__ Bkl,
              const f16* __restrict__ Bvh,
              f16* __restrict__ Qh, f16* __restrict__ Qlo2,
              f16* __restrict__ Kh, f16* __restrict__ Klo2,
              f16* __restrict__ VT)
{
  constexpr int N = D_MODEL, K = D_MODEL;
  constexpr int STRIDE = 36864;
  __shared__ __align__(16) char smem[2 * STRIDE];
  // per buffer: Ahi 0 | Alo 8192 | Bqh 16384 | Bql 20480 | Bkh 24576 |
  //             Bkl 28672 | Bvh 32768

  const int tid = threadIdx.x;
  const int w = tid >> 6, l = tid & 63;
  const int wr = (w >> 1) * 64;
  const int wc = (w & 1) * 32;

  const int flat = blockIdx.y * 16 + blockIdx.x;           // grid (16, 32)
  const int swz = (flat & 7) * 64 + (flat >> 3);           // XCD-chunked
  const int bm = (swz / 16) * 128, bn = (swz % 16) * 64;

  f32x4 accQ[4][2] = {}, accK[4][2] = {}, accV[4][2] = {};

  const int srow = tid >> 2;
  const int schunk = 8 * (((tid & 3) ^ ((srow >> 1) & 3)));

  auto stage = [&](int kt) {
    char* dst = smem + (kt & 1) * STRIDE;
    const int k0 = kt * 32;
    const f16* ga = Ahi + (size_t)(bm + srow) * K + k0 + schunk;
    gload16(ga,        dst + (w << 10));
    gload16(ga + 64*K, dst + 4096 + (w << 10));
    const f16* gal = Alo + (size_t)(bm + srow) * K + k0 + schunk;
    gload16(gal,        dst + 8192 + (w << 10));
    gload16(gal + 64*K, dst + 12288 + (w << 10));
    const size_t bo = (size_t)(bn + srow) * K + k0 + schunk;
    gload16(Bqh + bo, dst + 16384 + (w << 10));
    gload16(Bql + bo, dst + 20480 + (w << 10));
    gload16(Bkh + bo, dst + 24576 + (w << 10));
    gload16(Bkl + bo, dst + 28672 + (w << 10));
    gload16(Bvh + bo, dst + 32768 + (w << 10));
  };

  const int nkt = K >> 5;   // 32
  stage(0);

  for (int kt = 0; kt < nkt; kt++) {
    if (kt + 1 < nkt) {
      stage(kt + 1);
      asm volatile("s_waitcnt vmcnt(9)" ::: "memory");
    } else {
      asm volatile("s_waitcnt vmcnt(0)" ::: "memory");
    }
    __builtin_amdgcn_s_barrier();

    const char* buf = smem + (kt & 1) * STRIDE;
    const int ar = (l & 15);
    const int ak = 16 * ((l >> 4) ^ ((ar >> 1) & 3));
    f16x8 a_hi[4], a_lo[4];
#pragma unroll
    for (int mi = 0; mi < 4; mi++) {
      a_hi[mi] = *(const f16x8*)(buf + (size_t)(wr + mi*16 + ar) * 64 + ak);
      a_lo[mi] = *(const f16x8*)(buf + 8192 + (size_t)(wr + mi*16 + ar) * 64 + ak);
    }
    __builtin_amdgcn_s_setprio(1);
#pragma unroll
    for (int ni = 0; ni < 2; ni++) {
      const int bo = (wc + ni*16 + ar) * 64 + ak;
      f16x8 bqh = *(const f16x8*)(buf + 16384 + bo);
      f16x8 bql = *(const f16x8*)(buf + 20480 + bo);
      f16x8 bkh = *(const f16x8*)(buf + 24576 + bo);
      f16x8 bkl = *(const f16x8*)(buf + 28672 + bo);
      f16x8 bvh = *(const f16x8*)(buf + 32768 + bo);
#pragma unroll
      for (int mi = 0; mi < 4; mi++) {
        accQ[mi][ni] = MFMA16(a_hi[mi], bqh, accQ[mi][ni], 0, 0, 0);
        accQ[mi][ni] = MFMA16(a_hi[mi], bql, accQ[mi][ni], 0, 0, 0);
        accQ[mi][ni] = MFMA16(a_lo[mi], bqh, accQ[mi][ni], 0, 0, 0);
        accK[mi][ni] = MFMA16(a_hi[mi], bkh, accK[mi][ni], 0, 0, 0);
        accK[mi][ni] = MFMA16(a_hi[mi], bkl, accK[mi][ni], 0, 0, 0);
        accK[mi][ni] = MFMA16(a_lo[mi], bkh, accK[mi][ni], 0, 0, 0);
        accV[mi][ni] = MFMA16(a_hi[mi], bvh, accV[mi][ni], 0, 0, 0);
      }
    }
    __builtin_amdgcn_s_setprio(0);
    __builtin_amdgcn_s_barrier();
  }

  // ---- Q/K epilogue: direct stores with hi/lo re-split ----
  const int crow0 = bm + wr + (l >> 4) * 4;
  const int ccol0 = bn + wc + (l & 15);
#pragma unroll
  for (int mi = 0; mi < 4; mi++) {
#pragma unroll
    for (int ni = 0; ni < 2; ni++) {
#pragma unroll
      for (int j = 0; j < 4; j++) {
        size_t idx = (size_t)(crow0 + mi*16 + j) * N + (ccol0 + ni*16);
        float qv = accQ[mi][ni][j];
        f16 qh = (f16)qv;
        Qh[idx] = qh;  Qlo2[idx] = (f16)(qv - (float)qh);
        float kv = accK[mi][ni][j];
        f16 kh = (f16)kv;
        Kh[idx] = kh;  Klo2[idx] = (f16)(kv - (float)kh);
      }
    }
  }

  // ---- V epilogue: transpose through LDS, coalesced VT stores ----
  // LDS tile [64 m][pitch 136 f16]; K-loop buffers are dead (final barrier
  // above guarantees all ds_reads drained).
  {
    f16* tl = (f16*)smem;
#pragma unroll
    for (int mi = 0; mi < 4; mi++) {
#pragma unroll
      for (int ni = 0; ni < 2; ni++) {
        f16x4 v;
#pragma unroll
        for (int j = 0; j < 4; j++) v[j] = (f16)accV[mi][ni][j];
        const int m_l = wc + ni*16 + (l & 15);
        const int n_l = wr + mi*16 + ((l >> 4) << 2);
        *reinterpret_cast<f16x4*>(tl + m_l*136 + n_l) = v;
      }
    }
    __syncthreads();
    const int m_l = tid >> 2, cg = tid & 3;
    const size_t vbase = (size_t)(bn + m_l) * NROWS + bm + cg*32;
#pragma unroll
    for (int k2 = 0; k2 < 4; k2++) {
      f16x8 v = *reinterpret_cast<const f16x8*>(tl + m_l*136 + cg*32 + k2*8);
      *reinterpret_cast<f16x8*>(VT + vbase + k2*8) = v;
    }
  }
}

// ---------------- flash attention v8 (pair blocks, hybrid KVBLK) -----------------
// (byte-identical to round 12 — isolating the QKV fusion)
__global__ __launch_bounds__(512, 4)
void attn_kernel(const f16* __restrict__ Qhi, const f16* __restrict__ Qlo,
                 const f16* __restrict__ Khi, const f16* __restrict__ Klo,
                 const f16* __restrict__ VT, f16* __restrict__ Out)
{
  __shared__ __align__(16) char smem[49152];

  const int tid = threadIdx.x, w = tid >> 6, l = tid & 63;
  const int g = l >> 4, q4 = l & 15;
  const int wi = w & 3, grp = w >> 2;
  const int flat = blockIdx.x;
  const int xcd = flat & 7, slot = flat >> 3;
  const int bh = xcd * 4 + (slot >> 4);        // 4 heads resident per XCD
  const int c = slot & 15;
  const int b = bh >> 4, h = bh & 15;
  const int bS = b * SEQ;
  const size_t hoff = (size_t)h * 64;
  const int T  = 64 - 2 * c;                   // total 32-tiles for B rows
  const int P1 = 2 * c + 2;                    // phase-2 start (32-units)
  const int P2 = 31 - 2 * c;                   // phase-2 iterations

  int qw = (grp ? (31 - c) : c) * 64 + wi * 16;

  f16x8 qh[2], ql[2];
  auto loadQ = [&]() {
#pragma unroll
    for (int ks = 0; ks < 2; ks++) {
      const size_t base = (size_t)(bS + qw + q4) * D_MODEL + hoff + ks * 32 + g * 8;
      qh[ks] = *(const f16x8*)(Qhi + base);
      ql[ks] = *(const f16x8*)(Qlo + base);
    }
  };
  loadQ();

  f32x4 o[4] = {};
  float m_run = -INFINITY, l_run = 0.f;

  const int k_src = 8 * ((l & 7) ^ (l >> 3));          // 128B rows: chunk ^ (row&7)
  const int v_src = 8 * ((l & 3) ^ ((l >> 2) & 3));    // 64B rows: chunk ^ (drow&3)
  const int rowloc = w * 8 + (l >> 3);                 // phase-1 staging row

  // P^T redistribution constants
  const int idx_lo = (q4 + 32 * (g & 1)) * 4;
  const int idx_hi = idx_lo + 64;
  const bool upper = (l >= 32);

  // ---------- phase-1 staging/compute (KVBLK=64) ----------
  auto stage64 = [&](int t) {                  // t in 64-kv units
    const int kv0 = t * 64;
    char* dst = smem + (t & 1) * 24576;
    const size_t krow = (size_t)(bS + kv0 + rowloc) * D_MODEL + hoff + k_src;
    gload16(Khi + krow, dst + (w << 10));
    gload16(Klo + krow, dst + 8192 + (w << 10));
    const size_t vrow = (hoff + rowloc) * (size_t)NROWS + bS + kv0 + k_src;
    gload16(VT + vrow, dst + 16384 + (w << 10));
  };

  auto compute64 = [&](int t) {
    const char* buf = smem + (t & 1) * 24576;
    const int kv0 = t * 64;

    f32x4 s[4] = {};
    __builtin_amdgcn_s_setprio(1);
#pragma unroll
    for (int ni = 0; ni < 4; ni++) {
      const int row = ni * 16 + q4;
#pragma unroll
      for (int ks = 0; ks < 2; ks++) {
        const int boff = row * 128 + 16 * ((ks * 4 + g) ^ (row & 7));
        f16x8 kh8 = *(const f16x8*)(buf + boff);
        f16x8 kl8 = *(const f16x8*)(buf + 8192 + boff);
        s[ni] = MFMA16(kh8, qh[ks], s[ni], 0, 0, 0);
        s[ni] = MFMA16(kh8, ql[ks], s[ni], 0, 0, 0);
        s[ni] = MFMA16(kl8, qh[ks], s[ni], 0, 0, 0);
      }
    }
    __builtin_amdgcn_s_setprio(0);

    const bool need_mask = (kv0 + 63) > qw;
    const int q_abs = qw + q4;
    float p[4][4];
    float pm = -INFINITY;
#pragma unroll
    for (int ni = 0; ni < 4; ni++)
#pragma unroll
      for (int j = 0; j < 4; j++) {
        float v = s[ni][j];
        if (need_mask && (kv0 + ni * 16 + 4 * g + j) > q_abs) v = -INFINITY;
        p[ni][j] = v;
        pm = fmaxf(pm, v);
      }
    pm = fmaxf(pm, __shfl_xor(pm, 16));
    pm = fmaxf(pm, __shfl_xor(pm, 32));

    if (!__all(pm - m_run <= 8.0f)) {
      const float mn = fmaxf(m_run, pm);
      const float sc2 = __builtin_amdgcn_exp2f(m_run - mn);
      m_run = mn;
      l_run *= sc2;
#pragma unroll
      for (int nd = 0; nd < 4; nd++)
#pragma unroll
        for (int j = 0; j < 4; j++) o[nd][j] *= sc2;
    }
    float ps = 0.f;
#pragma unroll
    for (int ni = 0; ni < 4; ni++)
#pragma unroll
      for (int j = 0; j < 4; j++) {
        const float e = __builtin_amdgcn_exp2f(p[ni][j] - m_run);
        p[ni][j] = e;
        ps += e;
      }
    ps += __shfl_xor(ps, 16);
    ps += __shfl_xor(ps, 32);
    l_run += ps;

    f16x8 pa[2];
#pragma unroll
    for (int h2 = 0; h2 < 2; h2++) {
      const int pk0 = pkh2(p[2*h2][0],   p[2*h2][1]);
      const int pk1 = pkh2(p[2*h2][2],   p[2*h2][3]);
      const int pk2 = pkh2(p[2*h2+1][0], p[2*h2+1][1]);
      const int pk3 = pkh2(p[2*h2+1][2], p[2*h2+1][3]);
      const int b0l = __builtin_amdgcn_ds_bpermute(idx_lo, pk0);
      const int b2l = __builtin_amdgcn_ds_bpermute(idx_lo, pk2);
      const int b1l = __builtin_amdgcn_ds_bpermute(idx_lo, pk1);
      const int b3l = __builtin_amdgcn_ds_bpermute(idx_lo, pk3);
      const int b0h = __builtin_amdgcn_ds_bpermute(idx_hi, pk0);
      const int b2h = __builtin_amdgcn_ds_bpermute(idx_hi, pk2);
      const int b1h = __builtin_amdgcn_ds_bpermute(idx_hi, pk1);
      const int b3h = __builtin_amdgcn_ds_bpermute(idx_hi, pk3);
      union { int u[4]; f16x8 v; } pu;
      pu.u[0] = upper ? b2l : b0l;
      pu.u[1] = upper ? b3l : b1l;
      pu.u[2] = upper ? b2h : b0h;
      pu.u[3] = upper ? b3h : b1h;
      pa[h2] = pu.v;
    }

    __builtin_amdgcn_s_setprio(1);
#pragma unroll
    for (int nd = 0; nd < 4; nd++) {
      const int d = nd * 16 + q4;
#pragma unroll
      for (int h2 = 0; h2 < 2; h2++) {
        f16x8 bv = *(const f16x8*)(buf + 16384 + d * 128 + 16 * ((h2 * 4 + g) ^ (d & 7)));
        o[nd] = MFMA16(bv, pa[h2], o[nd], 0, 0, 0);
      }
    }
    __builtin_amdgcn_s_setprio(0);
  };

  // ---------- phase-2 staging/compute (KVBLK=32) ----------
  auto stage32 = [&](int t) {                  // t in 32-kv units
    const int kv0 = t * 32;
    char* sb = smem + (t & 3) * 12288;
    if (w < 4) {
      const f16* src = (w < 2) ? Khi : Klo;
      char* dstc = sb + ((w < 2) ? 0 : 4096);
      const int wi2 = w & 1;
#pragma unroll
      for (int gi = 0; gi < 2; gi++) {
        const int sub = 2 * wi2 + gi;
        const int row = 8 * sub + (l >> 3);
        gload16(src + (size_t)(bS + kv0 + row) * D_MODEL + hoff + k_src,
                dstc + sub * 1024);
      }
    } else if (w < 6) {
      const int wi2 = w - 4;
#pragma unroll
      for (int gi = 0; gi < 2; gi++) {
        const int sub = 2 * wi2 + gi;
        const int drow = 16 * sub + (l >> 2);
        gload16(VT + (hoff + drow) * (size_t)NROWS + bS + kv0 + v_src,
                sb + 8192 + sub * 1024);
      }
    }
  };

  auto compute32 = [&](int t) {
    const char* sb = smem + (t & 3) * 12288;
    const int kv0 = t * 32;

    f32x4 s[2] = {};
    __builtin_amdgcn_s_setprio(1);
#pragma unroll
    for (int ni = 0; ni < 2; ni++) {
      const int row = ni * 16 + q4;
#pragma unroll
      for (int ks = 0; ks < 2; ks++) {
        const int boff = row * 128 + 16 * ((ks * 4 + g) ^ (row & 7));
        f16x8 kh8 = *(const f16x8*)(sb + boff);
        f16x8 kl8 = *(const f16x8*)(sb + 4096 + boff);
        s[ni] = MFMA16(kh8, qh[ks], s[ni], 0, 0, 0);
        s[ni] = MFMA16(kh8, ql[ks], s[ni], 0, 0, 0);
        s[ni] = MFMA16(kl8, qh[ks], s[ni], 0, 0, 0);
      }
    }
    __builtin_amdgcn_s_setprio(0);

    const bool need_mask = (kv0 + 31) > qw;
    const int q_abs = qw + q4;
    float p[2][4];
    float pm = -INFINITY;
#pragma unroll
    for (int ni = 0; ni < 2; ni++)
#pragma unroll
      for (int j = 0; j < 4; j++) {
        float v = s[ni][j];
        if (need_mask && (kv0 + ni * 16 + 4 * g + j) > q_abs) v = -INFINITY;
        p[ni][j] = v;
        pm = fmaxf(pm, v);
      }
    pm = fmaxf(pm, __shfl_xor(pm, 16));
    pm = fmaxf(pm, __shfl_xor(pm, 32));

    if (!__all(pm - m_run <= 8.0f)) {
      const float mn = fmaxf(m_run, pm);
      const float sc2 = __builtin_amdgcn_exp2f(m_run - mn);
      m_run = mn;
      l_run *= sc2;
#pragma unroll
      for (int nd = 0; nd < 4; nd++)
#pragma unroll
        for (int j = 0; j < 4; j++) o[nd][j] *= sc2;
    }
    float ps = 0.f;
#pragma unroll
    for (int ni = 0; ni < 2; ni++)
#pragma unroll
      for (int j = 0; j < 4; j++) {
        const float e = __builtin_amdgcn_exp2f(p[ni][j] - m_run);
        p[ni][j] = e;
        ps += e;
      }
    ps += __shfl_xor(ps, 16);
    ps += __shfl_xor(ps, 32);
    l_run += ps;

    const int pk0 = pkh2(p[0][0], p[0][1]);
    const int pk1 = pkh2(p[0][2], p[0][3]);
    const int pk2 = pkh2(p[1][0], p[1][1]);
    const int pk3 = pkh2(p[1][2], p[1][3]);
    const int b0l = __builtin_amdgcn_ds_bpermute(idx_lo, pk0);
    const int b2l = __builtin_amdgcn_ds_bpermute(idx_lo, pk2);
    const int b1l = __builtin_amdgcn_ds_bpermute(idx_lo, pk1);
    const int b3l = __builtin_amdgcn_ds_bpermute(idx_lo, pk3);
    const int b0h = __builtin_amdgcn_ds_bpermute(idx_hi, pk0);
    const int b2h = __builtin_amdgcn_ds_bpermute(idx_hi, pk2);
    const int b1h = __builtin_amdgcn_ds_bpermute(idx_hi, pk1);
    const int b3h = __builtin_amdgcn_ds_bpermute(idx_hi, pk3);
    union { int u[4]; f16x8 v; } pu;
    pu.u[0] = upper ? b2l : b0l;
    pu.u[1] = upper ? b3l : b1l;
    pu.u[2] = upper ? b2h : b0h;
    pu.u[3] = upper ? b3h : b1h;
    const f16x8 pa = pu.v;

    __builtin_amdgcn_s_setprio(1);
#pragma unroll
    for (int nd = 0; nd < 4; nd++) {
      const int d = nd * 16 + q4;
      f16x8 bv = *(const f16x8*)(sb + 8192 + d * 64 + 16 * (g ^ (d & 3)));
      o[nd] = MFMA16(bv, pa, o[nd], 0, 0, 0);
    }
    __builtin_amdgcn_s_setprio(0);
  };

  // ---------- phase 1: KVBLK=64, tiles 0..c, both groups ----------
  stage64(0);
  for (int t = 0; t <= c; t++) {
    if (t + 1 <= c) {
      stage64(t + 1);
      asm volatile("s_waitcnt vmcnt(3)" ::: "memory");
    } else {
      asm volatile("s_waitcnt vmcnt(0)" ::: "memory");
    }
    __builtin_amdgcn_s_barrier();
    compute64(t);
    __builtin_amdgcn_s_barrier();
  }

  // ---------- transition: A writes output, switches to B rows ----------
  if (grp == 0) {
    const float inv = 1.0f / l_run;
    const size_t rowb = (size_t)(bS + qw + q4) * D_MODEL + hoff;
#pragma unroll
    for (int nd = 0; nd < 4; nd++) {
      f16x4 v;
#pragma unroll
      for (int j = 0; j < 4; j++) v[j] = (f16)(o[nd][j] * inv);
      *reinterpret_cast<f16x4*>(Out + rowb + nd * 16 + 4 * g) = v;
    }
    qw = (31 - c) * 64 + wi * 16;
    loadQ();
#pragma unroll
    for (int nd = 0; nd < 4; nd++)
#pragma unroll
      for (int j = 0; j < 4; j++) o[nd][j] = 0.f;
    m_run = -INFINITY;
    l_run = 0.f;
  }

  // ---------- phase 2: KVBLK=32, A = even, B = odd ----------
  stage32(P1);
  stage32(P1 + 1);
  for (int j = 0; j < P2; j++) {
    const int u = P1 + 2 * j;
    const bool st = (u + 3) < T;
    if (st) { stage32(u + 2); stage32(u + 3); }
    if (st) asm volatile("s_waitcnt vmcnt(4)" ::: "memory");
    else    asm volatile("s_waitcnt vmcnt(0)" ::: "memory");
    __builtin_amdgcn_s_barrier();
    compute32(u + grp);
    __builtin_amdgcn_s_barrier();
  }

  // ---------- merge A's phase-2 partial into B's state, write B ----------
  if (grp == 0) {
    float* mb = (float*)smem + wi * 1152 + l * 18;
#pragma unroll
    for (int nd = 0; nd < 4; nd++)
#pragma unroll
      for (int j = 0; j < 4; j++) mb[nd * 4 + j] = o[nd][j];
    mb[16] = m_run;
    mb[17] = l_run;
  }
  __syncthreads();
  if (grp == 1) {
    const float* mb = (const float*)smem + wi * 1152 + l * 18;
    const float m2 = mb[16], l2 = mb[17];
    const float mm = fmaxf(m_run, m2);
    const float a1 = __builtin_amdgcn_exp2f(m_run - mm);
    const float a2 = __builtin_amdgcn_exp2f(m2 - mm);
    const float inv = 1.0f / (l_run * a1 + l2 * a2);
    const size_t rowb = (size_t)(bS + qw + q4) * D_MODEL + hoff;
#pragma unroll
    for (int nd = 0; nd < 4; nd++) {
      f16x4 v;
#pragma unroll
      for (int j = 0; j < 4; j++)
        v[j] = (f16)((o[nd][j] * a1 + mb[nd * 4 + j] * a2) * inv);
      *reinterpret_cast<f16x4*>(Out + rowb + nd * 16 + 4 * g) = v;
    }
  }
}

// ---------------- launcher ----------------
extern "C" void kernel_launch(void* const* d_in, const int* in_sizes, int n_in,
                              void* d_out, int out_size, void* d_ws, size_t ws_size,
                              hipStream_t stream) {
  const float* x  = (const float*)d_in[0];
  const float* pq = (const float*)d_in[1];
  const float* pk = (const float*)d_in[2];
  const float* pv = (const float*)d_in[3];
  const float* po = (const float*)d_in[4];
  float* out = (float*)d_out;

  char* ws = (char*)d_ws;
  size_t off = 0;
  auto alloc = [&](size_t elems) {
    f16* p = (f16*)(ws + off);
    off += ((elems * 2 + 255) & ~(size_t)255);
    return p;
  };
  f16* x_hi  = alloc((size_t)NROWS * D_MODEL);
  f16* x_lo  = alloc((size_t)NROWS * D_MODEL);
  f16* wq_hi = alloc((size_t)D_MODEL * D_MODEL);
  f16* wq_lo = alloc((size_t)D_MODEL * D_MODEL);
  f16* wk_hi = alloc((size_t)D_MODEL * D_MODEL);
  f16* wk_lo = alloc((size_t)D_MODEL * D_MODEL);
  f16* wv_h  = alloc((size_t)D_MODEL * D_MODEL);
  f16* wo_h  = alloc((size_t)D_MODEL * D_MODEL);
  f16* q_hi  = alloc((size_t)NROWS * D_MODEL);
  f16* q_lo  = alloc((size_t)NROWS * D_MODEL);
  f16* k_hi  = alloc((size_t)NROWS * D_MODEL);
  f16* k_lo  = alloc((size_t)NROWS * D_MODEL);
  f16* vt    = alloc((size_t)NROWS * D_MODEL);   // VT[m][b*SEQ+s]
  f16* ao    = alloc((size_t)NROWS * D_MODEL);

  const int n4x = NROWS * D_MODEL / 4;
  const int n4w = D_MODEL * D_MODEL / 4;
  const float qscale = 0.125f * 1.44269504088896f;
  split4_kernel<<<n4x/256, 256, 0, stream>>>(x, x_hi, x_lo, n4x, 1.0f);
  prep_w_kernel<<<n4w/256, 256, 0, stream>>>(pq, pk, pv, po,
                                             wq_hi, wq_lo, wk_hi, wk_lo, wv_h, wo_h,
                                             n4w, qscale);

  // fused Q+K+V projection (V written transposed via LDS epilogue)
  gemm_qkv<<<dim3(16, 32), 256, 0, stream>>>(x_hi, x_lo, wq_hi, wq_lo, wk_hi, wk_lo,
                                             wv_h, q_hi, q_lo, k_hi, k_lo, vt);

  attn_kernel<<<dim3(512), 512, 0, stream>>>(q_hi, q_lo, k_hi, k_lo, vt, ao);

  dim3 gg(D_MODEL/64, NROWS/128);  // (16, 32) row-chunked, 512 blocks
  gemm_nt<true, false><<<gg, 256, 0, stream>>>(ao, wo_h, nullptr, out, NROWS, D_MODEL, D_MODEL);
}

// Round 14
// 150.949 us; speedup vs baseline: 1.6990x; 1.0404x over previous
//
#include <hip/hip_runtime.h>
#include <stdint.h>

#define D_MODEL 1024
#define SEQ     2048
#define NHEAD   16
#define BATCH   2
#define NROWS   (BATCH*SEQ)   // 4096

typedef _Float16 f16;
typedef _Float16 f16x8 __attribute__((ext_vector_type(8)));
typedef _Float16 f16x4 __attribute__((ext_vector_type(4)));
typedef __fp16   h16x2 __attribute__((ext_vector_type(2)));
typedef float    f32x4 __attribute__((ext_vector_type(4)));

#define MFMA16 __builtin_amdgcn_mfma_f32_16x16x32_f16

__device__ __forceinline__ void gload16(const void* g, void* l) {
  __builtin_amdgcn_global_load_lds(
      (const __attribute__((address_space(1))) void*)g,
      (__attribute__((address_space(3))) void*)l, 16, 0, 0);
}

__device__ __forceinline__ int pkh2(float a, float b) {
  union { h16x2 h; int i; } u;
  u.h = __builtin_amdgcn_cvt_pkrtz(a, b);
  return u.i;
}

// ---------------- convert / split kernels ----------------
__global__ void split4_kernel(const float* __restrict__ in, f16* __restrict__ hi,
                              f16* __restrict__ lo, int n4, float scale) {
  int i = blockIdx.x * blockDim.x + threadIdx.x;
  if (i >= n4) return;
  float4 v = reinterpret_cast<const float4*>(in)[i];
  v.x *= scale; v.y *= scale; v.z *= scale; v.w *= scale;
  f16x4 h, l4;
  h[0] = (f16)v.x; h[1] = (f16)v.y; h[2] = (f16)v.z; h[3] = (f16)v.w;
  l4[0] = (f16)(v.x - (float)h[0]);
  l4[1] = (f16)(v.y - (float)h[1]);
  l4[2] = (f16)(v.z - (float)h[2]);
  l4[3] = (f16)(v.w - (float)h[3]);
  *reinterpret_cast<f16x4*>(hi + 4*(size_t)i) = h;
  *reinterpret_cast<f16x4*>(lo + 4*(size_t)i) = l4;
}

// fused weight prep: wq split (scaled), wk split, wv cvt, wo cvt — one pass
__global__ void prep_w_kernel(const float* __restrict__ pq, const float* __restrict__ pk,
                              const float* __restrict__ pv, const float* __restrict__ po,
                              f16* __restrict__ wq_hi, f16* __restrict__ wq_lo,
                              f16* __restrict__ wk_hi, f16* __restrict__ wk_lo,
                              f16* __restrict__ wv_h,  f16* __restrict__ wo_h,
                              int n4, float qscale) {
  int i = blockIdx.x * blockDim.x + threadIdx.x;
  if (i >= n4) return;
  {
    float4 v = reinterpret_cast<const float4*>(pq)[i];
    v.x *= qscale; v.y *= qscale; v.z *= qscale; v.w *= qscale;
    f16x4 h, l4;
    h[0] = (f16)v.x; h[1] = (f16)v.y; h[2] = (f16)v.z; h[3] = (f16)v.w;
    l4[0] = (f16)(v.x - (float)h[0]); l4[1] = (f16)(v.y - (float)h[1]);
    l4[2] = (f16)(v.z - (float)h[2]); l4[3] = (f16)(v.w - (float)h[3]);
    *reinterpret_cast<f16x4*>(wq_hi + 4*(size_t)i) = h;
    *reinterpret_cast<f16x4*>(wq_lo + 4*(size_t)i) = l4;
  }
  {
    float4 v = reinterpret_cast<const float4*>(pk)[i];
    f16x4 h, l4;
    h[0] = (f16)v.x; h[1] = (f16)v.y; h[2] = (f16)v.z; h[3] = (f16)v.w;
    l4[0] = (f16)(v.x - (float)h[0]); l4[1] = (f16)(v.y - (float)h[1]);
    l4[2] = (f16)(v.z - (float)h[2]); l4[3] = (f16)(v.w - (float)h[3]);
    *reinterpret_cast<f16x4*>(wk_hi + 4*(size_t)i) = h;
    *reinterpret_cast<f16x4*>(wk_lo + 4*(size_t)i) = l4;
  }
  {
    float4 v = reinterpret_cast<const float4*>(pv)[i];
    f16x4 h;
    h[0] = (f16)v.x; h[1] = (f16)v.y; h[2] = (f16)v.z; h[3] = (f16)v.w;
    *reinterpret_cast<f16x4*>(wv_h + 4*(size_t)i) = h;
  }
  {
    float4 v = reinterpret_cast<const float4*>(po)[i];
    f16x4 h;
    h[0] = (f16)v.x; h[1] = (f16)v.y; h[2] = (f16)v.z; h[3] = (f16)v.w;
    *reinterpret_cast<f16x4*>(wo_h + 4*(size_t)i) = h;
  }
}

// ---------------- GEMM: C[M,N] = A[M,K] · B[N,K]^T  (NT, plain fp16) -------------
// 128x64 tile, 512 blocks -> 2/CU. Used for the O projection.
template<bool F32_OUT, bool COLCHUNK>
__global__ __launch_bounds__(256, 2)
void gemm_nt(const f16* __restrict__ Ahi,
             const f16* __restrict__ Bhi,
             f16* __restrict__ Chi, float* __restrict__ Cf,
             int M, int N, int K)
{
  constexpr int B_OFF  = 8192;
  constexpr int STRIDE = 12288;
  __shared__ __align__(16) char smem[2 * STRIDE];

  const int tid = threadIdx.x;
  const int w = tid >> 6, l = tid & 63;
  const int wr = (w >> 1) * 64;
  const int wc = (w & 1) * 32;

  const int gx = gridDim.x, gy = gridDim.y;
  const int nwg = gx * gy;
  const int flat = blockIdx.y * gx + blockIdx.x;
  const int swz = (flat & 7) * (nwg >> 3) + (flat >> 3);
  const int bxn = COLCHUNK ? (swz / gy) : (swz % gx);
  const int byn = COLCHUNK ? (swz % gy) : (swz / gx);
  const int bm = byn * 128, bn = bxn * 64;

  f32x4 acc[4][2] = {};

  const int srow = tid >> 2;
  const int schunk = 8 * (((tid & 3) ^ ((srow >> 1) & 3)));

  auto stage = [&](int kt) {
    char* dst = smem + (kt & 1) * STRIDE;
    const int k0 = kt * 32;
    const f16* ga = Ahi + (size_t)(bm + srow) * K + k0 + schunk;
    gload16(ga,        dst + (w << 10));
    gload16(ga + 64*K, dst + 4096 + (w << 10));
    const f16* gb = Bhi + (size_t)(bn + srow) * K + k0 + schunk;
    gload16(gb,        dst + B_OFF + (w << 10));
  };

  const int nkt = K >> 5;
  stage(0);

  for (int kt = 0; kt < nkt; kt++) {
    if (kt + 1 < nkt) {
      stage(kt + 1);
      asm volatile("s_waitcnt vmcnt(3)" ::: "memory");
    } else {
      asm volatile("s_waitcnt vmcnt(0)" ::: "memory");
    }
    __builtin_amdgcn_s_barrier();

    const char* buf = smem + (kt & 1) * STRIDE;
    const int ar = (l & 15);
    const int ak = 16 * ((l >> 4) ^ ((ar >> 1) & 3));
    f16x8 a_hi[4];
#pragma unroll
    for (int mi = 0; mi < 4; mi++)
      a_hi[mi] = *(const f16x8*)(buf + (size_t)(wr + mi*16 + ar) * 64 + ak);
    __builtin_amdgcn_s_setprio(1);
#pragma unroll
    for (int ni = 0; ni < 2; ni++) {
      f16x8 b_hi = *(const f16x8*)(buf + B_OFF + (size_t)(wc + ni*16 + ar) * 64 + ak);
#pragma unroll
      for (int mi = 0; mi < 4; mi++)
        acc[mi][ni] = MFMA16(a_hi[mi], b_hi, acc[mi][ni], 0, 0, 0);
    }
    __builtin_amdgcn_s_setprio(0);
    __builtin_amdgcn_s_barrier();
  }

  const int crow0 = bm + wr + (l >> 4) * 4;
  const int ccol0 = bn + wc + (l & 15);
#pragma unroll
  for (int mi = 0; mi < 4; mi++) {
#pragma unroll
    for (int ni = 0; ni < 2; ni++) {
#pragma unroll
      for (int j = 0; j < 4; j++) {
        size_t idx = (size_t)(crow0 + mi*16 + j) * N + (ccol0 + ni*16);
        float v = acc[mi][ni][j];
        if (F32_OUT) Cf[idx] = v;
        else         Chi[idx] = (f16)v;
      }
    }
  }
}

// ---------------- fused Q+K+V projection GEMM (R13, measured ~57us) ----------
__global__ __launch_bounds__(256, 2)
void gemm_qkv(const f16* __restrict__ Ahi, const f16* __restrict__ Alo,
              const f16* __restrict__ Bqh, const f16* __restrict__ Bql,
              const f16* __restrict__ Bkh, const f16* __restrict__ Bkl,
              const f16* __restrict__ Bvh,
              f16* __restrict__ Qh, f16* __restrict__ Qlo2,
              f16* __restrict__ Kh, f16* __restrict__ Klo2,
              f16* __restrict__ VT)
{
  constexpr int N = D_MODEL, K = D_MODEL;
  constexpr int STRIDE = 36864;
  __shared__ __align__(16) char smem[2 * STRIDE];

  const int tid = threadIdx.x;
  const int w = tid >> 6, l = tid & 63;
  const int wr = (w >> 1) * 64;
  const int wc = (w & 1) * 32;

  const int flat = blockIdx.y * 16 + blockIdx.x;           // grid (16, 32)
  const int swz = (flat & 7) * 64 + (flat >> 3);           // XCD-chunked
  const int bm = (swz / 16) * 128, bn = (swz % 16) * 64;

  f32x4 accQ[4][2] = {}, accK[4][2] = {}, accV[4][2] = {};

  const int srow = tid >> 2;
  const int schunk = 8 * (((tid & 3) ^ ((srow >> 1) & 3)));

  auto stage = [&](int kt) {
    char* dst = smem + (kt & 1) * STRIDE;
    const int k0 = kt * 32;
    const f16* ga = Ahi + (size_t)(bm + srow) * K + k0 + schunk;
    gload16(ga,        dst + (w << 10));
    gload16(ga + 64*K, dst + 4096 + (w << 10));
    const f16* gal = Alo + (size_t)(bm + srow) * K + k0 + schunk;
    gload16(gal,        dst + 8192 + (w << 10));
    gload16(gal + 64*K, dst + 12288 + (w << 10));
    const size_t bo = (size_t)(bn + srow) * K + k0 + schunk;
    gload16(Bqh + bo, dst + 16384 + (w << 10));
    gload16(Bql + bo, dst + 20480 + (w << 10));
    gload16(Bkh + bo, dst + 24576 + (w << 10));
    gload16(Bkl + bo, dst + 28672 + (w << 10));
    gload16(Bvh + bo, dst + 32768 + (w << 10));
  };

  const int nkt = K >> 5;   // 32
  stage(0);

  for (int kt = 0; kt < nkt; kt++) {
    if (kt + 1 < nkt) {
      stage(kt + 1);
      asm volatile("s_waitcnt vmcnt(9)" ::: "memory");
    } else {
      asm volatile("s_waitcnt vmcnt(0)" ::: "memory");
    }
    __builtin_amdgcn_s_barrier();

    const char* buf = smem + (kt & 1) * STRIDE;
    const int ar = (l & 15);
    const int ak = 16 * ((l >> 4) ^ ((ar >> 1) & 3));
    f16x8 a_hi[4], a_lo[4];
#pragma unroll
    for (int mi = 0; mi < 4; mi++) {
      a_hi[mi] = *(const f16x8*)(buf + (size_t)(wr + mi*16 + ar) * 64 + ak);
      a_lo[mi] = *(const f16x8*)(buf + 8192 + (size_t)(wr + mi*16 + ar) * 64 + ak);
    }
    __builtin_amdgcn_s_setprio(1);
#pragma unroll
    for (int ni = 0; ni < 2; ni++) {
      const int bo = (wc + ni*16 + ar) * 64 + ak;
      f16x8 bqh = *(const f16x8*)(buf + 16384 + bo);
      f16x8 bql = *(const f16x8*)(buf + 20480 + bo);
      f16x8 bkh = *(const f16x8*)(buf + 24576 + bo);
      f16x8 bkl = *(const f16x8*)(buf + 28672 + bo);
      f16x8 bvh = *(const f16x8*)(buf + 32768 + bo);
#pragma unroll
      for (int mi = 0; mi < 4; mi++) {
        accQ[mi][ni] = MFMA16(a_hi[mi], bqh, accQ[mi][ni], 0, 0, 0);
        accQ[mi][ni] = MFMA16(a_hi[mi], bql, accQ[mi][ni], 0, 0, 0);
        accQ[mi][ni] = MFMA16(a_lo[mi], bqh, accQ[mi][ni], 0, 0, 0);
        accK[mi][ni] = MFMA16(a_hi[mi], bkh, accK[mi][ni], 0, 0, 0);
        accK[mi][ni] = MFMA16(a_hi[mi], bkl, accK[mi][ni], 0, 0, 0);
        accK[mi][ni] = MFMA16(a_lo[mi], bkh, accK[mi][ni], 0, 0, 0);
        accV[mi][ni] = MFMA16(a_hi[mi], bvh, accV[mi][ni], 0, 0, 0);
      }
    }
    __builtin_amdgcn_s_setprio(0);
    __builtin_amdgcn_s_barrier();
  }

  // ---- Q/K epilogue: direct stores with hi/lo re-split ----
  const int crow0 = bm + wr + (l >> 4) * 4;
  const int ccol0 = bn + wc + (l & 15);
#pragma unroll
  for (int mi = 0; mi < 4; mi++) {
#pragma unroll
    for (int ni = 0; ni < 2; ni++) {
#pragma unroll
      for (int j = 0; j < 4; j++) {
        size_t idx = (size_t)(crow0 + mi*16 + j) * N + (ccol0 + ni*16);
        float qv = accQ[mi][ni][j];
        f16 qh = (f16)qv;
        Qh[idx] = qh;  Qlo2[idx] = (f16)(qv - (float)qh);
        float kv = accK[mi][ni][j];
        f16 kh = (f16)kv;
        Kh[idx] = kh;  Klo2[idx] = (f16)(kv - (float)kh);
      }
    }
  }

  // ---- V epilogue: transpose through LDS, coalesced VT stores ----
  {
    f16* tl = (f16*)smem;
#pragma unroll
    for (int mi = 0; mi < 4; mi++) {
#pragma unroll
      for (int ni = 0; ni < 2; ni++) {
        f16x4 v;
#pragma unroll
        for (int j = 0; j < 4; j++) v[j] = (f16)accV[mi][ni][j];
        const int m_l = wc + ni*16 + (l & 15);
        const int n_l = wr + mi*16 + ((l >> 4) << 2);
        *reinterpret_cast<f16x4*>(tl + m_l*136 + n_l) = v;
      }
    }
    __syncthreads();
    const int m_l = tid >> 2, cg = tid & 3;
    const size_t vbase = (size_t)(bn + m_l) * NROWS + bm + cg*32;
#pragma unroll
    for (int k2 = 0; k2 < 4; k2++) {
      f16x8 v = *reinterpret_cast<const f16x8*>(tl + m_l*136 + cg*32 + k2*8);
      *reinterpret_cast<f16x8*>(VT + vbase + k2*8) = v;
    }
  }
}

// ---------------- flash attention v9 (pair blocks, KVBLK=64 everywhere) ----------
// Block = q-tile pair (c, 31-c); waves 0-3 = group A, 4-7 = group B.
// Phase 1 (tiles 0..c): both groups compute the same 64-kv tile.
// Transition: A writes output, reloads Q for B rows, resets state.
// Phase 2 (tiles c+1..31-c): group A = even-index tiles, B = odd, 2 tiles/iter
//   in a ring of 3 x 24KB slots (u%3); stage(u+2) before compute, stage(u+3)
//   after the post-compute barrier (slot u%3, dead by then); vmcnt(3)/(0).
// Every block = exactly 17 iterations. (m,l,o) merged via LDS at the end.
__global__ __launch_bounds__(512, 4)
void attn_kernel(const f16* __restrict__ Qhi, const f16* __restrict__ Qlo,
                 const f16* __restrict__ Khi, const f16* __restrict__ Klo,
                 const f16* __restrict__ VT, f16* __restrict__ Out)
{
  __shared__ __align__(16) char smem[73728];   // 3 x 24KB ring (+ merge reuse)

  const int tid = threadIdx.x, w = tid >> 6, l = tid & 63;
  const int g = l >> 4, q4 = l & 15;
  const int wi = w & 3, grp = w >> 2;
  const int flat = blockIdx.x;
  const int xcd = flat & 7, slot = flat >> 3;
  const int bh = xcd * 4 + (slot >> 4);        // 4 heads resident per XCD
  const int c = slot & 15;
  const int b = bh >> 4, h = bh & 15;
  const int bS = b * SEQ;
  const size_t hoff = (size_t)h * 64;
  const int TB = 31 - c;                       // last 64-tile index for B rows

  int qw = (grp ? (31 - c) : c) * 64 + wi * 16;

  f16x8 qh[2], ql[2];
  auto loadQ = [&]() {
#pragma unroll
    for (int ks = 0; ks < 2; ks++) {
      const size_t base = (size_t)(bS + qw + q4) * D_MODEL + hoff + ks * 32 + g * 8;
      qh[ks] = *(const f16x8*)(Qhi + base);
      ql[ks] = *(const f16x8*)(Qlo + base);
    }
  };
  loadQ();

  f32x4 o[4] = {};
  float m_run = -INFINITY, l_run = 0.f;

  const int k_src = 8 * ((l & 7) ^ (l >> 3));          // 128B rows: chunk ^ (row&7)
  const int rowloc = w * 8 + (l >> 3);                 // staging row (8/wave)

  // P^T redistribution constants
  const int idx_lo = (q4 + 32 * (g & 1)) * 4;
  const int idx_hi = idx_lo + 64;
  const bool upper = (l >= 32);

  // stage a 64-kv tile into ring slot sb (24KB: Khi 8K | Klo 8K | VT 8K)
  auto stage64 = [&](int t, int slot3) {
    const int kv0 = t * 64;
    char* dst = smem + slot3 * 24576;
    const size_t krow = (size_t)(bS + kv0 + rowloc) * D_MODEL + hoff + k_src;
    gload16(Khi + krow, dst + (w << 10));
    gload16(Klo + krow, dst + 8192 + (w << 10));
    const size_t vrow = (hoff + rowloc) * (size_t)NROWS + bS + kv0 + k_src;
    gload16(VT + vrow, dst + 16384 + (w << 10));
  };

  auto compute64 = [&](int t, int slot3) {
    const char* buf = smem + slot3 * 24576;
    const int kv0 = t * 64;

    f32x4 s[4] = {};
    __builtin_amdgcn_s_setprio(1);
#pragma unroll
    for (int ni = 0; ni < 4; ni++) {
      const int row = ni * 16 + q4;
#pragma unroll
      for (int ks = 0; ks < 2; ks++) {
        const int boff = row * 128 + 16 * ((ks * 4 + g) ^ (row & 7));
        f16x8 kh8 = *(const f16x8*)(buf + boff);
        f16x8 kl8 = *(const f16x8*)(buf + 8192 + boff);
        s[ni] = MFMA16(kh8, qh[ks], s[ni], 0, 0, 0);
        s[ni] = MFMA16(kh8, ql[ks], s[ni], 0, 0, 0);
        s[ni] = MFMA16(kl8, qh[ks], s[ni], 0, 0, 0);
      }
    }
    __builtin_amdgcn_s_setprio(0);

    const bool need_mask = (kv0 + 63) > qw;
    const int q_abs = qw + q4;
    float p[4][4];
    float pm = -INFINITY;
#pragma unroll
    for (int ni = 0; ni < 4; ni++)
#pragma unroll
      for (int j = 0; j < 4; j++) {
        float v = s[ni][j];
        if (need_mask && (kv0 + ni * 16 + 4 * g + j) > q_abs) v = -INFINITY;
        p[ni][j] = v;
        pm = fmaxf(pm, v);
      }
    pm = fmaxf(pm, __shfl_xor(pm, 16));
    pm = fmaxf(pm, __shfl_xor(pm, 32));

    if (!__all(pm - m_run <= 8.0f)) {
      const float mn = fmaxf(m_run, pm);
      const float sc2 = __builtin_amdgcn_exp2f(m_run - mn);
      m_run = mn;
      l_run *= sc2;
#pragma unroll
      for (int nd = 0; nd < 4; nd++)
#pragma unroll
        for (int j = 0; j < 4; j++) o[nd][j] *= sc2;
    }
    float ps = 0.f;
#pragma unroll
    for (int ni = 0; ni < 4; ni++)
#pragma unroll
      for (int j = 0; j < 4; j++) {
        const float e = __builtin_amdgcn_exp2f(p[ni][j] - m_run);
        p[ni][j] = e;
        ps += e;
      }
    ps += __shfl_xor(ps, 16);
    ps += __shfl_xor(ps, 32);
    l_run += ps;

    f16x8 pa[2];
#pragma unroll
    for (int h2 = 0; h2 < 2; h2++) {
      const int pk0 = pkh2(p[2*h2][0],   p[2*h2][1]);
      const int pk1 = pkh2(p[2*h2][2],   p[2*h2][3]);
      const int pk2 = pkh2(p[2*h2+1][0], p[2*h2+1][1]);
      const int pk3 = pkh2(p[2*h2+1][2], p[2*h2+1][3]);
      const int b0l = __builtin_amdgcn_ds_bpermute(idx_lo, pk0);
      const int b2l = __builtin_amdgcn_ds_bpermute(idx_lo, pk2);
      const int b1l = __builtin_amdgcn_ds_bpermute(idx_lo, pk1);
      const int b3l = __builtin_amdgcn_ds_bpermute(idx_lo, pk3);
      const int b0h = __builtin_amdgcn_ds_bpermute(idx_hi, pk0);
      const int b2h = __builtin_amdgcn_ds_bpermute(idx_hi, pk2);
      const int b1h = __builtin_amdgcn_ds_bpermute(idx_hi, pk1);
      const int b3h = __builtin_amdgcn_ds_bpermute(idx_hi, pk3);
      union { int u[4]; f16x8 v; } pu;
      pu.u[0] = upper ? b2l : b0l;
      pu.u[1] = upper ? b3l : b1l;
      pu.u[2] = upper ? b2h : b0h;
      pu.u[3] = upper ? b3h : b1h;
      pa[h2] = pu.v;
    }

    __builtin_amdgcn_s_setprio(1);
#pragma unroll
    for (int nd = 0; nd < 4; nd++) {
      const int d = nd * 16 + q4;
#pragma unroll
      for (int h2 = 0; h2 < 2; h2++) {
        f16x8 bv = *(const f16x8*)(buf + 16384 + d * 128 + 16 * ((h2 * 4 + g) ^ (d & 7)));
        o[nd] = MFMA16(bv, pa[h2], o[nd], 0, 0, 0);
      }
    }
    __builtin_amdgcn_s_setprio(0);
  };

  // ---------- phase 1: tiles 0..c, both groups (double-buffer slots 0/1) -------
  stage64(0, 0);
  for (int t = 0; t <= c; t++) {
    if (t + 1 <= c) {
      stage64(t + 1, (t + 1) & 1);
      asm volatile("s_waitcnt vmcnt(3)" ::: "memory");
    } else {
      asm volatile("s_waitcnt vmcnt(0)" ::: "memory");
    }
    __builtin_amdgcn_s_barrier();
    compute64(t, t & 1);
    __builtin_amdgcn_s_barrier();
  }

  // ---------- transition: A writes output, switches to B rows ----------
  if (grp == 0) {
    const float inv = 1.0f / l_run;
    const size_t rowb = (size_t)(bS + qw + q4) * D_MODEL + hoff;
#pragma unroll
    for (int nd = 0; nd < 4; nd++) {
      f16x4 v;
#pragma unroll
      for (int j = 0; j < 4; j++) v[j] = (f16)(o[nd][j] * inv);
      *reinterpret_cast<f16x4*>(Out + rowb + nd * 16 + 4 * g) = v;
    }
    qw = (31 - c) * 64 + wi * 16;
    loadQ();
#pragma unroll
    for (int nd = 0; nd < 4; nd++)
#pragma unroll
      for (int j = 0; j < 4; j++) o[nd][j] = 0.f;
    m_run = -INFINITY;
    l_run = 0.f;
  }

  // ---------- phase 2: tiles c+1..TB, A = even-pos, B = odd-pos ----------
  {
    const int u0 = c + 1;
    stage64(u0, u0 % 3);
    if (u0 + 1 <= TB) stage64(u0 + 1, (u0 + 1) % 3);
    const int iters = (TB - u0) / 2 + 1;       // = 16 - c
    for (int j = 0; j < iters; j++) {
      const int u = u0 + 2 * j;
      const bool pf1 = (u + 2) <= TB;
      if (pf1) {
        stage64(u + 2, (u + 2) % 3);
        asm volatile("s_waitcnt vmcnt(3)" ::: "memory");
      } else {
        asm volatile("s_waitcnt vmcnt(0)" ::: "memory");
      }
      __builtin_amdgcn_s_barrier();
      if (grp == 0)          compute64(u, u % 3);
      else if (u + 1 <= TB)  compute64(u + 1, (u + 1) % 3);
      __builtin_amdgcn_s_barrier();
      if ((u + 3) <= TB) stage64(u + 3, (u + 3) % 3);
    }
  }

  // ---------- merge A's phase-2 partial into B's state, write B ----------
  __builtin_amdgcn_s_barrier();
  if (grp == 0) {
    float* mb = (float*)smem + wi * 1152 + l * 18;
#pragma unroll
    for (int nd = 0; nd < 4; nd++)
#pragma unroll
      for (int j = 0; j < 4; j++) mb[nd * 4 + j] = o[nd][j];
    mb[16] = m_run;
    mb[17] = l_run;
  }
  __syncthreads();
  if (grp == 1) {
    const float* mb = (const float*)smem + wi * 1152 + l * 18;
    const float m2 = mb[16], l2 = mb[17];
    const float mm = fmaxf(m_run, m2);
    const float a1 = __builtin_amdgcn_exp2f(m_run - mm);
    const float a2 = __builtin_amdgcn_exp2f(m2 - mm);
    const float inv = 1.0f / (l_run * a1 + l2 * a2);
    const size_t rowb = (size_t)(bS + qw + q4) * D_MODEL + hoff;
#pragma unroll
    for (int nd = 0; nd < 4; nd++) {
      f16x4 v;
#pragma unroll
      for (int j = 0; j < 4; j++)
        v[j] = (f16)((o[nd][j] * a1 + mb[nd * 4 + j] * a2) * inv);
      *reinterpret_cast<f16x4*>(Out + rowb + nd * 16 + 4 * g) = v;
    }
  }
}

// ---------------- launcher ----------------
extern "C" void kernel_launch(void* const* d_in, const int* in_sizes, int n_in,
                              void* d_out, int out_size, void* d_ws, size_t ws_size,
                              hipStream_t stream) {
  const float* x  = (const float*)d_in[0];
  const float* pq = (const float*)d_in[1];
  const float* pk = (const float*)d_in[2];
  const float* pv = (const float*)d_in[3];
  const float* po = (const float*)d_in[4];
  float* out = (float*)d_out;

  char* ws = (char*)d_ws;
  size_t off = 0;
  auto alloc = [&](size_t elems) {
    f16* p = (f16*)(ws + off);
    off += ((elems * 2 + 255) & ~(size_t)255);
    return p;
  };
  f16* x_hi  = alloc((size_t)NROWS * D_MODEL);
  f16* x_lo  = alloc((size_t)NROWS * D_MODEL);
  f16* wq_hi = alloc((size_t)D_MODEL * D_MODEL);
  f16* wq_lo = alloc((size_t)D_MODEL * D_MODEL);
  f16* wk_hi = alloc((size_t)D_MODEL * D_MODEL);
  f16* wk_lo = alloc((size_t)D_MODEL * D_MODEL);
  f16* wv_h  = alloc((size_t)D_MODEL * D_MODEL);
  f16* wo_h  = alloc((size_t)D_MODEL * D_MODEL);
  f16* q_hi  = alloc((size_t)NROWS * D_MODEL);
  f16* q_lo  = alloc((size_t)NROWS * D_MODEL);
  f16* k_hi  = alloc((size_t)NROWS * D_MODEL);
  f16* k_lo  = alloc((size_t)NROWS * D_MODEL);
  f16* vt    = alloc((size_t)NROWS * D_MODEL);   // VT[m][b*SEQ+s]
  f16* ao    = alloc((size_t)NROWS * D_MODEL);

  const int n4x = NROWS * D_MODEL / 4;
  const int n4w = D_MODEL * D_MODEL / 4;
  const float qscale = 0.125f * 1.44269504088896f;
  split4_kernel<<<n4x/256, 256, 0, stream>>>(x, x_hi, x_lo, n4x, 1.0f);
  prep_w_kernel<<<n4w/256, 256, 0, stream>>>(pq, pk, pv, po,
                                             wq_hi, wq_lo, wk_hi, wk_lo, wv_h, wo_h,
                                             n4w, qscale);

  // fused Q+K+V projection (V written transposed via LDS epilogue)
  gemm_qkv<<<dim3(16, 32), 256, 0, stream>>>(x_hi, x_lo, wq_hi, wq_lo, wk_hi, wk_lo,
                                             wv_h, q_hi, q_lo, k_hi, k_lo, vt);

  attn_kernel<<<dim3(512), 512, 0, stream>>>(q_hi, q_lo, k_hi, k_lo, vt, ao);

  dim3 gg(D_MODEL/64, NROWS/128);  // (16, 32) row-chunked, 512 blocks
  gemm_nt<true, false><<<gg, 256, 0, stream>>>(ao, wo_h, nullptr, out, NROWS, D_MODEL, D_MODEL);
}

// Round 15
// 147.429 us; speedup vs baseline: 1.7395x; 1.0239x over previous
//
#include <hip/hip_runtime.h>
#include <stdint.h>

#define D_MODEL 1024
#define SEQ     2048
#define NHEAD   16
#define BATCH   2
#define NROWS   (BATCH*SEQ)   // 4096

typedef _Float16 f16;
typedef _Float16 f16x8 __attribute__((ext_vector_type(8)));
typedef _Float16 f16x4 __attribute__((ext_vector_type(4)));
typedef __fp16   h16x2 __attribute__((ext_vector_type(2)));
typedef float    f32x4 __attribute__((ext_vector_type(4)));

#define MFMA16 __builtin_amdgcn_mfma_f32_16x16x32_f16

__device__ __forceinline__ void gload16(const void* g, void* l) {
  __builtin_amdgcn_global_load_lds(
      (const __attribute__((address_space(1))) void*)g,
      (__attribute__((address_space(3))) void*)l, 16, 0, 0);
}

__device__ __forceinline__ int pkh2(float a, float b) {
  union { h16x2 h; int i; } u;
  u.h = __builtin_amdgcn_cvt_pkrtz(a, b);
  return u.i;
}

// fused weight prep: wq split (scaled), wk split, wv cvt, wo cvt — one pass
__global__ void prep_w_kernel(const float* __restrict__ pq, const float* __restrict__ pk,
                              const float* __restrict__ pv, const float* __restrict__ po,
                              f16* __restrict__ wq_hi, f16* __restrict__ wq_lo,
                              f16* __restrict__ wk_hi, f16* __restrict__ wk_lo,
                              f16* __restrict__ wv_h,  f16* __restrict__ wo_h,
                              int n4, float qscale) {
  int i = blockIdx.x * blockDim.x + threadIdx.x;
  if (i >= n4) return;
  {
    float4 v = reinterpret_cast<const float4*>(pq)[i];
    v.x *= qscale; v.y *= qscale; v.z *= qscale; v.w *= qscale;
    f16x4 h, l4;
    h[0] = (f16)v.x; h[1] = (f16)v.y; h[2] = (f16)v.z; h[3] = (f16)v.w;
    l4[0] = (f16)(v.x - (float)h[0]); l4[1] = (f16)(v.y - (float)h[1]);
    l4[2] = (f16)(v.z - (float)h[2]); l4[3] = (f16)(v.w - (float)h[3]);
    *reinterpret_cast<f16x4*>(wq_hi + 4*(size_t)i) = h;
    *reinterpret_cast<f16x4*>(wq_lo + 4*(size_t)i) = l4;
  }
  {
    float4 v = reinterpret_cast<const float4*>(pk)[i];
    f16x4 h, l4;
    h[0] = (f16)v.x; h[1] = (f16)v.y; h[2] = (f16)v.z; h[3] = (f16)v.w;
    l4[0] = (f16)(v.x - (float)h[0]); l4[1] = (f16)(v.y - (float)h[1]);
    l4[2] = (f16)(v.z - (float)h[2]); l4[3] = (f16)(v.w - (float)h[3]);
    *reinterpret_cast<f16x4*>(wk_hi + 4*(size_t)i) = h;
    *reinterpret_cast<f16x4*>(wk_lo + 4*(size_t)i) = l4;
  }
  {
    float4 v = reinterpret_cast<const float4*>(pv)[i];
    f16x4 h;
    h[0] = (f16)v.x; h[1] = (f16)v.y; h[2] = (f16)v.z; h[3] = (f16)v.w;
    *reinterpret_cast<f16x4*>(wv_h + 4*(size_t)i) = h;
  }
  {
    float4 v = reinterpret_cast<const float4*>(po)[i];
    f16x4 h;
    h[0] = (f16)v.x; h[1] = (f16)v.y; h[2] = (f16)v.z; h[3] = (f16)v.w;
    *reinterpret_cast<f16x4*>(wo_h + 4*(size_t)i) = h;
  }
}

// ---------------- GEMM: C[M,N] = A[M,K] · B[N,K]^T  (NT, plain fp16) -------------
// 128x64 tile, 512 blocks -> 2/CU. Used for the O projection.
template<bool F32_OUT, bool COLCHUNK>
__global__ __launch_bounds__(256, 2)
void gemm_nt(const f16* __restrict__ Ahi,
             const f16* __restrict__ Bhi,
             f16* __restrict__ Chi, float* __restrict__ Cf,
             int M, int N, int K)
{
  constexpr int B_OFF  = 8192;
  constexpr int STRIDE = 12288;
  __shared__ __align__(16) char smem[2 * STRIDE];

  const int tid = threadIdx.x;
  const int w = tid >> 6, l = tid & 63;
  const int wr = (w >> 1) * 64;
  const int wc = (w & 1) * 32;

  const int gx = gridDim.x, gy = gridDim.y;
  const int nwg = gx * gy;
  const int flat = blockIdx.y * gx + blockIdx.x;
  const int swz = (flat & 7) * (nwg >> 3) + (flat >> 3);
  const int bxn = COLCHUNK ? (swz / gy) : (swz % gx);
  const int byn = COLCHUNK ? (swz % gy) : (swz / gx);
  const int bm = byn * 128, bn = bxn * 64;

  f32x4 acc[4][2] = {};

  const int srow = tid >> 2;
  const int schunk = 8 * (((tid & 3) ^ ((srow >> 1) & 3)));

  auto stage = [&](int kt) {
    char* dst = smem + (kt & 1) * STRIDE;
    const int k0 = kt * 32;
    const f16* ga = Ahi + (size_t)(bm + srow) * K + k0 + schunk;
    gload16(ga,        dst + (w << 10));
    gload16(ga + 64*K, dst + 4096 + (w << 10));
    const f16* gb = Bhi + (size_t)(bn + srow) * K + k0 + schunk;
    gload16(gb,        dst + B_OFF + (w << 10));
  };

  const int nkt = K >> 5;
  stage(0);

  for (int kt = 0; kt < nkt; kt++) {
    if (kt + 1 < nkt) {
      stage(kt + 1);
      asm volatile("s_waitcnt vmcnt(3)" ::: "memory");
    } else {
      asm volatile("s_waitcnt vmcnt(0)" ::: "memory");
    }
    __builtin_amdgcn_s_barrier();

    const char* buf = smem + (kt & 1) * STRIDE;
    const int ar = (l & 15);
    const int ak = 16 * ((l >> 4) ^ ((ar >> 1) & 3));
    f16x8 a_hi[4];
#pragma unroll
    for (int mi = 0; mi < 4; mi++)
      a_hi[mi] = *(const f16x8*)(buf + (size_t)(wr + mi*16 + ar) * 64 + ak);
    __builtin_amdgcn_s_setprio(1);
#pragma unroll
    for (int ni = 0; ni < 2; ni++) {
      f16x8 b_hi = *(const f16x8*)(buf + B_OFF + (size_t)(wc + ni*16 + ar) * 64 + ak);
#pragma unroll
      for (int mi = 0; mi < 4; mi++)
        acc[mi][ni] = MFMA16(a_hi[mi], b_hi, acc[mi][ni], 0, 0, 0);
    }
    __builtin_amdgcn_s_setprio(0);
    __builtin_amdgcn_s_barrier();
  }

  const int crow0 = bm + wr + (l >> 4) * 4;
  const int ccol0 = bn + wc + (l & 15);
#pragma unroll
  for (int mi = 0; mi < 4; mi++) {
#pragma unroll
    for (int ni = 0; ni < 2; ni++) {
#pragma unroll
      for (int j = 0; j < 4; j++) {
        size_t idx = (size_t)(crow0 + mi*16 + j) * N + (ccol0 + ni*16);
        float v = acc[mi][ni][j];
        if (F32_OUT) Cf[idx] = v;
        else         Chi[idx] = (f16)v;
      }
    }
  }
}

// ---------------- fused Q+K+V projection GEMM (f32-A staging, R15) ----------
// A = raw f32 x [4096x1024] staged directly (16KB/buffer = same bytes as the
// old hi+lo pair); hi/lo split happens in-register after ds_read (RNE casts,
// numerically identical to the old split4 path). B = wq/wk (hi/lo) + wv.
// Tile 128x64, BK=32, double-buffered (2x36KB LDS), counted vmcnt(9).
__global__ __launch_bounds__(256, 2)
void gemm_qkv(const float* __restrict__ Xf,
              const f16* __restrict__ Bqh, const f16* __restrict__ Bql,
              const f16* __restrict__ Bkh, const f16* __restrict__ Bkl,
              const f16* __restrict__ Bvh,
              f16* __restrict__ Qh, f16* __restrict__ Qlo2,
              f16* __restrict__ Kh, f16* __restrict__ Klo2,
              f16* __restrict__ VT)
{
  constexpr int N = D_MODEL, K = D_MODEL;
  constexpr int STRIDE = 36864;
  __shared__ __align__(16) char smem[2 * STRIDE];
  // per buffer: A_f32 0..16384 | Bqh 16384 | Bql 20480 | Bkh 24576 |
  //             Bkl 28672 | Bvh 32768

  const int tid = threadIdx.x;
  const int w = tid >> 6, l = tid & 63;
  const int wr = (w >> 1) * 64;
  const int wc = (w & 1) * 32;

  const int flat = blockIdx.y * 16 + blockIdx.x;           // grid (16, 32)
  const int swz = (flat & 7) * 64 + (flat >> 3);           // XCD-chunked
  const int bm = (swz / 16) * 128, bn = (swz % 16) * 64;

  f32x4 accQ[4][2] = {}, accK[4][2] = {}, accV[4][2] = {};

  // A staging: f32 rows of 128B (8 chunks); chunk swizzle c ^= (row&7).
  // wave w, call j: lds dst = (w*4+j)*1024 + lane*16; row = w*32+j*8+(l>>3).
  const int a_src = 4 * ((l & 7) ^ (l >> 3));   // f32 units (row&7 == l>>3)
  // B staging: f16 rows of 64B (4 chunks); swizzle c ^= (row>>1)&3.
  const int srow = tid >> 2;
  const int schunk = 8 * (((tid & 3) ^ ((srow >> 1) & 3)));

  auto stage = [&](int kt) {
    char* dst = smem + (kt & 1) * STRIDE;
    const int k0 = kt * 32;
#pragma unroll
    for (int j = 0; j < 4; j++) {
      const int r = w * 32 + j * 8 + (l >> 3);
      gload16(Xf + (size_t)(bm + r) * K + k0 + a_src,
              dst + (w * 4 + j) * 1024);
    }
    const size_t bo = (size_t)(bn + srow) * K + k0 + schunk;
    gload16(Bqh + bo, dst + 16384 + (w << 10));
    gload16(Bql + bo, dst + 20480 + (w << 10));
    gload16(Bkh + bo, dst + 24576 + (w << 10));
    gload16(Bkl + bo, dst + 28672 + (w << 10));
    gload16(Bvh + bo, dst + 32768 + (w << 10));
  };

  const int nkt = K >> 5;   // 32
  stage(0);

  for (int kt = 0; kt < nkt; kt++) {
    if (kt + 1 < nkt) {
      stage(kt + 1);
      asm volatile("s_waitcnt vmcnt(9)" ::: "memory");
    } else {
      asm volatile("s_waitcnt vmcnt(0)" ::: "memory");
    }
    __builtin_amdgcn_s_barrier();

    const char* buf = smem + (kt & 1) * STRIDE;
    const int ar = (l & 15);
    const int g = l >> 4;
    const int ak = 16 * ((l >> 4) ^ ((ar >> 1) & 3));
    f16x8 a_hi[4], a_lo[4];
#pragma unroll
    for (int mi = 0; mi < 4; mi++) {
      const int row = wr + mi * 16 + ar;
      const int rk = ar & 7;
      f32x4 a0 = *(const f32x4*)(buf + row * 128 + 16 * ((2 * g)     ^ rk));
      f32x4 a1 = *(const f32x4*)(buf + row * 128 + 16 * ((2 * g + 1) ^ rk));
      f16x8 h, lo8;
#pragma unroll
      for (int e = 0; e < 4; e++) {
        f16 h0 = (f16)a0[e]; h[e]     = h0; lo8[e]     = (f16)(a0[e] - (float)h0);
        f16 h1 = (f16)a1[e]; h[4 + e] = h1; lo8[4 + e] = (f16)(a1[e] - (float)h1);
      }
      a_hi[mi] = h;
      a_lo[mi] = lo8;
    }
    __builtin_amdgcn_s_setprio(1);
#pragma unroll
    for (int ni = 0; ni < 2; ni++) {
      const int bo = (wc + ni*16 + ar) * 64 + ak;
      f16x8 bqh = *(const f16x8*)(buf + 16384 + bo);
      f16x8 bql = *(const f16x8*)(buf + 20480 + bo);
      f16x8 bkh = *(const f16x8*)(buf + 24576 + bo);
      f16x8 bkl = *(const f16x8*)(buf + 28672 + bo);
      f16x8 bvh = *(const f16x8*)(buf + 32768 + bo);
#pragma unroll
      for (int mi = 0; mi < 4; mi++) {
        accQ[mi][ni] = MFMA16(a_hi[mi], bqh, accQ[mi][ni], 0, 0, 0);
        accQ[mi][ni] = MFMA16(a_hi[mi], bql, accQ[mi][ni], 0, 0, 0);
        accQ[mi][ni] = MFMA16(a_lo[mi], bqh, accQ[mi][ni], 0, 0, 0);
        accK[mi][ni] = MFMA16(a_hi[mi], bkh, accK[mi][ni], 0, 0, 0);
        accK[mi][ni] = MFMA16(a_hi[mi], bkl, accK[mi][ni], 0, 0, 0);
        accK[mi][ni] = MFMA16(a_lo[mi], bkh, accK[mi][ni], 0, 0, 0);
        accV[mi][ni] = MFMA16(a_hi[mi], bvh, accV[mi][ni], 0, 0, 0);
      }
    }
    __builtin_amdgcn_s_setprio(0);
    __builtin_amdgcn_s_barrier();
  }

  // ---- Q/K epilogue: direct stores with hi/lo re-split ----
  const int crow0 = bm + wr + (l >> 4) * 4;
  const int ccol0 = bn + wc + (l & 15);
#pragma unroll
  for (int mi = 0; mi < 4; mi++) {
#pragma unroll
    for (int ni = 0; ni < 2; ni++) {
#pragma unroll
      for (int j = 0; j < 4; j++) {
        size_t idx = (size_t)(crow0 + mi*16 + j) * N + (ccol0 + ni*16);
        float qv = accQ[mi][ni][j];
        f16 qh = (f16)qv;
        Qh[idx] = qh;  Qlo2[idx] = (f16)(qv - (float)qh);
        float kv = accK[mi][ni][j];
        f16 kh = (f16)kv;
        Kh[idx] = kh;  Klo2[idx] = (f16)(kv - (float)kh);
      }
    }
  }

  // ---- V epilogue: transpose through LDS, coalesced VT stores ----
  {
    f16* tl = (f16*)smem;
#pragma unroll
    for (int mi = 0; mi < 4; mi++) {
#pragma unroll
      for (int ni = 0; ni < 2; ni++) {
        f16x4 v;
#pragma unroll
        for (int j = 0; j < 4; j++) v[j] = (f16)accV[mi][ni][j];
        const int m_l = wc + ni*16 + (l & 15);
        const int n_l = wr + mi*16 + ((l >> 4) << 2);
        *reinterpret_cast<f16x4*>(tl + m_l*136 + n_l) = v;
      }
    }
    __syncthreads();
    const int m_l = tid >> 2, cg = tid & 3;
    const size_t vbase = (size_t)(bn + m_l) * NROWS + bm + cg*32;
#pragma unroll
    for (int k2 = 0; k2 < 4; k2++) {
      f16x8 v = *reinterpret_cast<const f16x8*>(tl + m_l*136 + cg*32 + k2*8);
      *reinterpret_cast<f16x8*>(VT + vbase + k2*8) = v;
    }
  }
}

// ---------------- flash attention v9 (pair blocks, KVBLK=64 everywhere) ----------
// (byte-identical to round 14)
__global__ __launch_bounds__(512, 4)
void attn_kernel(const f16* __restrict__ Qhi, const f16* __restrict__ Qlo,
                 const f16* __restrict__ Khi, const f16* __restrict__ Klo,
                 const f16* __restrict__ VT, f16* __restrict__ Out)
{
  __shared__ __align__(16) char smem[73728];   // 3 x 24KB ring (+ merge reuse)

  const int tid = threadIdx.x, w = tid >> 6, l = tid & 63;
  const int g = l >> 4, q4 = l & 15;
  const int wi = w & 3, grp = w >> 2;
  const int flat = blockIdx.x;
  const int xcd = flat & 7, slot = flat >> 3;
  const int bh = xcd * 4 + (slot >> 4);        // 4 heads resident per XCD
  const int c = slot & 15;
  const int b = bh >> 4, h = bh & 15;
  const int bS = b * SEQ;
  const size_t hoff = (size_t)h * 64;
  const int TB = 31 - c;                       // last 64-tile index for B rows

  int qw = (grp ? (31 - c) : c) * 64 + wi * 16;

  f16x8 qh[2], ql[2];
  auto loadQ = [&]() {
#pragma unroll
    for (int ks = 0; ks < 2; ks++) {
      const size_t base = (size_t)(bS + qw + q4) * D_MODEL + hoff + ks * 32 + g * 8;
      qh[ks] = *(const f16x8*)(Qhi + base);
      ql[ks] = *(const f16x8*)(Qlo + base);
    }
  };
  loadQ();

  f32x4 o[4] = {};
  float m_run = -INFINITY, l_run = 0.f;

  const int k_src = 8 * ((l & 7) ^ (l >> 3));          // 128B rows: chunk ^ (row&7)
  const int rowloc = w * 8 + (l >> 3);                 // staging row (8/wave)

  // P^T redistribution constants
  const int idx_lo = (q4 + 32 * (g & 1)) * 4;
  const int idx_hi = idx_lo + 64;
  const bool upper = (l >= 32);

  // stage a 64-kv tile into ring slot (24KB: Khi 8K | Klo 8K | VT 8K)
  auto stage64 = [&](int t, int slot3) {
    const int kv0 = t * 64;
    char* dst = smem + slot3 * 24576;
    const size_t krow = (size_t)(bS + kv0 + rowloc) * D_MODEL + hoff + k_src;
    gload16(Khi + krow, dst + (w << 10));
    gload16(Klo + krow, dst + 8192 + (w << 10));
    const size_t vrow = (hoff + rowloc) * (size_t)NROWS + bS + kv0 + k_src;
    gload16(VT + vrow, dst + 16384 + (w << 10));
  };

  auto compute64 = [&](int t, int slot3) {
    const char* buf = smem + slot3 * 24576;
    const int kv0 = t * 64;

    f32x4 s[4] = {};
    __builtin_amdgcn_s_setprio(1);
#pragma unroll
    for (int ni = 0; ni < 4; ni++) {
      const int row = ni * 16 + q4;
#pragma unroll
      for (int ks = 0; ks < 2; ks++) {
        const int boff = row * 128 + 16 * ((ks * 4 + g) ^ (row & 7));
        f16x8 kh8 = *(const f16x8*)(buf + boff);
        f16x8 kl8 = *(const f16x8*)(buf + 8192 + boff);
        s[ni] = MFMA16(kh8, qh[ks], s[ni], 0, 0, 0);
        s[ni] = MFMA16(kh8, ql[ks], s[ni], 0, 0, 0);
        s[ni] = MFMA16(kl8, qh[ks], s[ni], 0, 0, 0);
      }
    }
    __builtin_amdgcn_s_setprio(0);

    const bool need_mask = (kv0 + 63) > qw;
    const int q_abs = qw + q4;
    float p[4][4];
    float pm = -INFINITY;
#pragma unroll
    for (int ni = 0; ni < 4; ni++)
#pragma unroll
      for (int j = 0; j < 4; j++) {
        float v = s[ni][j];
        if (need_mask && (kv0 + ni * 16 + 4 * g + j) > q_abs) v = -INFINITY;
        p[ni][j] = v;
        pm = fmaxf(pm, v);
      }
    pm = fmaxf(pm, __shfl_xor(pm, 16));
    pm = fmaxf(pm, __shfl_xor(pm, 32));

    if (!__all(pm - m_run <= 8.0f)) {
      const float mn = fmaxf(m_run, pm);
      const float sc2 = __builtin_amdgcn_exp2f(m_run - mn);
      m_run = mn;
      l_run *= sc2;
#pragma unroll
      for (int nd = 0; nd < 4; nd++)
#pragma unroll
        for (int j = 0; j < 4; j++) o[nd][j] *= sc2;
    }
    float ps = 0.f;
#pragma unroll
    for (int ni = 0; ni < 4; ni++)
#pragma unroll
      for (int j = 0; j < 4; j++) {
        const float e = __builtin_amdgcn_exp2f(p[ni][j] - m_run);
        p[ni][j] = e;
        ps += e;
      }
    ps += __shfl_xor(ps, 16);
    ps += __shfl_xor(ps, 32);
    l_run += ps;

    f16x8 pa[2];
#pragma unroll
    for (int h2 = 0; h2 < 2; h2++) {
      const int pk0 = pkh2(p[2*h2][0],   p[2*h2][1]);
      const int pk1 = pkh2(p[2*h2][2],   p[2*h2][3]);
      const int pk2 = pkh2(p[2*h2+1][0], p[2*h2+1][1]);
      const int pk3 = pkh2(p[2*h2+1][2], p[2*h2+1][3]);
      const int b0l = __builtin_amdgcn_ds_bpermute(idx_lo, pk0);
      const int b2l = __builtin_amdgcn_ds_bpermute(idx_lo, pk2);
      const int b1l = __builtin_amdgcn_ds_bpermute(idx_lo, pk1);
      const int b3l = __builtin_amdgcn_ds_bpermute(idx_lo, pk3);
      const int b0h = __builtin_amdgcn_ds_bpermute(idx_hi, pk0);
      const int b2h = __builtin_amdgcn_ds_bpermute(idx_hi, pk2);
      const int b1h = __builtin_amdgcn_ds_bpermute(idx_hi, pk1);
      const int b3h = __builtin_amdgcn_ds_bpermute(idx_hi, pk3);
      union { int u[4]; f16x8 v; } pu;
      pu.u[0] = upper ? b2l : b0l;
      pu.u[1] = upper ? b3l : b1l;
      pu.u[2] = upper ? b2h : b0h;
      pu.u[3] = upper ? b3h : b1h;
      pa[h2] = pu.v;
    }

    __builtin_amdgcn_s_setprio(1);
#pragma unroll
    for (int nd = 0; nd < 4; nd++) {
      const int d = nd * 16 + q4;
#pragma unroll
      for (int h2 = 0; h2 < 2; h2++) {
        f16x8 bv = *(const f16x8*)(buf + 16384 + d * 128 + 16 * ((h2 * 4 + g) ^ (d & 7)));
        o[nd] = MFMA16(bv, pa[h2], o[nd], 0, 0, 0);
      }
    }
    __builtin_amdgcn_s_setprio(0);
  };

  // ---------- phase 1: tiles 0..c, both groups (double-buffer slots 0/1) -------
  stage64(0, 0);
  for (int t = 0; t <= c; t++) {
    if (t + 1 <= c) {
      stage64(t + 1, (t + 1) & 1);
      asm volatile("s_waitcnt vmcnt(3)" ::: "memory");
    } else {
      asm volatile("s_waitcnt vmcnt(0)" ::: "memory");
    }
    __builtin_amdgcn_s_barrier();
    compute64(t, t & 1);
    __builtin_amdgcn_s_barrier();
  }

  // ---------- transition: A writes output, switches to B rows ----------
  if (grp == 0) {
    const float inv = 1.0f / l_run;
    const size_t rowb = (size_t)(bS + qw + q4) * D_MODEL + hoff;
#pragma unroll
    for (int nd = 0; nd < 4; nd++) {
      f16x4 v;
#pragma unroll
      for (int j = 0; j < 4; j++) v[j] = (f16)(o[nd][j] * inv);
      *reinterpret_cast<f16x4*>(Out + rowb + nd * 16 + 4 * g) = v;
    }
    qw = (31 - c) * 64 + wi * 16;
    loadQ();
#pragma unroll
    for (int nd = 0; nd < 4; nd++)
#pragma unroll
      for (int j = 0; j < 4; j++) o[nd][j] = 0.f;
    m_run = -INFINITY;
    l_run = 0.f;
  }

  // ---------- phase 2: tiles c+1..TB, A = even-pos, B = odd-pos ----------
  {
    const int u0 = c + 1;
    stage64(u0, u0 % 3);
    if (u0 + 1 <= TB) stage64(u0 + 1, (u0 + 1) % 3);
    const int iters = (TB - u0) / 2 + 1;       // = 16 - c
    for (int j = 0; j < iters; j++) {
      const int u = u0 + 2 * j;
      const bool pf1 = (u + 2) <= TB;
      if (pf1) {
        stage64(u + 2, (u + 2) % 3);
        asm volatile("s_waitcnt vmcnt(3)" ::: "memory");
      } else {
        asm volatile("s_waitcnt vmcnt(0)" ::: "memory");
      }
      __builtin_amdgcn_s_barrier();
      if (grp == 0)          compute64(u, u % 3);
      else if (u + 1 <= TB)  compute64(u + 1, (u + 1) % 3);
      __builtin_amdgcn_s_barrier();
      if ((u + 3) <= TB) stage64(u + 3, (u + 3) % 3);
    }
  }

  // ---------- merge A's phase-2 partial into B's state, write B ----------
  __builtin_amdgcn_s_barrier();
  if (grp == 0) {
    float* mb = (float*)smem + wi * 1152 + l * 18;
#pragma unroll
    for (int nd = 0; nd < 4; nd++)
#pragma unroll
      for (int j = 0; j < 4; j++) mb[nd * 4 + j] = o[nd][j];
    mb[16] = m_run;
    mb[17] = l_run;
  }
  __syncthreads();
  if (grp == 1) {
    const float* mb = (const float*)smem + wi * 1152 + l * 18;
    const float m2 = mb[16], l2 = mb[17];
    const float mm = fmaxf(m_run, m2);
    const float a1 = __builtin_amdgcn_exp2f(m_run - mm);
    const float a2 = __builtin_amdgcn_exp2f(m2 - mm);
    const float inv = 1.0f / (l_run * a1 + l2 * a2);
    const size_t rowb = (size_t)(bS + qw + q4) * D_MODEL + hoff;
#pragma unroll
    for (int nd = 0; nd < 4; nd++) {
      f16x4 v;
#pragma unroll
      for (int j = 0; j < 4; j++)
        v[j] = (f16)((o[nd][j] * a1 + mb[nd * 4 + j] * a2) * inv);
      *reinterpret_cast<f16x4*>(Out + rowb + nd * 16 + 4 * g) = v;
    }
  }
}

// ---------------- launcher ----------------
extern "C" void kernel_launch(void* const* d_in, const int* in_sizes, int n_in,
                              void* d_out, int out_size, void* d_ws, size_t ws_size,
                              hipStream_t stream) {
  const float* x  = (const float*)d_in[0];
  const float* pq = (const float*)d_in[1];
  const float* pk = (const float*)d_in[2];
  const float* pv = (const float*)d_in[3];
  const float* po = (const float*)d_in[4];
  float* out = (float*)d_out;

  char* ws = (char*)d_ws;
  size_t off = 0;
  auto alloc = [&](size_t elems) {
    f16* p = (f16*)(ws + off);
    off += ((elems * 2 + 255) & ~(size_t)255);
    return p;
  };
  f16* wq_hi = alloc((size_t)D_MODEL * D_MODEL);
  f16* wq_lo = alloc((size_t)D_MODEL * D_MODEL);
  f16* wk_hi = alloc((size_t)D_MODEL * D_MODEL);
  f16* wk_lo = alloc((size_t)D_MODEL * D_MODEL);
  f16* wv_h  = alloc((size_t)D_MODEL * D_MODEL);
  f16* wo_h  = alloc((size_t)D_MODEL * D_MODEL);
  f16* q_hi  = alloc((size_t)NROWS * D_MODEL);
  f16* q_lo  = alloc((size_t)NROWS * D_MODEL);
  f16* k_hi  = alloc((size_t)NROWS * D_MODEL);
  f16* k_lo  = alloc((size_t)NROWS * D_MODEL);
  f16* vt    = alloc((size_t)NROWS * D_MODEL);   // VT[m][b*SEQ+s]
  f16* ao    = alloc((size_t)NROWS * D_MODEL);

  const int n4w = D_MODEL * D_MODEL / 4;
  const float qscale = 0.125f * 1.44269504088896f;
  prep_w_kernel<<<n4w/256, 256, 0, stream>>>(pq, pk, pv, po,
                                             wq_hi, wq_lo, wk_hi, wk_lo, wv_h, wo_h,
                                             n4w, qscale);

  // fused Q+K+V projection (raw f32 x staged; in-register hi/lo split)
  gemm_qkv<<<dim3(16, 32), 256, 0, stream>>>(x, wq_hi, wq_lo, wk_hi, wk_lo,
                                             wv_h, q_hi, q_lo, k_hi, k_lo, vt);

  attn_kernel<<<dim3(512), 512, 0, stream>>>(q_hi, q_lo, k_hi, k_lo, vt, ao);

  dim3 gg(D_MODEL/64, NROWS/128);  // (16, 32) row-chunked, 512 blocks
  gemm_nt<true, false><<<gg, 256, 0, stream>>>(ao, wo_h, nullptr, out, NROWS, D_MODEL, D_MODEL);
}

// Round 16
// 147.166 us; speedup vs baseline: 1.7426x; 1.0018x over previous
//
#include <hip/hip_runtime.h>
#include <stdint.h>

#define D_MODEL 1024
#define SEQ     2048
#define NHEAD   16
#define BATCH   2
#define NROWS   (BATCH*SEQ)   // 4096

typedef _Float16 f16;
typedef _Float16 f16x8 __attribute__((ext_vector_type(8)));
typedef _Float16 f16x4 __attribute__((ext_vector_type(4)));
typedef __fp16   h16x2 __attribute__((ext_vector_type(2)));
typedef float    f32x4 __attribute__((ext_vector_type(4)));

#define MFMA16 __builtin_amdgcn_mfma_f32_16x16x32_f16

__device__ __forceinline__ void gload16(const void* g, void* l) {
  __builtin_amdgcn_global_load_lds(
      (const __attribute__((address_space(1))) void*)g,
      (__attribute__((address_space(3))) void*)l, 16, 0, 0);
}

__device__ __forceinline__ int pkh2(float a, float b) {
  union { h16x2 h; int i; } u;
  u.h = __builtin_amdgcn_cvt_pkrtz(a, b);
  return u.i;
}

// fused weight prep: wq split (scaled), wk split, wv cvt, wo cvt — one pass
__global__ void prep_w_kernel(const float* __restrict__ pq, const float* __restrict__ pk,
                              const float* __restrict__ pv, const float* __restrict__ po,
                              f16* __restrict__ wq_hi, f16* __restrict__ wq_lo,
                              f16* __restrict__ wk_hi, f16* __restrict__ wk_lo,
                              f16* __restrict__ wv_h,  f16* __restrict__ wo_h,
                              int n4, float qscale) {
  int i = blockIdx.x * blockDim.x + threadIdx.x;
  if (i >= n4) return;
  {
    float4 v = reinterpret_cast<const float4*>(pq)[i];
    v.x *= qscale; v.y *= qscale; v.z *= qscale; v.w *= qscale;
    f16x4 h, l4;
    h[0] = (f16)v.x; h[1] = (f16)v.y; h[2] = (f16)v.z; h[3] = (f16)v.w;
    l4[0] = (f16)(v.x - (float)h[0]); l4[1] = (f16)(v.y - (float)h[1]);
    l4[2] = (f16)(v.z - (float)h[2]); l4[3] = (f16)(v.w - (float)h[3]);
    *reinterpret_cast<f16x4*>(wq_hi + 4*(size_t)i) = h;
    *reinterpret_cast<f16x4*>(wq_lo + 4*(size_t)i) = l4;
  }
  {
    float4 v = reinterpret_cast<const float4*>(pk)[i];
    f16x4 h, l4;
    h[0] = (f16)v.x; h[1] = (f16)v.y; h[2] = (f16)v.z; h[3] = (f16)v.w;
    l4[0] = (f16)(v.x - (float)h[0]); l4[1] = (f16)(v.y - (float)h[1]);
    l4[2] = (f16)(v.z - (float)h[2]); l4[3] = (f16)(v.w - (float)h[3]);
    *reinterpret_cast<f16x4*>(wk_hi + 4*(size_t)i) = h;
    *reinterpret_cast<f16x4*>(wk_lo + 4*(size_t)i) = l4;
  }
  {
    float4 v = reinterpret_cast<const float4*>(pv)[i];
    f16x4 h;
    h[0] = (f16)v.x; h[1] = (f16)v.y; h[2] = (f16)v.z; h[3] = (f16)v.w;
    *reinterpret_cast<f16x4*>(wv_h + 4*(size_t)i) = h;
  }
  {
    float4 v = reinterpret_cast<const float4*>(po)[i];
    f16x4 h;
    h[0] = (f16)v.x; h[1] = (f16)v.y; h[2] = (f16)v.z; h[3] = (f16)v.w;
    *reinterpret_cast<f16x4*>(wo_h + 4*(size_t)i) = h;
  }
}

// ---------------- GEMM: C[M,N] = A[M,K] · B[N,K]^T  (NT, plain fp16) -------------
// 128x64 tile, 512 blocks -> 2/CU. Used for the O projection.
template<bool F32_OUT, bool COLCHUNK>
__global__ __launch_bounds__(256, 2)
void gemm_nt(const f16* __restrict__ Ahi,
             const f16* __restrict__ Bhi,
             f16* __restrict__ Chi, float* __restrict__ Cf,
             int M, int N, int K)
{
  constexpr int B_OFF  = 8192;
  constexpr int STRIDE = 12288;
  __shared__ __align__(16) char smem[2 * STRIDE];

  const int tid = threadIdx.x;
  const int w = tid >> 6, l = tid & 63;
  const int wr = (w >> 1) * 64;
  const int wc = (w & 1) * 32;

  const int gx = gridDim.x, gy = gridDim.y;
  const int nwg = gx * gy;
  const int flat = blockIdx.y * gx + blockIdx.x;
  const int swz = (flat & 7) * (nwg >> 3) + (flat >> 3);
  const int bxn = COLCHUNK ? (swz / gy) : (swz % gx);
  const int byn = COLCHUNK ? (swz % gy) : (swz / gx);
  const int bm = byn * 128, bn = bxn * 64;

  f32x4 acc[4][2] = {};

  const int srow = tid >> 2;
  const int schunk = 8 * (((tid & 3) ^ ((srow >> 1) & 3)));

  auto stage = [&](int kt) {
    char* dst = smem + (kt & 1) * STRIDE;
    const int k0 = kt * 32;
    const f16* ga = Ahi + (size_t)(bm + srow) * K + k0 + schunk;
    gload16(ga,        dst + (w << 10));
    gload16(ga + 64*K, dst + 4096 + (w << 10));
    const f16* gb = Bhi + (size_t)(bn + srow) * K + k0 + schunk;
    gload16(gb,        dst + B_OFF + (w << 10));
  };

  const int nkt = K >> 5;
  stage(0);

  for (int kt = 0; kt < nkt; kt++) {
    if (kt + 1 < nkt) {
      stage(kt + 1);
      asm volatile("s_waitcnt vmcnt(3)" ::: "memory");
    } else {
      asm volatile("s_waitcnt vmcnt(0)" ::: "memory");
    }
    __builtin_amdgcn_s_barrier();

    const char* buf = smem + (kt & 1) * STRIDE;
    const int ar = (l & 15);
    const int ak = 16 * ((l >> 4) ^ ((ar >> 1) & 3));
    f16x8 a_hi[4];
#pragma unroll
    for (int mi = 0; mi < 4; mi++)
      a_hi[mi] = *(const f16x8*)(buf + (size_t)(wr + mi*16 + ar) * 64 + ak);
    __builtin_amdgcn_s_setprio(1);
#pragma unroll
    for (int ni = 0; ni < 2; ni++) {
      f16x8 b_hi = *(const f16x8*)(buf + B_OFF + (size_t)(wc + ni*16 + ar) * 64 + ak);
#pragma unroll
      for (int mi = 0; mi < 4; mi++)
        acc[mi][ni] = MFMA16(a_hi[mi], b_hi, acc[mi][ni], 0, 0, 0);
    }
    __builtin_amdgcn_s_setprio(0);
    __builtin_amdgcn_s_barrier();
  }

  const int crow0 = bm + wr + (l >> 4) * 4;
  const int ccol0 = bn + wc + (l & 15);
#pragma unroll
  for (int mi = 0; mi < 4; mi++) {
#pragma unroll
    for (int ni = 0; ni < 2; ni++) {
#pragma unroll
      for (int j = 0; j < 4; j++) {
        size_t idx = (size_t)(crow0 + mi*16 + j) * N + (ccol0 + ni*16);
        float v = acc[mi][ni][j];
        if (F32_OUT) Cf[idx] = v;
        else         Chi[idx] = (f16)v;
      }
    }
  }
}

// ---------------- fused Q+K+V projection GEMM (f32-A staging, packed split) -------
// A = raw f32 x staged directly; hi/lo split in-register via v_cvt_pkrtz packs
// (hi: 4 packs; lo: 8 cvt-back + 8 sub + 4 packs — ~24 VALU/fragment vs ~40
// for the scalar chain). RTZ rounding on hi doubles |lo| bound but residual
// a_lo*b_lo stays ~(1e-3)^2 relative — negligible vs logit budget.
__global__ __launch_bounds__(256, 2)
void gemm_qkv(const float* __restrict__ Xf,
              const f16* __restrict__ Bqh, const f16* __restrict__ Bql,
              const f16* __restrict__ Bkh, const f16* __restrict__ Bkl,
              const f16* __restrict__ Bvh,
              f16* __restrict__ Qh, f16* __restrict__ Qlo2,
              f16* __restrict__ Kh, f16* __restrict__ Klo2,
              f16* __restrict__ VT)
{
  constexpr int N = D_MODEL, K = D_MODEL;
  constexpr int STRIDE = 36864;
  __shared__ __align__(16) char smem[2 * STRIDE];
  // per buffer: A_f32 0..16384 | Bqh 16384 | Bql 20480 | Bkh 24576 |
  //             Bkl 28672 | Bvh 32768

  const int tid = threadIdx.x;
  const int w = tid >> 6, l = tid & 63;
  const int wr = (w >> 1) * 64;
  const int wc = (w & 1) * 32;

  const int flat = blockIdx.y * 16 + blockIdx.x;           // grid (16, 32)
  const int swz = (flat & 7) * 64 + (flat >> 3);           // XCD-chunked
  const int bm = (swz / 16) * 128, bn = (swz % 16) * 64;

  f32x4 accQ[4][2] = {}, accK[4][2] = {}, accV[4][2] = {};

  const int a_src = 4 * ((l & 7) ^ (l >> 3));   // f32 units; row&7 == l>>3
  const int srow = tid >> 2;
  const int schunk = 8 * (((tid & 3) ^ ((srow >> 1) & 3)));

  auto stage = [&](int kt) {
    char* dst = smem + (kt & 1) * STRIDE;
    const int k0 = kt * 32;
#pragma unroll
    for (int j = 0; j < 4; j++) {
      const int r = w * 32 + j * 8 + (l >> 3);
      gload16(Xf + (size_t)(bm + r) * K + k0 + a_src,
              dst + (w * 4 + j) * 1024);
    }
    const size_t bo = (size_t)(bn + srow) * K + k0 + schunk;
    gload16(Bqh + bo, dst + 16384 + (w << 10));
    gload16(Bql + bo, dst + 20480 + (w << 10));
    gload16(Bkh + bo, dst + 24576 + (w << 10));
    gload16(Bkl + bo, dst + 28672 + (w << 10));
    gload16(Bvh + bo, dst + 32768 + (w << 10));
  };

  const int nkt = K >> 5;   // 32
  stage(0);

  for (int kt = 0; kt < nkt; kt++) {
    if (kt + 1 < nkt) {
      stage(kt + 1);
      asm volatile("s_waitcnt vmcnt(9)" ::: "memory");
    } else {
      asm volatile("s_waitcnt vmcnt(0)" ::: "memory");
    }
    __builtin_amdgcn_s_barrier();

    const char* buf = smem + (kt & 1) * STRIDE;
    const int ar = (l & 15);
    const int g = l >> 4;
    const int ak = 16 * ((l >> 4) ^ ((ar >> 1) & 3));
    f16x8 a_hi[4], a_lo[4];
#pragma unroll
    for (int mi = 0; mi < 4; mi++) {
      const int row = wr + mi * 16 + ar;
      const int rk = ar & 7;
      f32x4 a0 = *(const f32x4*)(buf + row * 128 + 16 * ((2 * g)     ^ rk));
      f32x4 a1 = *(const f32x4*)(buf + row * 128 + 16 * ((2 * g + 1) ^ rk));
      union { int u[4]; f16x8 v; } hh, ll;
      hh.u[0] = pkh2(a0[0], a0[1]);
      hh.u[1] = pkh2(a0[2], a0[3]);
      hh.u[2] = pkh2(a1[0], a1[1]);
      hh.u[3] = pkh2(a1[2], a1[3]);
      const f16x8 h = hh.v;
      ll.u[0] = pkh2(a0[0] - (float)h[0], a0[1] - (float)h[1]);
      ll.u[1] = pkh2(a0[2] - (float)h[2], a0[3] - (float)h[3]);
      ll.u[2] = pkh2(a1[0] - (float)h[4], a1[1] - (float)h[5]);
      ll.u[3] = pkh2(a1[2] - (float)h[6], a1[3] - (float)h[7]);
      a_hi[mi] = h;
      a_lo[mi] = ll.v;
    }
    __builtin_amdgcn_s_setprio(1);
#pragma unroll
    for (int ni = 0; ni < 2; ni++) {
      const int bo = (wc + ni*16 + ar) * 64 + ak;
      f16x8 bqh = *(const f16x8*)(buf + 16384 + bo);
      f16x8 bql = *(const f16x8*)(buf + 20480 + bo);
      f16x8 bkh = *(const f16x8*)(buf + 24576 + bo);
      f16x8 bkl = *(const f16x8*)(buf + 28672 + bo);
      f16x8 bvh = *(const f16x8*)(buf + 32768 + bo);
#pragma unroll
      for (int mi = 0; mi < 4; mi++) {
        accQ[mi][ni] = MFMA16(a_hi[mi], bqh, accQ[mi][ni], 0, 0, 0);
        accQ[mi][ni] = MFMA16(a_hi[mi], bql, accQ[mi][ni], 0, 0, 0);
        accQ[mi][ni] = MFMA16(a_lo[mi], bqh, accQ[mi][ni], 0, 0, 0);
        accK[mi][ni] = MFMA16(a_hi[mi], bkh, accK[mi][ni], 0, 0, 0);
        accK[mi][ni] = MFMA16(a_hi[mi], bkl, accK[mi][ni], 0, 0, 0);
        accK[mi][ni] = MFMA16(a_lo[mi], bkh, accK[mi][ni], 0, 0, 0);
        accV[mi][ni] = MFMA16(a_hi[mi], bvh, accV[mi][ni], 0, 0, 0);
      }
    }
    __builtin_amdgcn_s_setprio(0);
    __builtin_amdgcn_s_barrier();
  }

  // ---- Q/K epilogue: direct stores with hi/lo re-split ----
  const int crow0 = bm + wr + (l >> 4) * 4;
  const int ccol0 = bn + wc + (l & 15);
#pragma unroll
  for (int mi = 0; mi < 4; mi++) {
#pragma unroll
    for (int ni = 0; ni < 2; ni++) {
#pragma unroll
      for (int j = 0; j < 4; j++) {
        size_t idx = (size_t)(crow0 + mi*16 + j) * N + (ccol0 + ni*16);
        float qv = accQ[mi][ni][j];
        f16 qh = (f16)qv;
        Qh[idx] = qh;  Qlo2[idx] = (f16)(qv - (float)qh);
        float kv = accK[mi][ni][j];
        f16 kh = (f16)kv;
        Kh[idx] = kh;  Klo2[idx] = (f16)(kv - (float)kh);
      }
    }
  }

  // ---- V epilogue: transpose through LDS, coalesced VT stores ----
  {
    f16* tl = (f16*)smem;
#pragma unroll
    for (int mi = 0; mi < 4; mi++) {
#pragma unroll
      for (int ni = 0; ni < 2; ni++) {
        f16x4 v;
#pragma unroll
        for (int j = 0; j < 4; j++) v[j] = (f16)accV[mi][ni][j];
        const int m_l = wc + ni*16 + (l & 15);
        const int n_l = wr + mi*16 + ((l >> 4) << 2);
        *reinterpret_cast<f16x4*>(tl + m_l*136 + n_l) = v;
      }
    }
    __syncthreads();
    const int m_l = tid >> 2, cg = tid & 3;
    const size_t vbase = (size_t)(bn + m_l) * NROWS + bm + cg*32;
#pragma unroll
    for (int k2 = 0; k2 < 4; k2++) {
      f16x8 v = *reinterpret_cast<const f16x8*>(tl + m_l*136 + cg*32 + k2*8);
      *reinterpret_cast<f16x8*>(VT + vbase + k2*8) = v;
    }
  }
}

// ---------------- flash attention v9 (pair blocks, KVBLK=64 everywhere) ----------
// (byte-identical to round 15)
__global__ __launch_bounds__(512, 4)
void attn_kernel(const f16* __restrict__ Qhi, const f16* __restrict__ Qlo,
                 const f16* __restrict__ Khi, const f16* __restrict__ Klo,
                 const f16* __restrict__ VT, f16* __restrict__ Out)
{
  __shared__ __align__(16) char smem[73728];   // 3 x 24KB ring (+ merge reuse)

  const int tid = threadIdx.x, w = tid >> 6, l = tid & 63;
  const int g = l >> 4, q4 = l & 15;
  const int wi = w & 3, grp = w >> 2;
  const int flat = blockIdx.x;
  const int xcd = flat & 7, slot = flat >> 3;
  const int bh = xcd * 4 + (slot >> 4);        // 4 heads resident per XCD
  const int c = slot & 15;
  const int b = bh >> 4, h = bh & 15;
  const int bS = b * SEQ;
  const size_t hoff = (size_t)h * 64;
  const int TB = 31 - c;                       // last 64-tile index for B rows

  int qw = (grp ? (31 - c) : c) * 64 + wi * 16;

  f16x8 qh[2], ql[2];
  auto loadQ = [&]() {
#pragma unroll
    for (int ks = 0; ks < 2; ks++) {
      const size_t base = (size_t)(bS + qw + q4) * D_MODEL + hoff + ks * 32 + g * 8;
      qh[ks] = *(const f16x8*)(Qhi + base);
      ql[ks] = *(const f16x8*)(Qlo + base);
    }
  };
  loadQ();

  f32x4 o[4] = {};
  float m_run = -INFINITY, l_run = 0.f;

  const int k_src = 8 * ((l & 7) ^ (l >> 3));          // 128B rows: chunk ^ (row&7)
  const int rowloc = w * 8 + (l >> 3);                 // staging row (8/wave)

  // P^T redistribution constants
  const int idx_lo = (q4 + 32 * (g & 1)) * 4;
  const int idx_hi = idx_lo + 64;
  const bool upper = (l >= 32);

  // stage a 64-kv tile into ring slot (24KB: Khi 8K | Klo 8K | VT 8K)
  auto stage64 = [&](int t, int slot3) {
    const int kv0 = t * 64;
    char* dst = smem + slot3 * 24576;
    const size_t krow = (size_t)(bS + kv0 + rowloc) * D_MODEL + hoff + k_src;
    gload16(Khi + krow, dst + (w << 10));
    gload16(Klo + krow, dst + 8192 + (w << 10));
    const size_t vrow = (hoff + rowloc) * (size_t)NROWS + bS + kv0 + k_src;
    gload16(VT + vrow, dst + 16384 + (w << 10));
  };

  auto compute64 = [&](int t, int slot3) {
    const char* buf = smem + slot3 * 24576;
    const int kv0 = t * 64;

    f32x4 s[4] = {};
    __builtin_amdgcn_s_setprio(1);
#pragma unroll
    for (int ni = 0; ni < 4; ni++) {
      const int row = ni * 16 + q4;
#pragma unroll
      for (int ks = 0; ks < 2; ks++) {
        const int boff = row * 128 + 16 * ((ks * 4 + g) ^ (row & 7));
        f16x8 kh8 = *(const f16x8*)(buf + boff);
        f16x8 kl8 = *(const f16x8*)(buf + 8192 + boff);
        s[ni] = MFMA16(kh8, qh[ks], s[ni], 0, 0, 0);
        s[ni] = MFMA16(kh8, ql[ks], s[ni], 0, 0, 0);
        s[ni] = MFMA16(kl8, qh[ks], s[ni], 0, 0, 0);
      }
    }
    __builtin_amdgcn_s_setprio(0);

    const bool need_mask = (kv0 + 63) > qw;
    const int q_abs = qw + q4;
    float p[4][4];
    float pm = -INFINITY;
#pragma unroll
    for (int ni = 0; ni < 4; ni++)
#pragma unroll
      for (int j = 0; j < 4; j++) {
        float v = s[ni][j];
        if (need_mask && (kv0 + ni * 16 + 4 * g + j) > q_abs) v = -INFINITY;
        p[ni][j] = v;
        pm = fmaxf(pm, v);
      }
    pm = fmaxf(pm, __shfl_xor(pm, 16));
    pm = fmaxf(pm, __shfl_xor(pm, 32));

    if (!__all(pm - m_run <= 8.0f)) {
      const float mn = fmaxf(m_run, pm);
      const float sc2 = __builtin_amdgcn_exp2f(m_run - mn);
      m_run = mn;
      l_run *= sc2;
#pragma unroll
      for (int nd = 0; nd < 4; nd++)
#pragma unroll
        for (int j = 0; j < 4; j++) o[nd][j] *= sc2;
    }
    float ps = 0.f;
#pragma unroll
    for (int ni = 0; ni < 4; ni++)
#pragma unroll
      for (int j = 0; j < 4; j++) {
        const float e = __builtin_amdgcn_exp2f(p[ni][j] - m_run);
        p[ni][j] = e;
        ps += e;
      }
    ps += __shfl_xor(ps, 16);
    ps += __shfl_xor(ps, 32);
    l_run += ps;

    f16x8 pa[2];
#pragma unroll
    for (int h2 = 0; h2 < 2; h2++) {
      const int pk0 = pkh2(p[2*h2][0],   p[2*h2][1]);
      const int pk1 = pkh2(p[2*h2][2],   p[2*h2][3]);
      const int pk2 = pkh2(p[2*h2+1][0], p[2*h2+1][1]);
      const int pk3 = pkh2(p[2*h2+1][2], p[2*h2+1][3]);
      const int b0l = __builtin_amdgcn_ds_bpermute(idx_lo, pk0);
      const int b2l = __builtin_amdgcn_ds_bpermute(idx_lo, pk2);
      const int b1l = __builtin_amdgcn_ds_bpermute(idx_lo, pk1);
      const int b3l = __builtin_amdgcn_ds_bpermute(idx_lo, pk3);
      const int b0h = __builtin_amdgcn_ds_bpermute(idx_hi, pk0);
      const int b2h = __builtin_amdgcn_ds_bpermute(idx_hi, pk2);
      const int b1h = __builtin_amdgcn_ds_bpermute(idx_hi, pk1);
      const int b3h = __builtin_amdgcn_ds_bpermute(idx_hi, pk3);
      union { int u[4]; f16x8 v; } pu;
      pu.u[0] = upper ? b2l : b0l;
      pu.u[1] = upper ? b3l : b1l;
      pu.u[2] = upper ? b2h : b0h;
      pu.u[3] = upper ? b3h : b1h;
      pa[h2] = pu.v;
    }

    __builtin_amdgcn_s_setprio(1);
#pragma unroll
    for (int nd = 0; nd < 4; nd++) {
      const int d = nd * 16 + q4;
#pragma unroll
      for (int h2 = 0; h2 < 2; h2++) {
        f16x8 bv = *(const f16x8*)(buf + 16384 + d * 128 + 16 * ((h2 * 4 + g) ^ (d & 7)));
        o[nd] = MFMA16(bv, pa[h2], o[nd], 0, 0, 0);
      }
    }
    __builtin_amdgcn_s_setprio(0);
  };

  // ---------- phase 1: tiles 0..c, both groups (double-buffer slots 0/1) -------
  stage64(0, 0);
  for (int t = 0; t <= c; t++) {
    if (t + 1 <= c) {
      stage64(t + 1, (t + 1) & 1);
      asm volatile("s_waitcnt vmcnt(3)" ::: "memory");
    } else {
      asm volatile("s_waitcnt vmcnt(0)" ::: "memory");
    }
    __builtin_amdgcn_s_barrier();
    compute64(t, t & 1);
    __builtin_amdgcn_s_barrier();
  }

  // ---------- transition: A writes output, switches to B rows ----------
  if (grp == 0) {
    const float inv = 1.0f / l_run;
    const size_t rowb = (size_t)(bS + qw + q4) * D_MODEL + hoff;
#pragma unroll
    for (int nd = 0; nd < 4; nd++) {
      f16x4 v;
#pragma unroll
      for (int j = 0; j < 4; j++) v[j] = (f16)(o[nd][j] * inv);
      *reinterpret_cast<f16x4*>(Out + rowb + nd * 16 + 4 * g) = v;
    }
    qw = (31 - c) * 64 + wi * 16;
    loadQ();
#pragma unroll
    for (int nd = 0; nd < 4; nd++)
#pragma unroll
      for (int j = 0; j < 4; j++) o[nd][j] = 0.f;
    m_run = -INFINITY;
    l_run = 0.f;
  }

  // ---------- phase 2: tiles c+1..TB, A = even-pos, B = odd-pos ----------
  {
    const int u0 = c + 1;
    stage64(u0, u0 % 3);
    if (u0 + 1 <= TB) stage64(u0 + 1, (u0 + 1) % 3);
    const int iters = (TB - u0) / 2 + 1;       // = 16 - c
    for (int j = 0; j < iters; j++) {
      const int u = u0 + 2 * j;
      const bool pf1 = (u + 2) <= TB;
      if (pf1) {
        stage64(u + 2, (u + 2) % 3);
        asm volatile("s_waitcnt vmcnt(3)" ::: "memory");
      } else {
        asm volatile("s_waitcnt vmcnt(0)" ::: "memory");
      }
      __builtin_amdgcn_s_barrier();
      if (grp == 0)          compute64(u, u % 3);
      else if (u + 1 <= TB)  compute64(u + 1, (u + 1) % 3);
      __builtin_amdgcn_s_barrier();
      if ((u + 3) <= TB) stage64(u + 3, (u + 3) % 3);
    }
  }

  // ---------- merge A's phase-2 partial into B's state, write B ----------
  __builtin_amdgcn_s_barrier();
  if (grp == 0) {
    float* mb = (float*)smem + wi * 1152 + l * 18;
#pragma unroll
    for (int nd = 0; nd < 4; nd++)
#pragma unroll
      for (int j = 0; j < 4; j++) mb[nd * 4 + j] = o[nd][j];
    mb[16] = m_run;
    mb[17] = l_run;
  }
  __syncthreads();
  if (grp == 1) {
    const float* mb = (const float*)smem + wi * 1152 + l * 18;
    const float m2 = mb[16], l2 = mb[17];
    const float mm = fmaxf(m_run, m2);
    const float a1 = __builtin_amdgcn_exp2f(m_run - mm);
    const float a2 = __builtin_amdgcn_exp2f(m2 - mm);
    const float inv = 1.0f / (l_run * a1 + l2 * a2);
    const size_t rowb = (size_t)(bS + qw + q4) * D_MODEL + hoff;
#pragma unroll
    for (int nd = 0; nd < 4; nd++) {
      f16x4 v;
#pragma unroll
      for (int j = 0; j < 4; j++)
        v[j] = (f16)((o[nd][j] * a1 + mb[nd * 4 + j] * a2) * inv);
      *reinterpret_cast<f16x4*>(Out + rowb + nd * 16 + 4 * g) = v;
    }
  }
}

// ---------------- launcher ----------------
extern "C" void kernel_launch(void* const* d_in, const int* in_sizes, int n_in,
                              void* d_out, int out_size, void* d_ws, size_t ws_size,
                              hipStream_t stream) {
  const float* x  = (const float*)d_in[0];
  const float* pq = (const float*)d_in[1];
  const float* pk = (const float*)d_in[2];
  const float* pv = (const float*)d_in[3];
  const float* po = (const float*)d_in[4];
  float* out = (float*)d_out;

  char* ws = (char*)d_ws;
  size_t off = 0;
  auto alloc = [&](size_t elems) {
    f16* p = (f16*)(ws + off);
    off += ((elems * 2 + 255) & ~(size_t)255);
    return p;
  };
  f16* wq_hi = alloc((size_t)D_MODEL * D_MODEL);
  f16* wq_lo = alloc((size_t)D_MODEL * D_MODEL);
  f16* wk_hi = alloc((size_t)D_MODEL * D_MODEL);
  f16* wk_lo = alloc((size_t)D_MODEL * D_MODEL);
  f16* wv_h  = alloc((size_t)D_MODEL * D_MODEL);
  f16* wo_h  = alloc((size_t)D_MODEL * D_MODEL);
  f16* q_hi  = alloc((size_t)NROWS * D_MODEL);
  f16* q_lo  = alloc((size_t)NROWS * D_MODEL);
  f16* k_hi  = alloc((size_t)NROWS * D_MODEL);
  f16* k_lo  = alloc((size_t)NROWS * D_MODEL);
  f16* vt    = alloc((size_t)NROWS * D_MODEL);   // VT[m][b*SEQ+s]
  f16* ao    = alloc((size_t)NROWS * D_MODEL);

  const int n4w = D_MODEL * D_MODEL / 4;
  const float qscale = 0.125f * 1.44269504088896f;
  prep_w_kernel<<<n4w/256, 256, 0, stream>>>(pq, pk, pv, po,
                                             wq_hi, wq_lo, wk_hi, wk_lo, wv_h, wo_h,
                                             n4w, qscale);

  // fused Q+K+V projection (raw f32 x staged; packed in-register hi/lo split)
  gemm_qkv<<<dim3(16, 32), 256, 0, stream>>>(x, wq_hi, wq_lo, wk_hi, wk_lo,
                                             wv_h, q_hi, q_lo, k_hi, k_lo, vt);

  attn_kernel<<<dim3(512), 512, 0, stream>>>(q_hi, q_lo, k_hi, k_lo, vt, ao);

  dim3 gg(D_MODEL/64, NROWS/128);  // (16, 32) row-chunked, 512 blocks
  gemm_nt<true, false><<<gg, 256, 0, stream>>>(ao, wo_h, nullptr, out, NROWS, D_MODEL, D_MODEL);
}